// Round 1
// baseline (1072.053 us; speedup 1.0000x reference)
//
#include <hip/hip_runtime.h>
#include <cstdint>

#define N_NODES 50000
#define E_EDGES 800000
#define HC 256           // H*C
#define B_GR 64
#define OUT_DIM 10
#define SLOPE 0.2f

// ---------------- GEMM: C[M x 256] = A[M x K] * W[K x 256] (fp32) -------------
template<int K>
__global__ __launch_bounds__(256) void gemm_kernel(const float* __restrict__ A,
                                                   const float* __restrict__ W,
                                                   float* __restrict__ C, int M) {
    const int BM = 64, BN = 128, BK = 16;
    __shared__ float As[BK][BM];   // transposed tile
    __shared__ float Bs[BK][BN];
    int tid = threadIdx.x;
    int row0 = blockIdx.x * BM;
    int col0 = blockIdx.y * BN;
    int tx = tid & 15;    // 16 col-groups of 8
    int ty = tid >> 4;    // 16 row-groups of 4
    float acc[4][8] = {};
    int am = tid >> 2;           // row in tile 0..63
    int ak = (tid & 3) * 4;      // k offset 0/4/8/12
    for (int k0 = 0; k0 < K; k0 += BK) {
        float4 av = make_float4(0.f, 0.f, 0.f, 0.f);
        int gr = row0 + am;
        if (gr < M) av = *(const float4*)&A[(size_t)gr * K + k0 + ak];
        As[ak + 0][am] = av.x; As[ak + 1][am] = av.y;
        As[ak + 2][am] = av.z; As[ak + 3][am] = av.w;
#pragma unroll
        for (int i = 0; i < 2; ++i) {
            int idx = tid + i * 256;      // 0..511
            int bk = idx >> 5;            // 0..15
            int bn = (idx & 31) * 4;
            *(float4*)&Bs[bk][bn] = *(const float4*)&W[(size_t)(k0 + bk) * HC + col0 + bn];
        }
        __syncthreads();
#pragma unroll
        for (int kk = 0; kk < BK; ++kk) {
            float4 a4 = *(const float4*)&As[kk][ty * 4];
            float4 b0 = *(const float4*)&Bs[kk][tx * 8];
            float4 b1 = *(const float4*)&Bs[kk][tx * 8 + 4];
            float a_[4] = {a4.x, a4.y, a4.z, a4.w};
            float b_[8] = {b0.x, b0.y, b0.z, b0.w, b1.x, b1.y, b1.z, b1.w};
#pragma unroll
            for (int r = 0; r < 4; ++r)
#pragma unroll
                for (int c = 0; c < 8; ++c)
                    acc[r][c] = fmaf(a_[r], b_[c], acc[r][c]);
        }
        __syncthreads();
    }
#pragma unroll
    for (int r = 0; r < 4; ++r) {
        int gr = row0 + ty * 4 + r;
        if (gr < M) {
            float4 o0 = make_float4(acc[r][0], acc[r][1], acc[r][2], acc[r][3]);
            float4 o1 = make_float4(acc[r][4], acc[r][5], acc[r][6], acc[r][7]);
            *(float4*)&C[(size_t)gr * HC + col0 + tx * 8]     = o0;
            *(float4*)&C[(size_t)gr * HC + col0 + tx * 8 + 4] = o1;
        }
    }
}

// ---------------- per-node attention logits al_s/al_d ------------------------
__global__ __launch_bounds__(256) void al_kernel(const float* __restrict__ h,
        const float* __restrict__ a_src, const float* __restrict__ a_dst,
        float* __restrict__ al_s, float* __restrict__ al_d) {
    int node = blockIdx.x * 4 + (threadIdx.x >> 6);
    int lane = threadIdx.x & 63;
    if (node >= N_NODES) return;
    float4 hv = *(const float4*)&h[(size_t)node * HC + lane * 4];
    float4 s4 = *(const float4*)&a_src[lane * 4];
    float4 d4 = *(const float4*)&a_dst[lane * 4];
    float ps = hv.x * s4.x + hv.y * s4.y + hv.z * s4.z + hv.w * s4.w;
    float pd = hv.x * d4.x + hv.y * d4.y + hv.z * d4.z + hv.w * d4.w;
#pragma unroll
    for (int off = 1; off < 16; off <<= 1) {
        ps += __shfl_xor(ps, off, 64);
        pd += __shfl_xor(pd, off, 64);
    }
    if ((lane & 15) == 0) {
        int head = lane >> 4;
        al_s[node * 4 + head] = ps;
        al_d[node * 4 + head] = pd;
    }
}

// ---------------- CSR build (counting sort by dst) ---------------------------
__global__ void init_cnt(int* cnt) {
    int i = blockIdx.x * blockDim.x + threadIdx.x;
    if (i < N_NODES) cnt[i] = 1;   // self-loop pre-counted
}
__global__ void hist_kernel(const int* __restrict__ dsts, int* cnt) {
    int i = blockIdx.x * blockDim.x + threadIdx.x;
    if (i < E_EDGES) atomicAdd(&cnt[dsts[i]], 1);
}
__global__ __launch_bounds__(1024) void scan_kernel(const int* __restrict__ cnt,
                                                    int* row_ptr, int* cursor) {
    __shared__ int sums[1024];
    int t = threadIdx.x;
    const int CH = (N_NODES + 1023) / 1024;  // 49
    int lo = t * CH, hi = min(lo + CH, N_NODES);
    int s = 0;
    for (int i = lo; i < hi; ++i) s += cnt[i];
    sums[t] = s;
    __syncthreads();
    for (int off = 1; off < 1024; off <<= 1) {
        int v = (t >= off) ? sums[t - off] : 0;
        __syncthreads();
        sums[t] += v;
        __syncthreads();
    }
    int run = (t == 0) ? 0 : sums[t - 1];
    for (int i = lo; i < hi; ++i) {
        row_ptr[i] = run; cursor[i] = run;
        run += cnt[i];
    }
    if (t == 1023) row_ptr[N_NODES] = run;
}
__global__ void scatter_kernel(const int* __restrict__ srcs, const int* __restrict__ dsts,
                               int* cursor, int* col) {
    int i = blockIdx.x * blockDim.x + threadIdx.x;
    if (i >= E_EDGES + N_NODES) return;
    int s, d;
    if (i < E_EDGES) { s = srcs[i]; d = dsts[i]; }
    else             { s = d = i - E_EDGES; }     // self loops
    int pos = atomicAdd(&cursor[d], 1);
    col[pos] = s;
}

// ---------------- per-node softmax + aggregation -----------------------------
// mode 0: concat heads, +bias[256], ELU.   mode 1: mean heads, +bias[64], no ELU.
__global__ __launch_bounds__(256) void agg_kernel(const float* __restrict__ h,
        const float* __restrict__ al_s, const float* __restrict__ al_d,
        const int* __restrict__ row_ptr, const int* __restrict__ col,
        const float* __restrict__ bias, float* __restrict__ out, int mode) {
    int node = blockIdx.x * 4 + (threadIdx.x >> 6);
    int lane = threadIdx.x & 63;
    if (node >= N_NODES) return;
    int start = row_ptr[node], end = row_ptr[node + 1];
    const float4 ald = *(const float4*)&al_d[node * 4];

    // pass 1: per-head max of leaky_relu(al_s[src]+al_d[node])
    float m0 = -1e30f, m1 = -1e30f, m2 = -1e30f, m3 = -1e30f;
    for (int j = start + lane; j < end; j += 64) {
        int s = col[j];
        float4 as = *(const float4*)&al_s[s * 4];
        float e0 = as.x + ald.x; e0 = e0 > 0.f ? e0 : SLOPE * e0;
        float e1 = as.y + ald.y; e1 = e1 > 0.f ? e1 : SLOPE * e1;
        float e2 = as.z + ald.z; e2 = e2 > 0.f ? e2 : SLOPE * e2;
        float e3 = as.w + ald.w; e3 = e3 > 0.f ? e3 : SLOPE * e3;
        m0 = fmaxf(m0, e0); m1 = fmaxf(m1, e1);
        m2 = fmaxf(m2, e2); m3 = fmaxf(m3, e3);
    }
#pragma unroll
    for (int off = 1; off < 64; off <<= 1) {
        m0 = fmaxf(m0, __shfl_xor(m0, off, 64));
        m1 = fmaxf(m1, __shfl_xor(m1, off, 64));
        m2 = fmaxf(m2, __shfl_xor(m2, off, 64));
        m3 = fmaxf(m3, __shfl_xor(m3, off, 64));
    }
    // pass 2: per-head denominator
    float d0 = 0.f, d1 = 0.f, d2 = 0.f, d3 = 0.f;
    for (int j = start + lane; j < end; j += 64) {
        int s = col[j];
        float4 as = *(const float4*)&al_s[s * 4];
        float e0 = as.x + ald.x; e0 = e0 > 0.f ? e0 : SLOPE * e0;
        float e1 = as.y + ald.y; e1 = e1 > 0.f ? e1 : SLOPE * e1;
        float e2 = as.z + ald.z; e2 = e2 > 0.f ? e2 : SLOPE * e2;
        float e3 = as.w + ald.w; e3 = e3 > 0.f ? e3 : SLOPE * e3;
        d0 += expf(e0 - m0); d1 += expf(e1 - m1);
        d2 += expf(e2 - m2); d3 += expf(e3 - m3);
    }
#pragma unroll
    for (int off = 1; off < 64; off <<= 1) {
        d0 += __shfl_xor(d0, off, 64);
        d1 += __shfl_xor(d1, off, 64);
        d2 += __shfl_xor(d2, off, 64);
        d3 += __shfl_xor(d3, off, 64);
    }
    float inv0 = 1.f / (d0 + 1e-16f), inv1 = 1.f / (d1 + 1e-16f);
    float inv2 = 1.f / (d2 + 1e-16f), inv3 = 1.f / (d3 + 1e-16f);

    // per-lane head constants (lane covers channels 4*lane..4*lane+3, head = lane/16)
    int head = lane >> 4;
    float ald_h = head == 0 ? ald.x : head == 1 ? ald.y : head == 2 ? ald.z : ald.w;
    float m_h   = head == 0 ? m0    : head == 1 ? m1    : head == 2 ? m2    : m3;
    float inv_h = head == 0 ? inv0  : head == 1 ? inv1  : head == 2 ? inv2  : inv3;

    // pass 3: weighted aggregation of h[src]
    float ax = 0.f, ay = 0.f, az = 0.f, aw = 0.f;
    for (int jb = start; jb < end; jb += 64) {
        int j = jb + lane;
        int cs = (j < end) ? col[j] : 0;
        int cnt = min(64, end - jb);
        for (int t = 0; t < cnt; ++t) {
            int s = __shfl(cs, t, 64);
            float als = al_s[s * 4 + head];
            float e = als + ald_h; e = e > 0.f ? e : SLOPE * e;
            float w = expf(e - m_h) * inv_h;
            float4 hv = *(const float4*)&h[(size_t)s * HC + lane * 4];
            ax = fmaf(w, hv.x, ax); ay = fmaf(w, hv.y, ay);
            az = fmaf(w, hv.z, az); aw = fmaf(w, hv.w, aw);
        }
    }
    if (mode == 0) {
        float4 b4 = *(const float4*)&bias[lane * 4];
        float vx = ax + b4.x; vx = vx > 0.f ? vx : expm1f(vx);
        float vy = ay + b4.y; vy = vy > 0.f ? vy : expm1f(vy);
        float vz = az + b4.z; vz = vz > 0.f ? vz : expm1f(vz);
        float vw = aw + b4.w; vw = vw > 0.f ? vw : expm1f(vw);
        float4 v = make_float4(vx, vy, vz, vw);
        *(float4*)&out[(size_t)node * HC + lane * 4] = v;
    } else {
        // mean over heads: sum lanes lane^16, lane^32
#pragma unroll
        for (int off = 16; off < 64; off <<= 1) {
            ax += __shfl_xor(ax, off, 64);
            ay += __shfl_xor(ay, off, 64);
            az += __shfl_xor(az, off, 64);
            aw += __shfl_xor(aw, off, 64);
        }
        if (lane < 16) {
            float4 b4 = *(const float4*)&bias[lane * 4];
            float4 v = make_float4(ax * 0.25f + b4.x, ay * 0.25f + b4.y,
                                   az * 0.25f + b4.z, aw * 0.25f + b4.w);
            *(float4*)&out[(size_t)node * 64 + lane * 4] = v;
        }
    }
}

// ---------------- pooling + MLP ----------------------------------------------
__global__ __launch_bounds__(64) void pool_kernel(const float* __restrict__ act,
        const int* __restrict__ batch, float* __restrict__ pooled) {
    int b = blockIdx.x;
    int lane = threadIdx.x;
    int lo = 0, hi = N_NODES;
    while (lo < hi) { int mid = (lo + hi) >> 1; if (batch[mid] < b) lo = mid + 1; else hi = mid; }
    int s = lo;
    lo = 0; hi = N_NODES;
    while (lo < hi) { int mid = (lo + hi) >> 1; if (batch[mid] < b + 1) lo = mid + 1; else hi = mid; }
    int e = lo;
    float sum = 0.f;
    for (int n = s; n < e; ++n) sum += act[(size_t)n * 64 + lane];
    float c = (float)max(e - s, 1);
    pooled[b * 64 + lane] = sum / c;
}

__global__ __launch_bounds__(64) void mlp_kernel(const float* __restrict__ pooled,
        const float* __restrict__ pW1, const float* __restrict__ pb1,
        const float* __restrict__ pW2, const float* __restrict__ pb2,
        float* __restrict__ outp) {
    __shared__ float z[32];
    int b = blockIdx.x, t = threadIdx.x;
    if (t < 32) {
        float s = pb1[t];
        for (int c = 0; c < 64; ++c) s += pooled[b * 64 + c] * pW1[c * 32 + t];
        z[t] = s > 0.f ? s : 0.f;
    }
    __syncthreads();
    if (t < OUT_DIM) {
        float s = pb2[t];
        for (int k = 0; k < 32; ++k) s += z[k] * pW2[k * 10 + t];
        outp[b * 10 + t] = s;
    }
}

// ---------------- launch ------------------------------------------------------
extern "C" void kernel_launch(void* const* d_in, const int* in_sizes, int n_in,
                              void* d_out, int out_size, void* d_ws, size_t ws_size,
                              hipStream_t stream) {
    const float* x    = (const float*)d_in[0];
    const int*   ei   = (const int*)d_in[1];
    const int*   batch= (const int*)d_in[2];
    const float* W0   = (const float*)d_in[3];
    const float* b0   = (const float*)d_in[4];
    const float* as0  = (const float*)d_in[5];
    const float* ad0  = (const float*)d_in[6];
    const float* W1   = (const float*)d_in[7];
    const float* b1   = (const float*)d_in[8];
    const float* as1  = (const float*)d_in[9];
    const float* ad1  = (const float*)d_in[10];
    const float* W2   = (const float*)d_in[11];
    const float* b2   = (const float*)d_in[12];
    const float* as2  = (const float*)d_in[13];
    const float* ad2  = (const float*)d_in[14];
    const float* pW1  = (const float*)d_in[15];
    const float* pb1  = (const float*)d_in[16];
    const float* pW2  = (const float*)d_in[17];
    const float* pb2  = (const float*)d_in[18];
    float* out = (float*)d_out;

    char* ws = (char*)d_ws;
    size_t off = 0;
    auto alloc = [&](size_t bytes) -> void* {
        void* p = ws + off;
        off += (bytes + 255) & ~(size_t)255;
        return p;
    };
    float* h      = (float*)alloc((size_t)N_NODES * HC * 4);
    float* act    = (float*)alloc((size_t)N_NODES * HC * 4);
    float* als    = (float*)alloc((size_t)N_NODES * 4 * 4);
    float* ald    = (float*)alloc((size_t)N_NODES * 4 * 4);
    int*   cnt    = (int*)alloc((size_t)N_NODES * 4);
    int*   row_ptr= (int*)alloc((size_t)(N_NODES + 1) * 4);
    int*   cursor = (int*)alloc((size_t)N_NODES * 4);
    int*   col    = (int*)alloc((size_t)(E_EDGES + N_NODES) * 4);
    float* pooled = (float*)alloc((size_t)B_GR * 64 * 4);

    const int* srcs = ei;
    const int* dsts = ei + E_EDGES;

    // CSR by dst (graph static within call; reused by all 3 layers)
    init_cnt<<<(N_NODES + 255) / 256, 256, 0, stream>>>(cnt);
    hist_kernel<<<(E_EDGES + 255) / 256, 256, 0, stream>>>(dsts, cnt);
    scan_kernel<<<1, 1024, 0, stream>>>(cnt, row_ptr, cursor);
    scatter_kernel<<<(E_EDGES + N_NODES + 255) / 256, 256, 0, stream>>>(srcs, dsts, cursor, col);

    dim3 ggrid((N_NODES + 63) / 64, 2);
    int nblk = (N_NODES + 3) / 4;

    // layer 0
    gemm_kernel<128><<<ggrid, 256, 0, stream>>>(x, W0, h, N_NODES);
    al_kernel<<<nblk, 256, 0, stream>>>(h, as0, ad0, als, ald);
    agg_kernel<<<nblk, 256, 0, stream>>>(h, als, ald, row_ptr, col, b0, act, 0);
    // layer 1
    gemm_kernel<256><<<ggrid, 256, 0, stream>>>(act, W1, h, N_NODES);
    al_kernel<<<nblk, 256, 0, stream>>>(h, as1, ad1, als, ald);
    agg_kernel<<<nblk, 256, 0, stream>>>(h, als, ald, row_ptr, col, b1, act, 0);
    // layer 2 (mean heads, no ELU)
    gemm_kernel<256><<<ggrid, 256, 0, stream>>>(act, W2, h, N_NODES);
    al_kernel<<<nblk, 256, 0, stream>>>(h, as2, ad2, als, ald);
    agg_kernel<<<nblk, 256, 0, stream>>>(h, als, ald, row_ptr, col, b2, act, 1);

    pool_kernel<<<B_GR, 64, 0, stream>>>(act, batch, pooled);
    mlp_kernel<<<B_GR, 64, 0, stream>>>(pooled, pW1, pb1, pW2, pb2, out);
}

// Round 2
// 873.979 us; speedup vs baseline: 1.2266x; 1.2266x over previous
//
#include <hip/hip_runtime.h>
#include <cstdint>

#define N_NODES 50000
#define E_EDGES 800000
#define HC 256           // H*C
#define B_GR 64
#define OUT_DIM 10
#define SLOPE 0.2f

// ---------------- GEMM: C[M x 256] = A[M x K] * W[K x 256] (fp32) -------------
template<int K>
__global__ __launch_bounds__(256) void gemm_kernel(const float* __restrict__ A,
                                                   const float* __restrict__ W,
                                                   float* __restrict__ C, int M) {
    const int BM = 64, BN = 128, BK = 16;
    __shared__ float As[BK][BM];   // transposed tile
    __shared__ float Bs[BK][BN];
    int tid = threadIdx.x;
    int row0 = blockIdx.x * BM;
    int col0 = blockIdx.y * BN;
    int tx = tid & 15;    // 16 col-groups of 8
    int ty = tid >> 4;    // 16 row-groups of 4
    float acc[4][8] = {};
    int am = tid >> 2;           // row in tile 0..63
    int ak = (tid & 3) * 4;      // k offset 0/4/8/12
    for (int k0 = 0; k0 < K; k0 += BK) {
        float4 av = make_float4(0.f, 0.f, 0.f, 0.f);
        int gr = row0 + am;
        if (gr < M) av = *(const float4*)&A[(size_t)gr * K + k0 + ak];
        As[ak + 0][am] = av.x; As[ak + 1][am] = av.y;
        As[ak + 2][am] = av.z; As[ak + 3][am] = av.w;
#pragma unroll
        for (int i = 0; i < 2; ++i) {
            int idx = tid + i * 256;      // 0..511
            int bk = idx >> 5;            // 0..15
            int bn = (idx & 31) * 4;
            *(float4*)&Bs[bk][bn] = *(const float4*)&W[(size_t)(k0 + bk) * HC + col0 + bn];
        }
        __syncthreads();
#pragma unroll
        for (int kk = 0; kk < BK; ++kk) {
            float4 a4 = *(const float4*)&As[kk][ty * 4];
            float4 b0 = *(const float4*)&Bs[kk][tx * 8];
            float4 b1 = *(const float4*)&Bs[kk][tx * 8 + 4];
            float a_[4] = {a4.x, a4.y, a4.z, a4.w};
            float b_[8] = {b0.x, b0.y, b0.z, b0.w, b1.x, b1.y, b1.z, b1.w};
#pragma unroll
            for (int r = 0; r < 4; ++r)
#pragma unroll
                for (int c = 0; c < 8; ++c)
                    acc[r][c] = fmaf(a_[r], b_[c], acc[r][c]);
        }
        __syncthreads();
    }
#pragma unroll
    for (int r = 0; r < 4; ++r) {
        int gr = row0 + ty * 4 + r;
        if (gr < M) {
            float4 o0 = make_float4(acc[r][0], acc[r][1], acc[r][2], acc[r][3]);
            float4 o1 = make_float4(acc[r][4], acc[r][5], acc[r][6], acc[r][7]);
            *(float4*)&C[(size_t)gr * HC + col0 + tx * 8]     = o0;
            *(float4*)&C[(size_t)gr * HC + col0 + tx * 8 + 4] = o1;
        }
    }
}

// ---------------- per-node attention logits al_s/al_d ------------------------
__global__ __launch_bounds__(256) void al_kernel(const float* __restrict__ h,
        const float* __restrict__ a_src, const float* __restrict__ a_dst,
        float* __restrict__ al_s, float* __restrict__ al_d) {
    int node = blockIdx.x * 4 + (threadIdx.x >> 6);
    int lane = threadIdx.x & 63;
    if (node >= N_NODES) return;
    float4 hv = *(const float4*)&h[(size_t)node * HC + lane * 4];
    float4 s4 = *(const float4*)&a_src[lane * 4];
    float4 d4 = *(const float4*)&a_dst[lane * 4];
    float ps = hv.x * s4.x + hv.y * s4.y + hv.z * s4.z + hv.w * s4.w;
    float pd = hv.x * d4.x + hv.y * d4.y + hv.z * d4.z + hv.w * d4.w;
#pragma unroll
    for (int off = 1; off < 16; off <<= 1) {
        ps += __shfl_xor(ps, off, 64);
        pd += __shfl_xor(pd, off, 64);
    }
    if ((lane & 15) == 0) {
        int head = lane >> 4;
        al_s[node * 4 + head] = ps;
        al_d[node * 4 + head] = pd;
    }
}

// ---------------- CSR build (counting sort by dst) ---------------------------
__global__ void init_cnt(int* cnt) {
    int i = blockIdx.x * blockDim.x + threadIdx.x;
    if (i < N_NODES) cnt[i] = 1;   // self-loop pre-counted
}
__global__ void hist_kernel(const int* __restrict__ dsts, int* cnt) {
    int i = blockIdx.x * blockDim.x + threadIdx.x;
    if (i < E_EDGES) atomicAdd(&cnt[dsts[i]], 1);
}
__global__ __launch_bounds__(1024) void scan_kernel(const int* __restrict__ cnt,
                                                    int* row_ptr, int* cursor) {
    __shared__ int sums[1024];
    int t = threadIdx.x;
    const int CH = (N_NODES + 1023) / 1024;  // 49
    int lo = t * CH, hi = min(lo + CH, N_NODES);
    int s = 0;
    for (int i = lo; i < hi; ++i) s += cnt[i];
    sums[t] = s;
    __syncthreads();
    for (int off = 1; off < 1024; off <<= 1) {
        int v = (t >= off) ? sums[t - off] : 0;
        __syncthreads();
        sums[t] += v;
        __syncthreads();
    }
    int run = (t == 0) ? 0 : sums[t - 1];
    for (int i = lo; i < hi; ++i) {
        row_ptr[i] = run; cursor[i] = run;
        run += cnt[i];
    }
    if (t == 1023) row_ptr[N_NODES] = run;
}
__global__ void scatter_kernel(const int* __restrict__ srcs, const int* __restrict__ dsts,
                               int* cursor, int* col) {
    int i = blockIdx.x * blockDim.x + threadIdx.x;
    if (i >= E_EDGES + N_NODES) return;
    int s, d;
    if (i < E_EDGES) { s = srcs[i]; d = dsts[i]; }
    else             { s = d = i - E_EDGES; }     // self loops
    int pos = atomicAdd(&cursor[d], 1);
    col[pos] = s;
}

// ---------------- per-node softmax + aggregation -----------------------------
// mode 0: concat heads, +bias[256], ELU.   mode 1: mean heads, +bias[64], no ELU.
__global__ __launch_bounds__(256) void agg_kernel(const float* __restrict__ h,
        const float* __restrict__ al_s, const float* __restrict__ al_d,
        const int* __restrict__ row_ptr, const int* __restrict__ col,
        const float* __restrict__ bias, float* __restrict__ out, int mode) {
    int node = blockIdx.x * 4 + (threadIdx.x >> 6);
    int lane = threadIdx.x & 63;
    if (node >= N_NODES) return;
    int start = row_ptr[node], end = row_ptr[node + 1];
    const float4 ald = *(const float4*)&al_d[node * 4];

    // pass 1: per-head max of leaky_relu(al_s[src]+al_d[node])
    float m0 = -1e30f, m1 = -1e30f, m2 = -1e30f, m3 = -1e30f;
    for (int j = start + lane; j < end; j += 64) {
        int s = col[j];
        float4 as = *(const float4*)&al_s[s * 4];
        float e0 = as.x + ald.x; e0 = e0 > 0.f ? e0 : SLOPE * e0;
        float e1 = as.y + ald.y; e1 = e1 > 0.f ? e1 : SLOPE * e1;
        float e2 = as.z + ald.z; e2 = e2 > 0.f ? e2 : SLOPE * e2;
        float e3 = as.w + ald.w; e3 = e3 > 0.f ? e3 : SLOPE * e3;
        m0 = fmaxf(m0, e0); m1 = fmaxf(m1, e1);
        m2 = fmaxf(m2, e2); m3 = fmaxf(m3, e3);
    }
#pragma unroll
    for (int off = 1; off < 64; off <<= 1) {
        m0 = fmaxf(m0, __shfl_xor(m0, off, 64));
        m1 = fmaxf(m1, __shfl_xor(m1, off, 64));
        m2 = fmaxf(m2, __shfl_xor(m2, off, 64));
        m3 = fmaxf(m3, __shfl_xor(m3, off, 64));
    }
    // pass 2: per-head denominator
    float d0 = 0.f, d1 = 0.f, d2 = 0.f, d3 = 0.f;
    for (int j = start + lane; j < end; j += 64) {
        int s = col[j];
        float4 as = *(const float4*)&al_s[s * 4];
        float e0 = as.x + ald.x; e0 = e0 > 0.f ? e0 : SLOPE * e0;
        float e1 = as.y + ald.y; e1 = e1 > 0.f ? e1 : SLOPE * e1;
        float e2 = as.z + ald.z; e2 = e2 > 0.f ? e2 : SLOPE * e2;
        float e3 = as.w + ald.w; e3 = e3 > 0.f ? e3 : SLOPE * e3;
        d0 += expf(e0 - m0); d1 += expf(e1 - m1);
        d2 += expf(e2 - m2); d3 += expf(e3 - m3);
    }
#pragma unroll
    for (int off = 1; off < 64; off <<= 1) {
        d0 += __shfl_xor(d0, off, 64);
        d1 += __shfl_xor(d1, off, 64);
        d2 += __shfl_xor(d2, off, 64);
        d3 += __shfl_xor(d3, off, 64);
    }
    float inv0 = 1.f / (d0 + 1e-16f), inv1 = 1.f / (d1 + 1e-16f);
    float inv2 = 1.f / (d2 + 1e-16f), inv3 = 1.f / (d3 + 1e-16f);

    // per-lane head constants (lane covers channels 4*lane..4*lane+3, head = lane/16)
    int head = lane >> 4;
    float ald_h = head == 0 ? ald.x : head == 1 ? ald.y : head == 2 ? ald.z : ald.w;
    float m_h   = head == 0 ? m0    : head == 1 ? m1    : head == 2 ? m2    : m3;
    float inv_h = head == 0 ? inv0  : head == 1 ? inv1  : head == 2 ? inv2  : inv3;

    // pass 3: weighted aggregation of h[src]
    float ax = 0.f, ay = 0.f, az = 0.f, aw = 0.f;
    for (int jb = start; jb < end; jb += 64) {
        int j = jb + lane;
        int cs = (j < end) ? col[j] : 0;
        int cnt = min(64, end - jb);
        for (int t = 0; t < cnt; ++t) {
            int s = __shfl(cs, t, 64);
            float als = al_s[s * 4 + head];
            float e = als + ald_h; e = e > 0.f ? e : SLOPE * e;
            float w = expf(e - m_h) * inv_h;
            float4 hv = *(const float4*)&h[(size_t)s * HC + lane * 4];
            ax = fmaf(w, hv.x, ax); ay = fmaf(w, hv.y, ay);
            az = fmaf(w, hv.z, az); aw = fmaf(w, hv.w, aw);
        }
    }
    if (mode == 0) {
        float4 b4 = *(const float4*)&bias[lane * 4];
        float vx = ax + b4.x; vx = vx > 0.f ? vx : expm1f(vx);
        float vy = ay + b4.y; vy = vy > 0.f ? vy : expm1f(vy);
        float vz = az + b4.z; vz = vz > 0.f ? vz : expm1f(vz);
        float vw = aw + b4.w; vw = vw > 0.f ? vw : expm1f(vw);
        float4 v = make_float4(vx, vy, vz, vw);
        *(float4*)&out[(size_t)node * HC + lane * 4] = v;
    } else {
        // mean over heads: sum lanes lane^16, lane^32
#pragma unroll
        for (int off = 16; off < 64; off <<= 1) {
            ax += __shfl_xor(ax, off, 64);
            ay += __shfl_xor(ay, off, 64);
            az += __shfl_xor(az, off, 64);
            aw += __shfl_xor(aw, off, 64);
        }
        if (lane < 16) {
            float4 b4 = *(const float4*)&bias[lane * 4];
            float4 v = make_float4(ax * 0.25f + b4.x, ay * 0.25f + b4.y,
                                   az * 0.25f + b4.z, aw * 0.25f + b4.w);
            *(float4*)&out[(size_t)node * 64 + lane * 4] = v;
        }
    }
}

// ---------------- pooling + MLP ----------------------------------------------
__global__ void pool_zero(float* __restrict__ pooled) {
    int i = blockIdx.x * blockDim.x + threadIdx.x;
    if (i < B_GR * 64) pooled[i] = 0.f;
}

// grid (B_GR, 16) x 256 threads: 64 waves per graph, stride-64 node slices,
// coalesced 256B row reads, one atomicAdd per channel per wave.
__global__ __launch_bounds__(256) void pool_kernel(const float* __restrict__ act,
        const int* __restrict__ batch, float* __restrict__ pooled) {
    int b = blockIdx.x;
    int chunk = blockIdx.y;          // 0..15
    int warp = threadIdx.x >> 6;     // 0..3
    int lane = threadIdx.x & 63;
    int lo = 0, hi = N_NODES;
    while (lo < hi) { int mid = (lo + hi) >> 1; if (batch[mid] < b) lo = mid + 1; else hi = mid; }
    int s = lo;
    lo = 0; hi = N_NODES;
    while (lo < hi) { int mid = (lo + hi) >> 1; if (batch[mid] < b + 1) lo = mid + 1; else hi = mid; }
    int e = lo;
    float sum = 0.f;
    for (int n = s + chunk * 4 + warp; n < e; n += 64)
        sum += act[(size_t)n * 64 + lane];
    if (sum != 0.f || true) atomicAdd(&pooled[b * 64 + lane], sum);
}

__global__ __launch_bounds__(64) void mlp_kernel(const float* __restrict__ pooled,
        const int* __restrict__ batch,
        const float* __restrict__ pW1, const float* __restrict__ pb1,
        const float* __restrict__ pW2, const float* __restrict__ pb2,
        float* __restrict__ outp) {
    __shared__ float p[64];
    __shared__ float z[32];
    int b = blockIdx.x, t = threadIdx.x;
    int lo = 0, hi = N_NODES;
    while (lo < hi) { int mid = (lo + hi) >> 1; if (batch[mid] < b) lo = mid + 1; else hi = mid; }
    int s = lo;
    lo = 0; hi = N_NODES;
    while (lo < hi) { int mid = (lo + hi) >> 1; if (batch[mid] < b + 1) lo = mid + 1; else hi = mid; }
    int e = lo;
    float inv = 1.f / (float)max(e - s, 1);
    p[t] = pooled[b * 64 + t] * inv;
    __syncthreads();
    if (t < 32) {
        float s2 = pb1[t];
        for (int c = 0; c < 64; ++c) s2 += p[c] * pW1[c * 32 + t];
        z[t] = s2 > 0.f ? s2 : 0.f;
    }
    __syncthreads();
    if (t < OUT_DIM) {
        float s2 = pb2[t];
        for (int k = 0; k < 32; ++k) s2 += z[k] * pW2[k * 10 + t];
        outp[b * 10 + t] = s2;
    }
}

// ---------------- launch ------------------------------------------------------
extern "C" void kernel_launch(void* const* d_in, const int* in_sizes, int n_in,
                              void* d_out, int out_size, void* d_ws, size_t ws_size,
                              hipStream_t stream) {
    const float* x    = (const float*)d_in[0];
    const int*   ei   = (const int*)d_in[1];
    const int*   batch= (const int*)d_in[2];
    const float* W0   = (const float*)d_in[3];
    const float* b0   = (const float*)d_in[4];
    const float* as0  = (const float*)d_in[5];
    const float* ad0  = (const float*)d_in[6];
    const float* W1   = (const float*)d_in[7];
    const float* b1   = (const float*)d_in[8];
    const float* as1  = (const float*)d_in[9];
    const float* ad1  = (const float*)d_in[10];
    const float* W2   = (const float*)d_in[11];
    const float* b2   = (const float*)d_in[12];
    const float* as2  = (const float*)d_in[13];
    const float* ad2  = (const float*)d_in[14];
    const float* pW1  = (const float*)d_in[15];
    const float* pb1  = (const float*)d_in[16];
    const float* pW2  = (const float*)d_in[17];
    const float* pb2  = (const float*)d_in[18];
    float* out = (float*)d_out;

    char* ws = (char*)d_ws;
    size_t off = 0;
    auto alloc = [&](size_t bytes) -> void* {
        void* p = ws + off;
        off += (bytes + 255) & ~(size_t)255;
        return p;
    };
    float* h      = (float*)alloc((size_t)N_NODES * HC * 4);
    float* act    = (float*)alloc((size_t)N_NODES * HC * 4);
    float* als    = (float*)alloc((size_t)N_NODES * 4 * 4);
    float* ald    = (float*)alloc((size_t)N_NODES * 4 * 4);
    int*   cnt    = (int*)alloc((size_t)N_NODES * 4);
    int*   row_ptr= (int*)alloc((size_t)(N_NODES + 1) * 4);
    int*   cursor = (int*)alloc((size_t)N_NODES * 4);
    int*   col    = (int*)alloc((size_t)(E_EDGES + N_NODES) * 4);
    float* pooled = (float*)alloc((size_t)B_GR * 64 * 4);

    const int* srcs = ei;
    const int* dsts = ei + E_EDGES;

    // CSR by dst (graph static within call; reused by all 3 layers)
    init_cnt<<<(N_NODES + 255) / 256, 256, 0, stream>>>(cnt);
    hist_kernel<<<(E_EDGES + 255) / 256, 256, 0, stream>>>(dsts, cnt);
    scan_kernel<<<1, 1024, 0, stream>>>(cnt, row_ptr, cursor);
    scatter_kernel<<<(E_EDGES + N_NODES + 255) / 256, 256, 0, stream>>>(srcs, dsts, cursor, col);

    dim3 ggrid((N_NODES + 63) / 64, 2);
    int nblk = (N_NODES + 3) / 4;

    // layer 0
    gemm_kernel<128><<<ggrid, 256, 0, stream>>>(x, W0, h, N_NODES);
    al_kernel<<<nblk, 256, 0, stream>>>(h, as0, ad0, als, ald);
    agg_kernel<<<nblk, 256, 0, stream>>>(h, als, ald, row_ptr, col, b0, act, 0);
    // layer 1
    gemm_kernel<256><<<ggrid, 256, 0, stream>>>(act, W1, h, N_NODES);
    al_kernel<<<nblk, 256, 0, stream>>>(h, as1, ad1, als, ald);
    agg_kernel<<<nblk, 256, 0, stream>>>(h, als, ald, row_ptr, col, b1, act, 0);
    // layer 2 (mean heads, no ELU)
    gemm_kernel<256><<<ggrid, 256, 0, stream>>>(act, W2, h, N_NODES);
    al_kernel<<<nblk, 256, 0, stream>>>(h, as2, ad2, als, ald);
    agg_kernel<<<nblk, 256, 0, stream>>>(h, als, ald, row_ptr, col, b2, act, 1);

    pool_zero<<<(B_GR * 64 + 255) / 256, 256, 0, stream>>>(pooled);
    dim3 pgrid(B_GR, 16);
    pool_kernel<<<pgrid, 256, 0, stream>>>(act, batch, pooled);
    mlp_kernel<<<B_GR, 64, 0, stream>>>(pooled, batch, pW1, pb1, pW2, pb2, out);
}

// Round 3
// 870.482 us; speedup vs baseline: 1.2316x; 1.0040x over previous
//
#include <hip/hip_runtime.h>
#include <cstdint>

#define N_NODES 50000
#define E_EDGES 800000
#define HC 256           // H*C
#define B_GR 64
#define OUT_DIM 10
#define SLOPE 0.2f

// ---------------- GEMM: C[M x 256] = A[M x K] * W[K x 256] (fp32) -------------
template<int K>
__global__ __launch_bounds__(256) void gemm_kernel(const float* __restrict__ A,
                                                   const float* __restrict__ W,
                                                   float* __restrict__ C, int M) {
    const int BM = 64, BN = 128, BK = 16;
    __shared__ float As[BK][BM];   // transposed tile
    __shared__ float Bs[BK][BN];
    int tid = threadIdx.x;
    int row0 = blockIdx.x * BM;
    int col0 = blockIdx.y * BN;
    int tx = tid & 15;    // 16 col-groups of 8
    int ty = tid >> 4;    // 16 row-groups of 4
    float acc[4][8] = {};
    int am = tid >> 2;           // row in tile 0..63
    int ak = (tid & 3) * 4;      // k offset 0/4/8/12
    for (int k0 = 0; k0 < K; k0 += BK) {
        float4 av = make_float4(0.f, 0.f, 0.f, 0.f);
        int gr = row0 + am;
        if (gr < M) av = *(const float4*)&A[(size_t)gr * K + k0 + ak];
        As[ak + 0][am] = av.x; As[ak + 1][am] = av.y;
        As[ak + 2][am] = av.z; As[ak + 3][am] = av.w;
#pragma unroll
        for (int i = 0; i < 2; ++i) {
            int idx = tid + i * 256;      // 0..511
            int bk = idx >> 5;            // 0..15
            int bn = (idx & 31) * 4;
            *(float4*)&Bs[bk][bn] = *(const float4*)&W[(size_t)(k0 + bk) * HC + col0 + bn];
        }
        __syncthreads();
#pragma unroll
        for (int kk = 0; kk < BK; ++kk) {
            float4 a4 = *(const float4*)&As[kk][ty * 4];
            float4 b0 = *(const float4*)&Bs[kk][tx * 8];
            float4 b1 = *(const float4*)&Bs[kk][tx * 8 + 4];
            float a_[4] = {a4.x, a4.y, a4.z, a4.w};
            float b_[8] = {b0.x, b0.y, b0.z, b0.w, b1.x, b1.y, b1.z, b1.w};
#pragma unroll
            for (int r = 0; r < 4; ++r)
#pragma unroll
                for (int c = 0; c < 8; ++c)
                    acc[r][c] = fmaf(a_[r], b_[c], acc[r][c]);
        }
        __syncthreads();
    }
#pragma unroll
    for (int r = 0; r < 4; ++r) {
        int gr = row0 + ty * 4 + r;
        if (gr < M) {
            float4 o0 = make_float4(acc[r][0], acc[r][1], acc[r][2], acc[r][3]);
            float4 o1 = make_float4(acc[r][4], acc[r][5], acc[r][6], acc[r][7]);
            *(float4*)&C[(size_t)gr * HC + col0 + tx * 8]     = o0;
            *(float4*)&C[(size_t)gr * HC + col0 + tx * 8 + 4] = o1;
        }
    }
}

// ---------------- per-node attention logits al_s/al_d ------------------------
__global__ __launch_bounds__(256) void al_kernel(const float* __restrict__ h,
        const float* __restrict__ a_src, const float* __restrict__ a_dst,
        float* __restrict__ al_s, float* __restrict__ al_d) {
    int node = blockIdx.x * 4 + (threadIdx.x >> 6);
    int lane = threadIdx.x & 63;
    if (node >= N_NODES) return;
    float4 hv = *(const float4*)&h[(size_t)node * HC + lane * 4];
    float4 s4 = *(const float4*)&a_src[lane * 4];
    float4 d4 = *(const float4*)&a_dst[lane * 4];
    float ps = hv.x * s4.x + hv.y * s4.y + hv.z * s4.z + hv.w * s4.w;
    float pd = hv.x * d4.x + hv.y * d4.y + hv.z * d4.z + hv.w * d4.w;
#pragma unroll
    for (int off = 1; off < 16; off <<= 1) {
        ps += __shfl_xor(ps, off, 64);
        pd += __shfl_xor(pd, off, 64);
    }
    if ((lane & 15) == 0) {
        int head = lane >> 4;
        al_s[node * 4 + head] = ps;
        al_d[node * 4 + head] = pd;
    }
}

// ---------------- CSR build (counting sort by dst) ---------------------------
__global__ void init_cnt(int* cnt) {
    int i = blockIdx.x * blockDim.x + threadIdx.x;
    if (i < N_NODES) cnt[i] = 1;   // self-loop pre-counted
}
__global__ void hist_kernel(const int* __restrict__ dsts, int* cnt) {
    int i = blockIdx.x * blockDim.x + threadIdx.x;
    if (i < E_EDGES) atomicAdd(&cnt[dsts[i]], 1);
}
__global__ __launch_bounds__(1024) void scan_kernel(const int* __restrict__ cnt,
                                                    int* row_ptr, int* cursor) {
    __shared__ int sums[1024];
    int t = threadIdx.x;
    const int CH = (N_NODES + 1023) / 1024;  // 49
    int lo = t * CH, hi = min(lo + CH, N_NODES);
    int s = 0;
    for (int i = lo; i < hi; ++i) s += cnt[i];
    sums[t] = s;
    __syncthreads();
    for (int off = 1; off < 1024; off <<= 1) {
        int v = (t >= off) ? sums[t - off] : 0;
        __syncthreads();
        sums[t] += v;
        __syncthreads();
    }
    int run = (t == 0) ? 0 : sums[t - 1];
    for (int i = lo; i < hi; ++i) {
        row_ptr[i] = run; cursor[i] = run;
        run += cnt[i];
    }
    if (t == 1023) row_ptr[N_NODES] = run;
}
__global__ void scatter_kernel(const int* __restrict__ srcs, const int* __restrict__ dsts,
                               int* cursor, int* col) {
    int i = blockIdx.x * blockDim.x + threadIdx.x;
    if (i >= E_EDGES + N_NODES) return;
    int s, d;
    if (i < E_EDGES) { s = srcs[i]; d = dsts[i]; }
    else             { s = d = i - E_EDGES; }     // self loops
    int pos = atomicAdd(&cursor[d], 1);
    col[pos] = s;
}

// ---------------- per-node softmax + aggregation -----------------------------
// mode 0: concat heads, +bias[256], ELU.   mode 1: mean heads, +bias[64], no ELU.
// Fast path (deg<=64): one al_s gather, alpha staged in LDS, 8-deep pipelined
// row gather. Fallback (deg>64): 3-pass streaming (rare/never for this graph).
__global__ __launch_bounds__(256) void agg_kernel(const float* __restrict__ h,
        const float* __restrict__ al_s, const float* __restrict__ al_d,
        const int* __restrict__ row_ptr, const int* __restrict__ col,
        const float* __restrict__ bias, float* __restrict__ out, int mode) {
    __shared__ int   lds_col[4][64];
    __shared__ float lds_alpha[4][64 * 4];
    int wid  = threadIdx.x >> 6;
    int node = blockIdx.x * 4 + wid;
    int lane = threadIdx.x & 63;
    if (node >= N_NODES) return;
    int start = row_ptr[node], end = row_ptr[node + 1];
    int deg = end - start;
    const float4 ald = *(const float4*)&al_d[node * 4];
    int head = lane >> 4;
    float ald_h = head == 0 ? ald.x : head == 1 ? ald.y : head == 2 ? ald.z : ald.w;

    float ax = 0.f, ay = 0.f, az = 0.f, aw = 0.f;

    if (deg <= 64) {
        // ---- single-gather softmax ----
        int j = start + lane;
        bool active = j < end;
        int s = active ? col[j] : 0;
        float4 as = *(const float4*)&al_s[s * 4];
        float e0 = as.x + ald.x; e0 = e0 > 0.f ? e0 : SLOPE * e0;
        float e1 = as.y + ald.y; e1 = e1 > 0.f ? e1 : SLOPE * e1;
        float e2 = as.z + ald.z; e2 = e2 > 0.f ? e2 : SLOPE * e2;
        float e3 = as.w + ald.w; e3 = e3 > 0.f ? e3 : SLOPE * e3;
        float m0 = active ? e0 : -1e30f, m1 = active ? e1 : -1e30f;
        float m2 = active ? e2 : -1e30f, m3 = active ? e3 : -1e30f;
#pragma unroll
        for (int off = 1; off < 64; off <<= 1) {
            m0 = fmaxf(m0, __shfl_xor(m0, off, 64));
            m1 = fmaxf(m1, __shfl_xor(m1, off, 64));
            m2 = fmaxf(m2, __shfl_xor(m2, off, 64));
            m3 = fmaxf(m3, __shfl_xor(m3, off, 64));
        }
        float x0 = active ? expf(e0 - m0) : 0.f;
        float x1 = active ? expf(e1 - m1) : 0.f;
        float x2 = active ? expf(e2 - m2) : 0.f;
        float x3 = active ? expf(e3 - m3) : 0.f;
        float d0 = x0, d1 = x1, d2 = x2, d3 = x3;
#pragma unroll
        for (int off = 1; off < 64; off <<= 1) {
            d0 += __shfl_xor(d0, off, 64);
            d1 += __shfl_xor(d1, off, 64);
            d2 += __shfl_xor(d2, off, 64);
            d3 += __shfl_xor(d3, off, 64);
        }
        float4 a4;
        a4.x = x0 / (d0 + 1e-16f); a4.y = x1 / (d1 + 1e-16f);
        a4.z = x2 / (d2 + 1e-16f); a4.w = x3 / (d3 + 1e-16f);
        lds_col[wid][lane] = s;
        *(float4*)&lds_alpha[wid][lane * 4] = a4;
        // same-wave LDS write->read: compiler-inserted lgkmcnt suffices
        const int*   lc = lds_col[wid];
        const float* la = lds_alpha[wid];
        // ---- 8-deep pipelined gather ----
        for (int t0 = 0; t0 < deg; t0 += 8) {
            int nn = deg - t0;   // >= 1
            float w[8]; float4 hv[8];
#pragma unroll
            for (int k = 0; k < 8; ++k) {
                if (k < nn) {
                    int s2 = lc[t0 + k];
                    w[k] = la[(t0 + k) * 4 + head];
                    hv[k] = *(const float4*)&h[(size_t)s2 * HC + lane * 4];
                } else {
                    w[k] = 0.f;
                    hv[k] = make_float4(0.f, 0.f, 0.f, 0.f);
                }
            }
#pragma unroll
            for (int k = 0; k < 8; ++k) {
                ax = fmaf(w[k], hv[k].x, ax); ay = fmaf(w[k], hv[k].y, ay);
                az = fmaf(w[k], hv[k].z, az); aw = fmaf(w[k], hv[k].w, aw);
            }
        }
    } else {
        // ---- fallback: 3-pass streaming (deg > 64) ----
        float m0 = -1e30f, m1 = -1e30f, m2 = -1e30f, m3 = -1e30f;
        for (int j = start + lane; j < end; j += 64) {
            int s = col[j];
            float4 as = *(const float4*)&al_s[s * 4];
            float e0 = as.x + ald.x; e0 = e0 > 0.f ? e0 : SLOPE * e0;
            float e1 = as.y + ald.y; e1 = e1 > 0.f ? e1 : SLOPE * e1;
            float e2 = as.z + ald.z; e2 = e2 > 0.f ? e2 : SLOPE * e2;
            float e3 = as.w + ald.w; e3 = e3 > 0.f ? e3 : SLOPE * e3;
            m0 = fmaxf(m0, e0); m1 = fmaxf(m1, e1);
            m2 = fmaxf(m2, e2); m3 = fmaxf(m3, e3);
        }
#pragma unroll
        for (int off = 1; off < 64; off <<= 1) {
            m0 = fmaxf(m0, __shfl_xor(m0, off, 64));
            m1 = fmaxf(m1, __shfl_xor(m1, off, 64));
            m2 = fmaxf(m2, __shfl_xor(m2, off, 64));
            m3 = fmaxf(m3, __shfl_xor(m3, off, 64));
        }
        float d0 = 0.f, d1 = 0.f, d2 = 0.f, d3 = 0.f;
        for (int j = start + lane; j < end; j += 64) {
            int s = col[j];
            float4 as = *(const float4*)&al_s[s * 4];
            float e0 = as.x + ald.x; e0 = e0 > 0.f ? e0 : SLOPE * e0;
            float e1 = as.y + ald.y; e1 = e1 > 0.f ? e1 : SLOPE * e1;
            float e2 = as.z + ald.z; e2 = e2 > 0.f ? e2 : SLOPE * e2;
            float e3 = as.w + ald.w; e3 = e3 > 0.f ? e3 : SLOPE * e3;
            d0 += expf(e0 - m0); d1 += expf(e1 - m1);
            d2 += expf(e2 - m2); d3 += expf(e3 - m3);
        }
#pragma unroll
        for (int off = 1; off < 64; off <<= 1) {
            d0 += __shfl_xor(d0, off, 64);
            d1 += __shfl_xor(d1, off, 64);
            d2 += __shfl_xor(d2, off, 64);
            d3 += __shfl_xor(d3, off, 64);
        }
        float inv0 = 1.f / (d0 + 1e-16f), inv1 = 1.f / (d1 + 1e-16f);
        float inv2 = 1.f / (d2 + 1e-16f), inv3 = 1.f / (d3 + 1e-16f);
        float m_h   = head == 0 ? m0   : head == 1 ? m1   : head == 2 ? m2   : m3;
        float inv_h = head == 0 ? inv0 : head == 1 ? inv1 : head == 2 ? inv2 : inv3;
        for (int jb = start; jb < end; jb += 64) {
            int j = jb + lane;
            int cs = (j < end) ? col[j] : 0;
            int cnt = min(64, end - jb);
            for (int t = 0; t < cnt; ++t) {
                int s = __shfl(cs, t, 64);
                float als = al_s[s * 4 + head];
                float e = als + ald_h; e = e > 0.f ? e : SLOPE * e;
                float w = expf(e - m_h) * inv_h;
                float4 hv = *(const float4*)&h[(size_t)s * HC + lane * 4];
                ax = fmaf(w, hv.x, ax); ay = fmaf(w, hv.y, ay);
                az = fmaf(w, hv.z, az); aw = fmaf(w, hv.w, aw);
            }
        }
    }

    if (mode == 0) {
        float4 b4 = *(const float4*)&bias[lane * 4];
        float vx = ax + b4.x; vx = vx > 0.f ? vx : expm1f(vx);
        float vy = ay + b4.y; vy = vy > 0.f ? vy : expm1f(vy);
        float vz = az + b4.z; vz = vz > 0.f ? vz : expm1f(vz);
        float vw = aw + b4.w; vw = vw > 0.f ? vw : expm1f(vw);
        float4 v = make_float4(vx, vy, vz, vw);
        *(float4*)&out[(size_t)node * HC + lane * 4] = v;
    } else {
        // mean over heads: sum lanes lane^16, lane^32
#pragma unroll
        for (int off = 16; off < 64; off <<= 1) {
            ax += __shfl_xor(ax, off, 64);
            ay += __shfl_xor(ay, off, 64);
            az += __shfl_xor(az, off, 64);
            aw += __shfl_xor(aw, off, 64);
        }
        if (lane < 16) {
            float4 b4 = *(const float4*)&bias[lane * 4];
            float4 v = make_float4(ax * 0.25f + b4.x, ay * 0.25f + b4.y,
                                   az * 0.25f + b4.z, aw * 0.25f + b4.w);
            *(float4*)&out[(size_t)node * 64 + lane * 4] = v;
        }
    }
}

// ---------------- pooling + MLP ----------------------------------------------
__global__ void pool_zero(float* __restrict__ pooled) {
    int i = blockIdx.x * blockDim.x + threadIdx.x;
    if (i < B_GR * 64) pooled[i] = 0.f;
}

// grid (B_GR, 16) x 256 threads: 64 waves per graph, stride-64 node slices,
// coalesced 256B row reads, one atomicAdd per channel per wave.
__global__ __launch_bounds__(256) void pool_kernel(const float* __restrict__ act,
        const int* __restrict__ batch, float* __restrict__ pooled) {
    int b = blockIdx.x;
    int chunk = blockIdx.y;          // 0..15
    int warp = threadIdx.x >> 6;     // 0..3
    int lane = threadIdx.x & 63;
    int lo = 0, hi = N_NODES;
    while (lo < hi) { int mid = (lo + hi) >> 1; if (batch[mid] < b) lo = mid + 1; else hi = mid; }
    int s = lo;
    lo = 0; hi = N_NODES;
    while (lo < hi) { int mid = (lo + hi) >> 1; if (batch[mid] < b + 1) lo = mid + 1; else hi = mid; }
    int e = lo;
    float sum = 0.f;
    for (int n = s + chunk * 4 + warp; n < e; n += 64)
        sum += act[(size_t)n * 64 + lane];
    atomicAdd(&pooled[b * 64 + lane], sum);
}

__global__ __launch_bounds__(64) void mlp_kernel(const float* __restrict__ pooled,
        const int* __restrict__ batch,
        const float* __restrict__ pW1, const float* __restrict__ pb1,
        const float* __restrict__ pW2, const float* __restrict__ pb2,
        float* __restrict__ outp) {
    __shared__ float p[64];
    __shared__ float z[32];
    int b = blockIdx.x, t = threadIdx.x;
    int lo = 0, hi = N_NODES;
    while (lo < hi) { int mid = (lo + hi) >> 1; if (batch[mid] < b) lo = mid + 1; else hi = mid; }
    int s = lo;
    lo = 0; hi = N_NODES;
    while (lo < hi) { int mid = (lo + hi) >> 1; if (batch[mid] < b + 1) lo = mid + 1; else hi = mid; }
    int e = lo;
    float inv = 1.f / (float)max(e - s, 1);
    p[t] = pooled[b * 64 + t] * inv;
    __syncthreads();
    if (t < 32) {
        float s2 = pb1[t];
        for (int c = 0; c < 64; ++c) s2 += p[c] * pW1[c * 32 + t];
        z[t] = s2 > 0.f ? s2 : 0.f;
    }
    __syncthreads();
    if (t < OUT_DIM) {
        float s2 = pb2[t];
        for (int k = 0; k < 32; ++k) s2 += z[k] * pW2[k * 10 + t];
        outp[b * 10 + t] = s2;
    }
}

// ---------------- launch ------------------------------------------------------
extern "C" void kernel_launch(void* const* d_in, const int* in_sizes, int n_in,
                              void* d_out, int out_size, void* d_ws, size_t ws_size,
                              hipStream_t stream) {
    const float* x    = (const float*)d_in[0];
    const int*   ei   = (const int*)d_in[1];
    const int*   batch= (const int*)d_in[2];
    const float* W0   = (const float*)d_in[3];
    const float* b0   = (const float*)d_in[4];
    const float* as0  = (const float*)d_in[5];
    const float* ad0  = (const float*)d_in[6];
    const float* W1   = (const float*)d_in[7];
    const float* b1   = (const float*)d_in[8];
    const float* as1  = (const float*)d_in[9];
    const float* ad1  = (const float*)d_in[10];
    const float* W2   = (const float*)d_in[11];
    const float* b2   = (const float*)d_in[12];
    const float* as2  = (const float*)d_in[13];
    const float* ad2  = (const float*)d_in[14];
    const float* pW1  = (const float*)d_in[15];
    const float* pb1  = (const float*)d_in[16];
    const float* pW2  = (const float*)d_in[17];
    const float* pb2  = (const float*)d_in[18];
    float* out = (float*)d_out;

    char* ws = (char*)d_ws;
    size_t off = 0;
    auto alloc = [&](size_t bytes) -> void* {
        void* p = ws + off;
        off += (bytes + 255) & ~(size_t)255;
        return p;
    };
    float* h      = (float*)alloc((size_t)N_NODES * HC * 4);
    float* act    = (float*)alloc((size_t)N_NODES * HC * 4);
    float* als    = (float*)alloc((size_t)N_NODES * 4 * 4);
    float* ald    = (float*)alloc((size_t)N_NODES * 4 * 4);
    int*   cnt    = (int*)alloc((size_t)N_NODES * 4);
    int*   row_ptr= (int*)alloc((size_t)(N_NODES + 1) * 4);
    int*   cursor = (int*)alloc((size_t)N_NODES * 4);
    int*   col    = (int*)alloc((size_t)(E_EDGES + N_NODES) * 4);
    float* pooled = (float*)alloc((size_t)B_GR * 64 * 4);

    const int* srcs = ei;
    const int* dsts = ei + E_EDGES;

    // CSR by dst (graph static within call; reused by all 3 layers)
    init_cnt<<<(N_NODES + 255) / 256, 256, 0, stream>>>(cnt);
    hist_kernel<<<(E_EDGES + 255) / 256, 256, 0, stream>>>(dsts, cnt);
    scan_kernel<<<1, 1024, 0, stream>>>(cnt, row_ptr, cursor);
    scatter_kernel<<<(E_EDGES + N_NODES + 255) / 256, 256, 0, stream>>>(srcs, dsts, cursor, col);

    dim3 ggrid((N_NODES + 63) / 64, 2);
    int nblk = (N_NODES + 3) / 4;

    // layer 0
    gemm_kernel<128><<<ggrid, 256, 0, stream>>>(x, W0, h, N_NODES);
    al_kernel<<<nblk, 256, 0, stream>>>(h, as0, ad0, als, ald);
    agg_kernel<<<nblk, 256, 0, stream>>>(h, als, ald, row_ptr, col, b0, act, 0);
    // layer 1
    gemm_kernel<256><<<ggrid, 256, 0, stream>>>(act, W1, h, N_NODES);
    al_kernel<<<nblk, 256, 0, stream>>>(h, as1, ad1, als, ald);
    agg_kernel<<<nblk, 256, 0, stream>>>(h, als, ald, row_ptr, col, b1, act, 0);
    // layer 2 (mean heads, no ELU)
    gemm_kernel<256><<<ggrid, 256, 0, stream>>>(act, W2, h, N_NODES);
    al_kernel<<<nblk, 256, 0, stream>>>(h, as2, ad2, als, ald);
    agg_kernel<<<nblk, 256, 0, stream>>>(h, als, ald, row_ptr, col, b2, act, 1);

    pool_zero<<<(B_GR * 64 + 255) / 256, 256, 0, stream>>>(pooled);
    dim3 pgrid(B_GR, 16);
    pool_kernel<<<pgrid, 256, 0, stream>>>(act, batch, pooled);
    mlp_kernel<<<B_GR, 64, 0, stream>>>(pooled, batch, pW1, pb1, pW2, pb2, out);
}

// Round 4
// 662.407 us; speedup vs baseline: 1.6184x; 1.3141x over previous
//
#include <hip/hip_runtime.h>
#include <hip/hip_fp16.h>
#include <cstdint>

#define N_NODES 50000
#define E_EDGES 800000
#define HC 256           // H*C
#define B_GR 64
#define OUT_DIM 10
#define SLOPE 0.2f

// ---------------- GEMM: h = A[M x K] * W[K x 256], fused epilogue -------------
// Writes h as fp16 (gather payload) and per-head attention logits al_s/al_d
// computed from the fp32 accumulators (BN=128 == 2 heads, block-complete dots).
template<int K>
__global__ __launch_bounds__(256) void gemm_kernel(const float* __restrict__ A,
        const float* __restrict__ W, __half* __restrict__ h_half,
        const float* __restrict__ a_src, const float* __restrict__ a_dst,
        float* __restrict__ al_s, float* __restrict__ al_d, int M) {
    const int BM = 64, BN = 128, BK = 16;
    __shared__ float As[BK][BM];   // transposed tile
    __shared__ float Bs[BK][BN];
    int tid = threadIdx.x;
    int row0 = blockIdx.x * BM;
    int col0 = blockIdx.y * BN;
    int tx = tid & 15;    // 16 col-groups of 8
    int ty = tid >> 4;    // 16 row-groups of 4
    float acc[4][8] = {};
    int am = tid >> 2;           // row in tile 0..63
    int ak = (tid & 3) * 4;      // k offset 0/4/8/12
    for (int k0 = 0; k0 < K; k0 += BK) {
        float4 av = make_float4(0.f, 0.f, 0.f, 0.f);
        int gr = row0 + am;
        if (gr < M) av = *(const float4*)&A[(size_t)gr * K + k0 + ak];
        As[ak + 0][am] = av.x; As[ak + 1][am] = av.y;
        As[ak + 2][am] = av.z; As[ak + 3][am] = av.w;
#pragma unroll
        for (int i = 0; i < 2; ++i) {
            int idx = tid + i * 256;      // 0..511
            int bk = idx >> 5;            // 0..15
            int bn = (idx & 31) * 4;
            *(float4*)&Bs[bk][bn] = *(const float4*)&W[(size_t)(k0 + bk) * HC + col0 + bn];
        }
        __syncthreads();
#pragma unroll
        for (int kk = 0; kk < BK; ++kk) {
            float4 a4 = *(const float4*)&As[kk][ty * 4];
            float4 b0 = *(const float4*)&Bs[kk][tx * 8];
            float4 b1 = *(const float4*)&Bs[kk][tx * 8 + 4];
            float a_[4] = {a4.x, a4.y, a4.z, a4.w};
            float b_[8] = {b0.x, b0.y, b0.z, b0.w, b1.x, b1.y, b1.z, b1.w};
#pragma unroll
            for (int r = 0; r < 4; ++r)
#pragma unroll
                for (int c = 0; c < 8; ++c)
                    acc[r][c] = fmaf(a_[r], b_[c], acc[r][c]);
        }
        __syncthreads();
    }
    // ---- epilogue: fp16 h + per-head logits ----
    float asv[8], adv[8];
#pragma unroll
    for (int c = 0; c < 8; ++c) {
        asv[c] = a_src[col0 + tx * 8 + c];
        adv[c] = a_dst[col0 + tx * 8 + c];
    }
    int head = (col0 >> 6) + (tx >> 3);   // 2 heads per block
#pragma unroll
    for (int r = 0; r < 4; ++r) {
        int gr = row0 + ty * 4 + r;
        // fp16 row segment (16B store)
        if (gr < M) {
            __half2 o[4];
            o[0] = __floats2half2_rn(acc[r][0], acc[r][1]);
            o[1] = __floats2half2_rn(acc[r][2], acc[r][3]);
            o[2] = __floats2half2_rn(acc[r][4], acc[r][5]);
            o[3] = __floats2half2_rn(acc[r][6], acc[r][7]);
            *(float4*)&h_half[(size_t)gr * HC + col0 + tx * 8] = *(float4*)o;
        }
        // logit partial dot over this thread's 8 channels, reduce across 8 lanes
        float ps = 0.f, pd = 0.f;
#pragma unroll
        for (int c = 0; c < 8; ++c) {
            ps = fmaf(acc[r][c], asv[c], ps);
            pd = fmaf(acc[r][c], adv[c], pd);
        }
#pragma unroll
        for (int off = 1; off < 8; off <<= 1) {
            ps += __shfl_xor(ps, off, 64);
            pd += __shfl_xor(pd, off, 64);
        }
        if ((tx & 7) == 0 && gr < M) {
            al_s[gr * 4 + head] = ps;
            al_d[gr * 4 + head] = pd;
        }
    }
}

// ---------------- CSR build (counting sort by dst) ---------------------------
__global__ void init_cnt(int* cnt) {
    int i = blockIdx.x * blockDim.x + threadIdx.x;
    if (i < N_NODES) cnt[i] = 1;   // self-loop pre-counted
}
__global__ void hist_kernel(const int* __restrict__ dsts, int* cnt) {
    int i = blockIdx.x * blockDim.x + threadIdx.x;
    if (i < E_EDGES) atomicAdd(&cnt[dsts[i]], 1);
}
__global__ __launch_bounds__(1024) void scan_kernel(const int* __restrict__ cnt,
                                                    int* row_ptr, int* cursor) {
    __shared__ int sums[1024];
    int t = threadIdx.x;
    const int CH = (N_NODES + 1023) / 1024;  // 49
    int lo = t * CH, hi = min(lo + CH, N_NODES);
    int s = 0;
    for (int i = lo; i < hi; ++i) s += cnt[i];
    sums[t] = s;
    __syncthreads();
    for (int off = 1; off < 1024; off <<= 1) {
        int v = (t >= off) ? sums[t - off] : 0;
        __syncthreads();
        sums[t] += v;
        __syncthreads();
    }
    int run = (t == 0) ? 0 : sums[t - 1];
    for (int i = lo; i < hi; ++i) {
        row_ptr[i] = run; cursor[i] = run;
        run += cnt[i];
    }
    if (t == 1023) row_ptr[N_NODES] = run;
}
__global__ void scatter_kernel(const int* __restrict__ srcs, const int* __restrict__ dsts,
                               int* cursor, int* col) {
    int i = blockIdx.x * blockDim.x + threadIdx.x;
    if (i >= E_EDGES + N_NODES) return;
    int s, d;
    if (i < E_EDGES) { s = srcs[i]; d = dsts[i]; }
    else             { s = d = i - E_EDGES; }     // self loops
    int pos = atomicAdd(&cursor[d], 1);
    col[pos] = s;
}

// ---------------- per-node softmax + aggregation -----------------------------
// mode 0: concat heads, +bias[256], ELU.   mode 1: mean heads, +bias[64], no ELU.
// Gather payload is fp16 (512B rows); all math fp32.
__global__ __launch_bounds__(256) void agg_kernel(const __half* __restrict__ hh,
        const float* __restrict__ al_s, const float* __restrict__ al_d,
        const int* __restrict__ row_ptr, const int* __restrict__ col,
        const float* __restrict__ bias, float* __restrict__ out, int mode) {
    __shared__ int   lds_col[4][64];
    __shared__ float lds_alpha[4][64 * 4];
    int wid  = threadIdx.x >> 6;
    int node = blockIdx.x * 4 + wid;
    int lane = threadIdx.x & 63;
    if (node >= N_NODES) return;
    int start = row_ptr[node], end = row_ptr[node + 1];
    int deg = end - start;
    const float4 ald = *(const float4*)&al_d[node * 4];
    int head = lane >> 4;
    float ald_h = head == 0 ? ald.x : head == 1 ? ald.y : head == 2 ? ald.z : ald.w;

    float ax = 0.f, ay = 0.f, az = 0.f, aw = 0.f;

    if (deg <= 64) {
        // ---- single-gather softmax ----
        int j = start + lane;
        bool active = j < end;
        int s = active ? col[j] : 0;
        float4 as = *(const float4*)&al_s[s * 4];
        float e0 = as.x + ald.x; e0 = e0 > 0.f ? e0 : SLOPE * e0;
        float e1 = as.y + ald.y; e1 = e1 > 0.f ? e1 : SLOPE * e1;
        float e2 = as.z + ald.z; e2 = e2 > 0.f ? e2 : SLOPE * e2;
        float e3 = as.w + ald.w; e3 = e3 > 0.f ? e3 : SLOPE * e3;
        float m0 = active ? e0 : -1e30f, m1 = active ? e1 : -1e30f;
        float m2 = active ? e2 : -1e30f, m3 = active ? e3 : -1e30f;
#pragma unroll
        for (int off = 1; off < 64; off <<= 1) {
            m0 = fmaxf(m0, __shfl_xor(m0, off, 64));
            m1 = fmaxf(m1, __shfl_xor(m1, off, 64));
            m2 = fmaxf(m2, __shfl_xor(m2, off, 64));
            m3 = fmaxf(m3, __shfl_xor(m3, off, 64));
        }
        float x0 = active ? expf(e0 - m0) : 0.f;
        float x1 = active ? expf(e1 - m1) : 0.f;
        float x2 = active ? expf(e2 - m2) : 0.f;
        float x3 = active ? expf(e3 - m3) : 0.f;
        float d0 = x0, d1 = x1, d2 = x2, d3 = x3;
#pragma unroll
        for (int off = 1; off < 64; off <<= 1) {
            d0 += __shfl_xor(d0, off, 64);
            d1 += __shfl_xor(d1, off, 64);
            d2 += __shfl_xor(d2, off, 64);
            d3 += __shfl_xor(d3, off, 64);
        }
        float4 a4;
        a4.x = x0 / (d0 + 1e-16f); a4.y = x1 / (d1 + 1e-16f);
        a4.z = x2 / (d2 + 1e-16f); a4.w = x3 / (d3 + 1e-16f);
        lds_col[wid][lane] = s;
        *(float4*)&lds_alpha[wid][lane * 4] = a4;
        const int*   lc = lds_col[wid];
        const float* la = lds_alpha[wid];
        // ---- 8-deep pipelined fp16 gather ----
        for (int t0 = 0; t0 < deg; t0 += 8) {
            int nn = deg - t0;   // >= 1
            float w[8]; float2 raw[8];
#pragma unroll
            for (int k = 0; k < 8; ++k) {
                if (k < nn) {
                    int s2 = lc[t0 + k];
                    w[k] = la[(t0 + k) * 4 + head];
                    raw[k] = *(const float2*)&hh[(size_t)s2 * HC + lane * 4];
                } else {
                    w[k] = 0.f;
                    raw[k] = make_float2(0.f, 0.f);
                }
            }
#pragma unroll
            for (int k = 0; k < 8; ++k) {
                float2 f0 = __half22float2(*(__half2*)&raw[k].x);
                float2 f1 = __half22float2(*(__half2*)&raw[k].y);
                ax = fmaf(w[k], f0.x, ax); ay = fmaf(w[k], f0.y, ay);
                az = fmaf(w[k], f1.x, az); aw = fmaf(w[k], f1.y, aw);
            }
        }
    } else {
        // ---- fallback: 3-pass streaming (deg > 64) ----
        float m0 = -1e30f, m1 = -1e30f, m2 = -1e30f, m3 = -1e30f;
        for (int j = start + lane; j < end; j += 64) {
            int s = col[j];
            float4 as = *(const float4*)&al_s[s * 4];
            float e0 = as.x + ald.x; e0 = e0 > 0.f ? e0 : SLOPE * e0;
            float e1 = as.y + ald.y; e1 = e1 > 0.f ? e1 : SLOPE * e1;
            float e2 = as.z + ald.z; e2 = e2 > 0.f ? e2 : SLOPE * e2;
            float e3 = as.w + ald.w; e3 = e3 > 0.f ? e3 : SLOPE * e3;
            m0 = fmaxf(m0, e0); m1 = fmaxf(m1, e1);
            m2 = fmaxf(m2, e2); m3 = fmaxf(m3, e3);
        }
#pragma unroll
        for (int off = 1; off < 64; off <<= 1) {
            m0 = fmaxf(m0, __shfl_xor(m0, off, 64));
            m1 = fmaxf(m1, __shfl_xor(m1, off, 64));
            m2 = fmaxf(m2, __shfl_xor(m2, off, 64));
            m3 = fmaxf(m3, __shfl_xor(m3, off, 64));
        }
        float d0 = 0.f, d1 = 0.f, d2 = 0.f, d3 = 0.f;
        for (int j = start + lane; j < end; j += 64) {
            int s = col[j];
            float4 as = *(const float4*)&al_s[s * 4];
            float e0 = as.x + ald.x; e0 = e0 > 0.f ? e0 : SLOPE * e0;
            float e1 = as.y + ald.y; e1 = e1 > 0.f ? e1 : SLOPE * e1;
            float e2 = as.z + ald.z; e2 = e2 > 0.f ? e2 : SLOPE * e2;
            float e3 = as.w + ald.w; e3 = e3 > 0.f ? e3 : SLOPE * e3;
            d0 += expf(e0 - m0); d1 += expf(e1 - m1);
            d2 += expf(e2 - m2); d3 += expf(e3 - m3);
        }
#pragma unroll
        for (int off = 1; off < 64; off <<= 1) {
            d0 += __shfl_xor(d0, off, 64);
            d1 += __shfl_xor(d1, off, 64);
            d2 += __shfl_xor(d2, off, 64);
            d3 += __shfl_xor(d3, off, 64);
        }
        float inv0 = 1.f / (d0 + 1e-16f), inv1 = 1.f / (d1 + 1e-16f);
        float inv2 = 1.f / (d2 + 1e-16f), inv3 = 1.f / (d3 + 1e-16f);
        float m_h   = head == 0 ? m0   : head == 1 ? m1   : head == 2 ? m2   : m3;
        float inv_h = head == 0 ? inv0 : head == 1 ? inv1 : head == 2 ? inv2 : inv3;
        for (int jb = start; jb < end; jb += 64) {
            int j = jb + lane;
            int cs = (j < end) ? col[j] : 0;
            int cnt = min(64, end - jb);
            for (int t = 0; t < cnt; ++t) {
                int s = __shfl(cs, t, 64);
                float als = al_s[s * 4 + head];
                float e = als + ald_h; e = e > 0.f ? e : SLOPE * e;
                float w = expf(e - m_h) * inv_h;
                float2 raw = *(const float2*)&hh[(size_t)s * HC + lane * 4];
                float2 f0 = __half22float2(*(__half2*)&raw.x);
                float2 f1 = __half22float2(*(__half2*)&raw.y);
                ax = fmaf(w, f0.x, ax); ay = fmaf(w, f0.y, ay);
                az = fmaf(w, f1.x, az); aw = fmaf(w, f1.y, aw);
            }
        }
    }

    if (mode == 0) {
        float4 b4 = *(const float4*)&bias[lane * 4];
        float vx = ax + b4.x; vx = vx > 0.f ? vx : expm1f(vx);
        float vy = ay + b4.y; vy = vy > 0.f ? vy : expm1f(vy);
        float vz = az + b4.z; vz = vz > 0.f ? vz : expm1f(vz);
        float vw = aw + b4.w; vw = vw > 0.f ? vw : expm1f(vw);
        float4 v = make_float4(vx, vy, vz, vw);
        *(float4*)&out[(size_t)node * HC + lane * 4] = v;
    } else {
        // mean over heads: sum lanes lane^16, lane^32
#pragma unroll
        for (int off = 16; off < 64; off <<= 1) {
            ax += __shfl_xor(ax, off, 64);
            ay += __shfl_xor(ay, off, 64);
            az += __shfl_xor(az, off, 64);
            aw += __shfl_xor(aw, off, 64);
        }
        if (lane < 16) {
            float4 b4 = *(const float4*)&bias[lane * 4];
            float4 v = make_float4(ax * 0.25f + b4.x, ay * 0.25f + b4.y,
                                   az * 0.25f + b4.z, aw * 0.25f + b4.w);
            *(float4*)&out[(size_t)node * 64 + lane * 4] = v;
        }
    }
}

// ---------------- pooling + MLP ----------------------------------------------
__global__ void pool_zero(float* __restrict__ pooled) {
    int i = blockIdx.x * blockDim.x + threadIdx.x;
    if (i < B_GR * 64) pooled[i] = 0.f;
}

__global__ __launch_bounds__(256) void pool_kernel(const float* __restrict__ act,
        const int* __restrict__ batch, float* __restrict__ pooled) {
    int b = blockIdx.x;
    int chunk = blockIdx.y;          // 0..15
    int warp = threadIdx.x >> 6;     // 0..3
    int lane = threadIdx.x & 63;
    int lo = 0, hi = N_NODES;
    while (lo < hi) { int mid = (lo + hi) >> 1; if (batch[mid] < b) lo = mid + 1; else hi = mid; }
    int s = lo;
    lo = 0; hi = N_NODES;
    while (lo < hi) { int mid = (lo + hi) >> 1; if (batch[mid] < b + 1) lo = mid + 1; else hi = mid; }
    int e = lo;
    float sum = 0.f;
    for (int n = s + chunk * 4 + warp; n < e; n += 64)
        sum += act[(size_t)n * 64 + lane];
    atomicAdd(&pooled[b * 64 + lane], sum);
}

__global__ __launch_bounds__(64) void mlp_kernel(const float* __restrict__ pooled,
        const int* __restrict__ batch,
        const float* __restrict__ pW1, const float* __restrict__ pb1,
        const float* __restrict__ pW2, const float* __restrict__ pb2,
        float* __restrict__ outp) {
    __shared__ float p[64];
    __shared__ float z[32];
    int b = blockIdx.x, t = threadIdx.x;
    int lo = 0, hi = N_NODES;
    while (lo < hi) { int mid = (lo + hi) >> 1; if (batch[mid] < b) lo = mid + 1; else hi = mid; }
    int s = lo;
    lo = 0; hi = N_NODES;
    while (lo < hi) { int mid = (lo + hi) >> 1; if (batch[mid] < b + 1) lo = mid + 1; else hi = mid; }
    int e = lo;
    float inv = 1.f / (float)max(e - s, 1);
    p[t] = pooled[b * 64 + t] * inv;
    __syncthreads();
    if (t < 32) {
        float s2 = pb1[t];
        for (int c = 0; c < 64; ++c) s2 += p[c] * pW1[c * 32 + t];
        z[t] = s2 > 0.f ? s2 : 0.f;
    }
    __syncthreads();
    if (t < OUT_DIM) {
        float s2 = pb2[t];
        for (int k = 0; k < 32; ++k) s2 += z[k] * pW2[k * 10 + t];
        outp[b * 10 + t] = s2;
    }
}

// ---------------- launch ------------------------------------------------------
extern "C" void kernel_launch(void* const* d_in, const int* in_sizes, int n_in,
                              void* d_out, int out_size, void* d_ws, size_t ws_size,
                              hipStream_t stream) {
    const float* x    = (const float*)d_in[0];
    const int*   ei   = (const int*)d_in[1];
    const int*   batch= (const int*)d_in[2];
    const float* W0   = (const float*)d_in[3];
    const float* b0   = (const float*)d_in[4];
    const float* as0  = (const float*)d_in[5];
    const float* ad0  = (const float*)d_in[6];
    const float* W1   = (const float*)d_in[7];
    const float* b1   = (const float*)d_in[8];
    const float* as1  = (const float*)d_in[9];
    const float* ad1  = (const float*)d_in[10];
    const float* W2   = (const float*)d_in[11];
    const float* b2   = (const float*)d_in[12];
    const float* as2  = (const float*)d_in[13];
    const float* ad2  = (const float*)d_in[14];
    const float* pW1  = (const float*)d_in[15];
    const float* pb1  = (const float*)d_in[16];
    const float* pW2  = (const float*)d_in[17];
    const float* pb2  = (const float*)d_in[18];
    float* out = (float*)d_out;

    char* ws = (char*)d_ws;
    size_t off = 0;
    auto alloc = [&](size_t bytes) -> void* {
        void* p = ws + off;
        off += (bytes + 255) & ~(size_t)255;
        return p;
    };
    __half* h_half = (__half*)alloc((size_t)N_NODES * HC * 2);
    float* act    = (float*)alloc((size_t)N_NODES * HC * 4);
    float* als    = (float*)alloc((size_t)N_NODES * 4 * 4);
    float* ald    = (float*)alloc((size_t)N_NODES * 4 * 4);
    int*   cnt    = (int*)alloc((size_t)N_NODES * 4);
    int*   row_ptr= (int*)alloc((size_t)(N_NODES + 1) * 4);
    int*   cursor = (int*)alloc((size_t)N_NODES * 4);
    int*   col    = (int*)alloc((size_t)(E_EDGES + N_NODES) * 4);
    float* pooled = (float*)alloc((size_t)B_GR * 64 * 4);

    const int* srcs = ei;
    const int* dsts = ei + E_EDGES;

    // CSR by dst (graph static within call; reused by all 3 layers)
    init_cnt<<<(N_NODES + 255) / 256, 256, 0, stream>>>(cnt);
    hist_kernel<<<(E_EDGES + 255) / 256, 256, 0, stream>>>(dsts, cnt);
    scan_kernel<<<1, 1024, 0, stream>>>(cnt, row_ptr, cursor);
    scatter_kernel<<<(E_EDGES + N_NODES + 255) / 256, 256, 0, stream>>>(srcs, dsts, cursor, col);

    dim3 ggrid((N_NODES + 63) / 64, 2);
    int nblk = (N_NODES + 3) / 4;

    // layer 0
    gemm_kernel<128><<<ggrid, 256, 0, stream>>>(x, W0, h_half, as0, ad0, als, ald, N_NODES);
    agg_kernel<<<nblk, 256, 0, stream>>>(h_half, als, ald, row_ptr, col, b0, act, 0);
    // layer 1
    gemm_kernel<256><<<ggrid, 256, 0, stream>>>(act, W1, h_half, as1, ad1, als, ald, N_NODES);
    agg_kernel<<<nblk, 256, 0, stream>>>(h_half, als, ald, row_ptr, col, b1, act, 0);
    // layer 2 (mean heads, no ELU)
    gemm_kernel<256><<<ggrid, 256, 0, stream>>>(act, W2, h_half, as2, ad2, als, ald, N_NODES);
    agg_kernel<<<nblk, 256, 0, stream>>>(h_half, als, ald, row_ptr, col, b2, act, 1);

    pool_zero<<<(B_GR * 64 + 255) / 256, 256, 0, stream>>>(pooled);
    dim3 pgrid(B_GR, 16);
    pool_kernel<<<pgrid, 256, 0, stream>>>(act, batch, pooled);
    mlp_kernel<<<B_GR, 64, 0, stream>>>(pooled, batch, pW1, pb1, pW2, pb2, out);
}

// Round 5
// 566.554 us; speedup vs baseline: 1.8922x; 1.1692x over previous
//
#include <hip/hip_runtime.h>
#include <hip/hip_fp16.h>
#include <cstdint>

#define N_NODES 50000
#define E_EDGES 800000
#define HC 256           // H*C
#define B_GR 64
#define OUT_DIM 10
#define SLOPE 0.2f
#define NBLK_SCAN ((N_NODES + 255) / 256)   // 196

// ---------------- GEMM: h = A[M x K] * W[K x 256], fused epilogue -------------
// Writes h as fp16 (gather payload) and per-head attention logits al_s/al_d
// computed from the fp32 accumulators (BN=128 == 2 heads, block-complete dots).
template<int K>
__global__ __launch_bounds__(256) void gemm_kernel(const float* __restrict__ A,
        const float* __restrict__ W, __half* __restrict__ h_half,
        const float* __restrict__ a_src, const float* __restrict__ a_dst,
        float* __restrict__ al_s, float* __restrict__ al_d, int M) {
    const int BM = 64, BN = 128, BK = 16;
    __shared__ float As[BK][BM];   // transposed tile
    __shared__ float Bs[BK][BN];
    int tid = threadIdx.x;
    int row0 = blockIdx.x * BM;
    int col0 = blockIdx.y * BN;
    int tx = tid & 15;    // 16 col-groups of 8
    int ty = tid >> 4;    // 16 row-groups of 4
    float acc[4][8] = {};
    int am = tid >> 2;           // row in tile 0..63
    int ak = (tid & 3) * 4;      // k offset 0/4/8/12
    for (int k0 = 0; k0 < K; k0 += BK) {
        float4 av = make_float4(0.f, 0.f, 0.f, 0.f);
        int gr = row0 + am;
        if (gr < M) av = *(const float4*)&A[(size_t)gr * K + k0 + ak];
        As[ak + 0][am] = av.x; As[ak + 1][am] = av.y;
        As[ak + 2][am] = av.z; As[ak + 3][am] = av.w;
#pragma unroll
        for (int i = 0; i < 2; ++i) {
            int idx = tid + i * 256;      // 0..511
            int bk = idx >> 5;            // 0..15
            int bn = (idx & 31) * 4;
            *(float4*)&Bs[bk][bn] = *(const float4*)&W[(size_t)(k0 + bk) * HC + col0 + bn];
        }
        __syncthreads();
#pragma unroll
        for (int kk = 0; kk < BK; ++kk) {
            float4 a4 = *(const float4*)&As[kk][ty * 4];
            float4 b0 = *(const float4*)&Bs[kk][tx * 8];
            float4 b1 = *(const float4*)&Bs[kk][tx * 8 + 4];
            float a_[4] = {a4.x, a4.y, a4.z, a4.w};
            float b_[8] = {b0.x, b0.y, b0.z, b0.w, b1.x, b1.y, b1.z, b1.w};
#pragma unroll
            for (int r = 0; r < 4; ++r)
#pragma unroll
                for (int c = 0; c < 8; ++c)
                    acc[r][c] = fmaf(a_[r], b_[c], acc[r][c]);
        }
        __syncthreads();
    }
    // ---- epilogue: fp16 h + per-head logits ----
    float asv[8], adv[8];
#pragma unroll
    for (int c = 0; c < 8; ++c) {
        asv[c] = a_src[col0 + tx * 8 + c];
        adv[c] = a_dst[col0 + tx * 8 + c];
    }
    int head = (col0 >> 6) + (tx >> 3);   // 2 heads per block
#pragma unroll
    for (int r = 0; r < 4; ++r) {
        int gr = row0 + ty * 4 + r;
        // fp16 row segment (16B store)
        if (gr < M) {
            __half2 o[4];
            o[0] = __floats2half2_rn(acc[r][0], acc[r][1]);
            o[1] = __floats2half2_rn(acc[r][2], acc[r][3]);
            o[2] = __floats2half2_rn(acc[r][4], acc[r][5]);
            o[3] = __floats2half2_rn(acc[r][6], acc[r][7]);
            *(float4*)&h_half[(size_t)gr * HC + col0 + tx * 8] = *(float4*)o;
        }
        // logit partial dot over this thread's 8 channels, reduce across 8 lanes
        float ps = 0.f, pd = 0.f;
#pragma unroll
        for (int c = 0; c < 8; ++c) {
            ps = fmaf(acc[r][c], asv[c], ps);
            pd = fmaf(acc[r][c], adv[c], pd);
        }
#pragma unroll
        for (int off = 1; off < 8; off <<= 1) {
            ps += __shfl_xor(ps, off, 64);
            pd += __shfl_xor(pd, off, 64);
        }
        if ((tx & 7) == 0 && gr < M) {
            al_s[gr * 4 + head] = ps;
            al_d[gr * 4 + head] = pd;
        }
    }
}

// ---------------- CSR build (counting sort by dst) ---------------------------
__global__ void init_cnt(int* cnt) {
    int i = blockIdx.x * blockDim.x + threadIdx.x;
    if (i < N_NODES) cnt[i] = 1;   // self-loop pre-counted
}
__global__ void hist_kernel(const int* __restrict__ dsts, int* cnt) {
    int i = blockIdx.x * blockDim.x + threadIdx.x;
    if (i < E_EDGES) atomicAdd(&cnt[dsts[i]], 1);
}
// hierarchical scan: (1) per-block sums, (2) scan of block sums, (3) final.
__global__ __launch_bounds__(256) void scan_bsum(const int* __restrict__ cnt,
                                                 int* __restrict__ bsum) {
    __shared__ int ws[4];
    int t = threadIdx.x;
    int i = blockIdx.x * 256 + t;
    int v = (i < N_NODES) ? cnt[i] : 0;
#pragma unroll
    for (int off = 1; off < 64; off <<= 1) v += __shfl_xor(v, off, 64);
    if ((t & 63) == 0) ws[t >> 6] = v;
    __syncthreads();
    if (t == 0) bsum[blockIdx.x] = ws[0] + ws[1] + ws[2] + ws[3];
}
__global__ __launch_bounds__(256) void scan_boff(const int* __restrict__ bsum,
                                                 int* __restrict__ boff) {
    __shared__ int s[256];
    int t = threadIdx.x;
    int v = (t < NBLK_SCAN) ? bsum[t] : 0;
    s[t] = v;
    __syncthreads();
    for (int off = 1; off < 256; off <<= 1) {
        int u = (t >= off) ? s[t - off] : 0;
        __syncthreads();
        s[t] += u;
        __syncthreads();
    }
    if (t < NBLK_SCAN) boff[t] = s[t] - v;   // exclusive
}
__global__ __launch_bounds__(256) void scan_final(const int* __restrict__ cnt,
        const int* __restrict__ boff, int* __restrict__ row_ptr,
        int* __restrict__ cursor) {
    __shared__ int s[256];
    int b = blockIdx.x, t = threadIdx.x;
    int i = b * 256 + t;
    int v = (i < N_NODES) ? cnt[i] : 0;
    s[t] = v;
    __syncthreads();
    for (int off = 1; off < 256; off <<= 1) {
        int u = (t >= off) ? s[t - off] : 0;
        __syncthreads();
        s[t] += u;
        __syncthreads();
    }
    int rp = boff[b] + s[t] - v;   // exclusive prefix
    if (i < N_NODES) { row_ptr[i] = rp; cursor[i] = rp; }
    if (i == N_NODES - 1) row_ptr[N_NODES] = rp + v;   // = E+N total
}
__global__ void scatter_kernel(const int* __restrict__ srcs, const int* __restrict__ dsts,
                               int* cursor, int* col) {
    int i = blockIdx.x * blockDim.x + threadIdx.x;
    if (i >= E_EDGES + N_NODES) return;
    int s, d;
    if (i < E_EDGES) { s = srcs[i]; d = dsts[i]; }
    else             { s = d = i - E_EDGES; }     // self loops
    int pos = atomicAdd(&cursor[d], 1);
    col[pos] = s;
}

// ---------------- per-node softmax + aggregation -----------------------------
// mode 0: concat heads, +bias[256], ELU.   mode 1: mean heads, +bias[64], no ELU.
// Gather payload is fp16 (512B rows); all math fp32.
__global__ __launch_bounds__(256) void agg_kernel(const __half* __restrict__ hh,
        const float* __restrict__ al_s, const float* __restrict__ al_d,
        const int* __restrict__ row_ptr, const int* __restrict__ col,
        const float* __restrict__ bias, float* __restrict__ out, int mode) {
    __shared__ int   lds_col[4][64];
    __shared__ float lds_alpha[4][64 * 4];
    int wid  = threadIdx.x >> 6;
    int node = blockIdx.x * 4 + wid;
    int lane = threadIdx.x & 63;
    if (node >= N_NODES) return;
    int start = row_ptr[node], end = row_ptr[node + 1];
    int deg = end - start;
    const float4 ald = *(const float4*)&al_d[node * 4];
    int head = lane >> 4;
    float ald_h = head == 0 ? ald.x : head == 1 ? ald.y : head == 2 ? ald.z : ald.w;

    float ax = 0.f, ay = 0.f, az = 0.f, aw = 0.f;

    if (deg <= 64) {
        // ---- single-gather softmax ----
        int j = start + lane;
        bool active = j < end;
        int s = active ? col[j] : 0;
        float4 as = *(const float4*)&al_s[s * 4];
        float e0 = as.x + ald.x; e0 = e0 > 0.f ? e0 : SLOPE * e0;
        float e1 = as.y + ald.y; e1 = e1 > 0.f ? e1 : SLOPE * e1;
        float e2 = as.z + ald.z; e2 = e2 > 0.f ? e2 : SLOPE * e2;
        float e3 = as.w + ald.w; e3 = e3 > 0.f ? e3 : SLOPE * e3;
        float m0 = active ? e0 : -1e30f, m1 = active ? e1 : -1e30f;
        float m2 = active ? e2 : -1e30f, m3 = active ? e3 : -1e30f;
#pragma unroll
        for (int off = 1; off < 64; off <<= 1) {
            m0 = fmaxf(m0, __shfl_xor(m0, off, 64));
            m1 = fmaxf(m1, __shfl_xor(m1, off, 64));
            m2 = fmaxf(m2, __shfl_xor(m2, off, 64));
            m3 = fmaxf(m3, __shfl_xor(m3, off, 64));
        }
        float x0 = active ? expf(e0 - m0) : 0.f;
        float x1 = active ? expf(e1 - m1) : 0.f;
        float x2 = active ? expf(e2 - m2) : 0.f;
        float x3 = active ? expf(e3 - m3) : 0.f;
        float d0 = x0, d1 = x1, d2 = x2, d3 = x3;
#pragma unroll
        for (int off = 1; off < 64; off <<= 1) {
            d0 += __shfl_xor(d0, off, 64);
            d1 += __shfl_xor(d1, off, 64);
            d2 += __shfl_xor(d2, off, 64);
            d3 += __shfl_xor(d3, off, 64);
        }
        float4 a4;
        a4.x = x0 / (d0 + 1e-16f); a4.y = x1 / (d1 + 1e-16f);
        a4.z = x2 / (d2 + 1e-16f); a4.w = x3 / (d3 + 1e-16f);
        lds_col[wid][lane] = s;
        *(float4*)&lds_alpha[wid][lane * 4] = a4;
        const int*   lc = lds_col[wid];
        const float* la = lds_alpha[wid];
        // ---- 8-deep pipelined fp16 gather ----
        for (int t0 = 0; t0 < deg; t0 += 8) {
            int nn = deg - t0;   // >= 1
            float w[8]; float2 raw[8];
#pragma unroll
            for (int k = 0; k < 8; ++k) {
                if (k < nn) {
                    int s2 = lc[t0 + k];
                    w[k] = la[(t0 + k) * 4 + head];
                    raw[k] = *(const float2*)&hh[(size_t)s2 * HC + lane * 4];
                } else {
                    w[k] = 0.f;
                    raw[k] = make_float2(0.f, 0.f);
                }
            }
#pragma unroll
            for (int k = 0; k < 8; ++k) {
                float2 f0 = __half22float2(*(__half2*)&raw[k].x);
                float2 f1 = __half22float2(*(__half2*)&raw[k].y);
                ax = fmaf(w[k], f0.x, ax); ay = fmaf(w[k], f0.y, ay);
                az = fmaf(w[k], f1.x, az); aw = fmaf(w[k], f1.y, aw);
            }
        }
    } else {
        // ---- fallback: 3-pass streaming (deg > 64) ----
        float m0 = -1e30f, m1 = -1e30f, m2 = -1e30f, m3 = -1e30f;
        for (int j = start + lane; j < end; j += 64) {
            int s = col[j];
            float4 as = *(const float4*)&al_s[s * 4];
            float e0 = as.x + ald.x; e0 = e0 > 0.f ? e0 : SLOPE * e0;
            float e1 = as.y + ald.y; e1 = e1 > 0.f ? e1 : SLOPE * e1;
            float e2 = as.z + ald.z; e2 = e2 > 0.f ? e2 : SLOPE * e2;
            float e3 = as.w + ald.w; e3 = e3 > 0.f ? e3 : SLOPE * e3;
            m0 = fmaxf(m0, e0); m1 = fmaxf(m1, e1);
            m2 = fmaxf(m2, e2); m3 = fmaxf(m3, e3);
        }
#pragma unroll
        for (int off = 1; off < 64; off <<= 1) {
            m0 = fmaxf(m0, __shfl_xor(m0, off, 64));
            m1 = fmaxf(m1, __shfl_xor(m1, off, 64));
            m2 = fmaxf(m2, __shfl_xor(m2, off, 64));
            m3 = fmaxf(m3, __shfl_xor(m3, off, 64));
        }
        float d0 = 0.f, d1 = 0.f, d2 = 0.f, d3 = 0.f;
        for (int j = start + lane; j < end; j += 64) {
            int s = col[j];
            float4 as = *(const float4*)&al_s[s * 4];
            float e0 = as.x + ald.x; e0 = e0 > 0.f ? e0 : SLOPE * e0;
            float e1 = as.y + ald.y; e1 = e1 > 0.f ? e1 : SLOPE * e1;
            float e2 = as.z + ald.z; e2 = e2 > 0.f ? e2 : SLOPE * e2;
            float e3 = as.w + ald.w; e3 = e3 > 0.f ? e3 : SLOPE * e3;
            d0 += expf(e0 - m0); d1 += expf(e1 - m1);
            d2 += expf(e2 - m2); d3 += expf(e3 - m3);
        }
#pragma unroll
        for (int off = 1; off < 64; off <<= 1) {
            d0 += __shfl_xor(d0, off, 64);
            d1 += __shfl_xor(d1, off, 64);
            d2 += __shfl_xor(d2, off, 64);
            d3 += __shfl_xor(d3, off, 64);
        }
        float inv0 = 1.f / (d0 + 1e-16f), inv1 = 1.f / (d1 + 1e-16f);
        float inv2 = 1.f / (d2 + 1e-16f), inv3 = 1.f / (d3 + 1e-16f);
        float m_h   = head == 0 ? m0   : head == 1 ? m1   : head == 2 ? m2   : m3;
        float inv_h = head == 0 ? inv0 : head == 1 ? inv1 : head == 2 ? inv2 : inv3;
        for (int jb = start; jb < end; jb += 64) {
            int j = jb + lane;
            int cs = (j < end) ? col[j] : 0;
            int cnt = min(64, end - jb);
            for (int t = 0; t < cnt; ++t) {
                int s = __shfl(cs, t, 64);
                float als = al_s[s * 4 + head];
                float e = als + ald_h; e = e > 0.f ? e : SLOPE * e;
                float w = expf(e - m_h) * inv_h;
                float2 raw = *(const float2*)&hh[(size_t)s * HC + lane * 4];
                float2 f0 = __half22float2(*(__half2*)&raw.x);
                float2 f1 = __half22float2(*(__half2*)&raw.y);
                ax = fmaf(w, f0.x, ax); ay = fmaf(w, f0.y, ay);
                az = fmaf(w, f1.x, az); aw = fmaf(w, f1.y, aw);
            }
        }
    }

    if (mode == 0) {
        float4 b4 = *(const float4*)&bias[lane * 4];
        float vx = ax + b4.x; vx = vx > 0.f ? vx : expm1f(vx);
        float vy = ay + b4.y; vy = vy > 0.f ? vy : expm1f(vy);
        float vz = az + b4.z; vz = vz > 0.f ? vz : expm1f(vz);
        float vw = aw + b4.w; vw = vw > 0.f ? vw : expm1f(vw);
        float4 v = make_float4(vx, vy, vz, vw);
        *(float4*)&out[(size_t)node * HC + lane * 4] = v;
    } else {
        // mean over heads: sum lanes lane^16, lane^32
#pragma unroll
        for (int off = 16; off < 64; off <<= 1) {
            ax += __shfl_xor(ax, off, 64);
            ay += __shfl_xor(ay, off, 64);
            az += __shfl_xor(az, off, 64);
            aw += __shfl_xor(aw, off, 64);
        }
        if (lane < 16) {
            float4 b4 = *(const float4*)&bias[lane * 4];
            float4 v = make_float4(ax * 0.25f + b4.x, ay * 0.25f + b4.y,
                                   az * 0.25f + b4.z, aw * 0.25f + b4.w);
            *(float4*)&out[(size_t)node * 64 + lane * 4] = v;
        }
    }
}

// ---------------- pooling + MLP ----------------------------------------------
__global__ void pool_zero(float* __restrict__ pooled) {
    int i = blockIdx.x * blockDim.x + threadIdx.x;
    if (i < B_GR * 64) pooled[i] = 0.f;
}

__global__ __launch_bounds__(256) void pool_kernel(const float* __restrict__ act,
        const int* __restrict__ batch, float* __restrict__ pooled) {
    int b = blockIdx.x;
    int chunk = blockIdx.y;          // 0..15
    int warp = threadIdx.x >> 6;     // 0..3
    int lane = threadIdx.x & 63;
    int lo = 0, hi = N_NODES;
    while (lo < hi) { int mid = (lo + hi) >> 1; if (batch[mid] < b) lo = mid + 1; else hi = mid; }
    int s = lo;
    lo = 0; hi = N_NODES;
    while (lo < hi) { int mid = (lo + hi) >> 1; if (batch[mid] < b + 1) lo = mid + 1; else hi = mid; }
    int e = lo;
    float sum = 0.f;
    for (int n = s + chunk * 4 + warp; n < e; n += 64)
        sum += act[(size_t)n * 64 + lane];
    atomicAdd(&pooled[b * 64 + lane], sum);
}

__global__ __launch_bounds__(64) void mlp_kernel(const float* __restrict__ pooled,
        const int* __restrict__ batch,
        const float* __restrict__ pW1, const float* __restrict__ pb1,
        const float* __restrict__ pW2, const float* __restrict__ pb2,
        float* __restrict__ outp) {
    __shared__ float p[64];
    __shared__ float z[32];
    int b = blockIdx.x, t = threadIdx.x;
    int lo = 0, hi = N_NODES;
    while (lo < hi) { int mid = (lo + hi) >> 1; if (batch[mid] < b) lo = mid + 1; else hi = mid; }
    int s = lo;
    lo = 0; hi = N_NODES;
    while (lo < hi) { int mid = (lo + hi) >> 1; if (batch[mid] < b + 1) lo = mid + 1; else hi = mid; }
    int e = lo;
    float inv = 1.f / (float)max(e - s, 1);
    p[t] = pooled[b * 64 + t] * inv;
    __syncthreads();
    if (t < 32) {
        float s2 = pb1[t];
        for (int c = 0; c < 64; ++c) s2 += p[c] * pW1[c * 32 + t];
        z[t] = s2 > 0.f ? s2 : 0.f;
    }
    __syncthreads();
    if (t < OUT_DIM) {
        float s2 = pb2[t];
        for (int k = 0; k < 32; ++k) s2 += z[k] * pW2[k * 10 + t];
        outp[b * 10 + t] = s2;
    }
}

// ---------------- launch ------------------------------------------------------
extern "C" void kernel_launch(void* const* d_in, const int* in_sizes, int n_in,
                              void* d_out, int out_size, void* d_ws, size_t ws_size,
                              hipStream_t stream) {
    const float* x    = (const float*)d_in[0];
    const int*   ei   = (const int*)d_in[1];
    const int*   batch= (const int*)d_in[2];
    const float* W0   = (const float*)d_in[3];
    const float* b0   = (const float*)d_in[4];
    const float* as0  = (const float*)d_in[5];
    const float* ad0  = (const float*)d_in[6];
    const float* W1   = (const float*)d_in[7];
    const float* b1   = (const float*)d_in[8];
    const float* as1  = (const float*)d_in[9];
    const float* ad1  = (const float*)d_in[10];
    const float* W2   = (const float*)d_in[11];
    const float* b2   = (const float*)d_in[12];
    const float* as2  = (const float*)d_in[13];
    const float* ad2  = (const float*)d_in[14];
    const float* pW1  = (const float*)d_in[15];
    const float* pb1  = (const float*)d_in[16];
    const float* pW2  = (const float*)d_in[17];
    const float* pb2  = (const float*)d_in[18];
    float* out = (float*)d_out;

    char* ws = (char*)d_ws;
    size_t off = 0;
    auto alloc = [&](size_t bytes) -> void* {
        void* p = ws + off;
        off += (bytes + 255) & ~(size_t)255;
        return p;
    };
    __half* h_half = (__half*)alloc((size_t)N_NODES * HC * 2);
    float* act    = (float*)alloc((size_t)N_NODES * HC * 4);
    float* als    = (float*)alloc((size_t)N_NODES * 4 * 4);
    float* ald    = (float*)alloc((size_t)N_NODES * 4 * 4);
    int*   cnt    = (int*)alloc((size_t)N_NODES * 4);
    int*   row_ptr= (int*)alloc((size_t)(N_NODES + 1) * 4);
    int*   cursor = (int*)alloc((size_t)N_NODES * 4);
    int*   col    = (int*)alloc((size_t)(E_EDGES + N_NODES) * 4);
    float* pooled = (float*)alloc((size_t)B_GR * 64 * 4);
    int*   bsum   = (int*)alloc((size_t)NBLK_SCAN * 4);
    int*   boff   = (int*)alloc((size_t)NBLK_SCAN * 4);

    const int* srcs = ei;
    const int* dsts = ei + E_EDGES;

    // CSR by dst (graph static within call; reused by all 3 layers)
    init_cnt<<<(N_NODES + 255) / 256, 256, 0, stream>>>(cnt);
    hist_kernel<<<(E_EDGES + 255) / 256, 256, 0, stream>>>(dsts, cnt);
    scan_bsum<<<NBLK_SCAN, 256, 0, stream>>>(cnt, bsum);
    scan_boff<<<1, 256, 0, stream>>>(bsum, boff);
    scan_final<<<NBLK_SCAN, 256, 0, stream>>>(cnt, boff, row_ptr, cursor);
    scatter_kernel<<<(E_EDGES + N_NODES + 255) / 256, 256, 0, stream>>>(srcs, dsts, cursor, col);

    dim3 ggrid((N_NODES + 63) / 64, 2);
    int nblk = (N_NODES + 3) / 4;

    // layer 0
    gemm_kernel<128><<<ggrid, 256, 0, stream>>>(x, W0, h_half, as0, ad0, als, ald, N_NODES);
    agg_kernel<<<nblk, 256, 0, stream>>>(h_half, als, ald, row_ptr, col, b0, act, 0);
    // layer 1
    gemm_kernel<256><<<ggrid, 256, 0, stream>>>(act, W1, h_half, as1, ad1, als, ald, N_NODES);
    agg_kernel<<<nblk, 256, 0, stream>>>(h_half, als, ald, row_ptr, col, b1, act, 0);
    // layer 2 (mean heads, no ELU)
    gemm_kernel<256><<<ggrid, 256, 0, stream>>>(act, W2, h_half, as2, ad2, als, ald, N_NODES);
    agg_kernel<<<nblk, 256, 0, stream>>>(h_half, als, ald, row_ptr, col, b2, act, 1);

    pool_zero<<<(B_GR * 64 + 255) / 256, 256, 0, stream>>>(pooled);
    dim3 pgrid(B_GR, 16);
    pool_kernel<<<pgrid, 256, 0, stream>>>(act, batch, pooled);
    mlp_kernel<<<B_GR, 64, 0, stream>>>(pooled, batch, pW1, pb1, pW2, pb2, out);
}

// Round 6
// 461.674 us; speedup vs baseline: 2.3221x; 1.2272x over previous
//
#include <hip/hip_runtime.h>
#include <hip/hip_fp16.h>
#include <cstdint>

#define N_NODES 50000
#define E_EDGES 800000
#define HC 256           // H*C
#define B_GR 64
#define OUT_DIM 10
#define SLOPE 0.2f
#define NBLK_SCAN ((N_NODES + 255) / 256)   // 196

using f16x8 = __attribute__((ext_vector_type(8))) _Float16;
using f32x4 = __attribute__((ext_vector_type(4))) float;

// ---------------- W split prep: W[K x 256] fp32 -> Wt_hi/Wt_lo[256 x K] fp16 --
__global__ void wsplit_kernel(const float* __restrict__ W, _Float16* __restrict__ wt_hi,
                              _Float16* __restrict__ wt_lo, int K) {
    int i = blockIdx.x * 256 + threadIdx.x;
    if (i >= K * 256) return;
    int k = i >> 8, n = i & 255;           // W[k][n], coalesced read
    float v = W[i];
    _Float16 h = (_Float16)v;
    _Float16 l = (_Float16)(v - (float)h);
    wt_hi[(size_t)n * K + k] = h;
    wt_lo[(size_t)n * K + k] = l;
}

// ---------------- MFMA GEMM: h = A[M x K] * W[K x 256], split-fp16 ------------
// 3-term split (hi*hi + hi*lo + lo*hi), fp32 accumulate -> fp32-grade accuracy.
// Block: 64 rows x 256 cols, 4 waves; wave w owns cols [64w,64w+64) = head w.
// Fused epilogue: fp16 h store + al_s/al_d logits from fp32 accumulators.
template<int K>
__global__ __launch_bounds__(256) void gemm_mfma(const float* __restrict__ A,
        const _Float16* __restrict__ wt_hi, const _Float16* __restrict__ wt_lo,
        __half* __restrict__ h_half,
        const float* __restrict__ a_src, const float* __restrict__ a_dst,
        float* __restrict__ al_s, float* __restrict__ al_d, int M) {
    __shared__ _Float16 a_hi[64][64];
    __shared__ _Float16 a_lo[64][64];
    int tid = threadIdx.x;
    int w = tid >> 6;           // wave 0..3 -> head / col quadrant
    int l = tid & 63;           // lane
    int rr = l & 15;            // frag row/col index
    int kg = l >> 4;            // k-group 0..3 within 32-k chunk
    int row0 = blockIdx.x * 64;
    int lrow = tid >> 2;        // staging row 0..63
    int lgp  = (tid & 3) * 2;   // staging k-group pair base (groups of 8)

    f32x4 acc[4][4] = {};

    for (int k0 = 0; k0 < K; k0 += 64) {
        if (k0 > 0) __syncthreads();
        // ---- stage A chunk [64][64] as hi/lo fp16, XOR-swizzled groups ----
        int gr = row0 + lrow;
#pragma unroll
        for (int gi = 0; gi < 2; ++gi) {
            int g = lgp + gi;
            float vv[8];
            if (gr < M) {
                float4 p = *(const float4*)&A[(size_t)gr * K + k0 + g * 8];
                float4 q = *(const float4*)&A[(size_t)gr * K + k0 + g * 8 + 4];
                vv[0] = p.x; vv[1] = p.y; vv[2] = p.z; vv[3] = p.w;
                vv[4] = q.x; vv[5] = q.y; vv[6] = q.z; vv[7] = q.w;
            } else {
#pragma unroll
                for (int j = 0; j < 8; ++j) vv[j] = 0.f;
            }
            f16x8 vh, vl;
#pragma unroll
            for (int j = 0; j < 8; ++j) {
                _Float16 hh = (_Float16)vv[j];
                vh[j] = hh;
                vl[j] = (_Float16)(vv[j] - (float)hh);
            }
            int gs = g ^ (lrow & 7);
            *(f16x8*)&a_hi[lrow][gs * 8] = vh;
            *(f16x8*)&a_lo[lrow][gs * 8] = vl;
        }
        __syncthreads();
        // ---- compute: 2 chunks of k=32 ----
#pragma unroll
        for (int c = 0; c < 2; ++c) {
            f16x8 ah[4], alo[4];
#pragma unroll
            for (int fm = 0; fm < 4; ++fm) {
                int row = fm * 16 + rr;
                int gsw = ((c * 4 + kg) ^ (row & 7));
                ah[fm]  = *(const f16x8*)&a_hi[row][gsw * 8];
                alo[fm] = *(const f16x8*)&a_lo[row][gsw * 8];
            }
#pragma unroll
            for (int fn = 0; fn < 4; ++fn) {
                int col = w * 64 + fn * 16 + rr;
                size_t boff = (size_t)col * K + k0 + (c * 4 + kg) * 8;
                f16x8 bh = *(const f16x8*)&wt_hi[boff];
                f16x8 bl = *(const f16x8*)&wt_lo[boff];
#pragma unroll
                for (int fm = 0; fm < 4; ++fm) {
                    acc[fm][fn] = __builtin_amdgcn_mfma_f32_16x16x32_f16(ah[fm],  bh, acc[fm][fn], 0, 0, 0);
                    acc[fm][fn] = __builtin_amdgcn_mfma_f32_16x16x32_f16(ah[fm],  bl, acc[fm][fn], 0, 0, 0);
                    acc[fm][fn] = __builtin_amdgcn_mfma_f32_16x16x32_f16(alo[fm], bh, acc[fm][fn], 0, 0, 0);
                }
            }
        }
    }

    // ---- epilogue: fp16 h + per-head logits (head = wave) ----
    int head = w;
    float asv[4], adv[4];
#pragma unroll
    for (int fn = 0; fn < 4; ++fn) {
        asv[fn] = a_src[head * 64 + fn * 16 + rr];
        adv[fn] = a_dst[head * 64 + fn * 16 + rr];
    }
#pragma unroll
    for (int fm = 0; fm < 4; ++fm) {
#pragma unroll
        for (int r = 0; r < 4; ++r) {
            int row = fm * 16 + kg * 4 + r;     // C/D: row=(lane>>4)*4+reg
            int gr = row0 + row;
            float ps = acc[fm][0][r] * asv[0] + acc[fm][1][r] * asv[1]
                     + acc[fm][2][r] * asv[2] + acc[fm][3][r] * asv[3];
            float pd = acc[fm][0][r] * adv[0] + acc[fm][1][r] * adv[1]
                     + acc[fm][2][r] * adv[2] + acc[fm][3][r] * adv[3];
#pragma unroll
            for (int off = 1; off < 16; off <<= 1) {
                ps += __shfl_xor(ps, off, 64);
                pd += __shfl_xor(pd, off, 64);
            }
            if (gr < M) {
#pragma unroll
                for (int fn = 0; fn < 4; ++fn)
                    h_half[(size_t)gr * HC + w * 64 + fn * 16 + rr] = __float2half(acc[fm][fn][r]);
                if (rr == 0) {
                    al_s[gr * 4 + head] = ps;
                    al_d[gr * 4 + head] = pd;
                }
            }
        }
    }
}

// ---------------- CSR build (counting sort by dst) ---------------------------
__global__ void init_cnt(int* cnt) {
    int i = blockIdx.x * blockDim.x + threadIdx.x;
    if (i < N_NODES) cnt[i] = 1;   // self-loop pre-counted
}
__global__ void hist_kernel(const int* __restrict__ dsts, int* cnt) {
    int i = blockIdx.x * blockDim.x + threadIdx.x;
    if (i < E_EDGES) atomicAdd(&cnt[dsts[i]], 1);
}
// hierarchical scan: (1) per-block sums, (2) scan of block sums, (3) final.
__global__ __launch_bounds__(256) void scan_bsum(const int* __restrict__ cnt,
                                                 int* __restrict__ bsum) {
    __shared__ int ws[4];
    int t = threadIdx.x;
    int i = blockIdx.x * 256 + t;
    int v = (i < N_NODES) ? cnt[i] : 0;
#pragma unroll
    for (int off = 1; off < 64; off <<= 1) v += __shfl_xor(v, off, 64);
    if ((t & 63) == 0) ws[t >> 6] = v;
    __syncthreads();
    if (t == 0) bsum[blockIdx.x] = ws[0] + ws[1] + ws[2] + ws[3];
}
__global__ __launch_bounds__(256) void scan_boff(const int* __restrict__ bsum,
                                                 int* __restrict__ boff) {
    __shared__ int s[256];
    int t = threadIdx.x;
    int v = (t < NBLK_SCAN) ? bsum[t] : 0;
    s[t] = v;
    __syncthreads();
    for (int off = 1; off < 256; off <<= 1) {
        int u = (t >= off) ? s[t - off] : 0;
        __syncthreads();
        s[t] += u;
        __syncthreads();
    }
    if (t < NBLK_SCAN) boff[t] = s[t] - v;   // exclusive
}
__global__ __launch_bounds__(256) void scan_final(const int* __restrict__ cnt,
        const int* __restrict__ boff, int* __restrict__ row_ptr,
        int* __restrict__ cursor) {
    __shared__ int s[256];
    int b = blockIdx.x, t = threadIdx.x;
    int i = b * 256 + t;
    int v = (i < N_NODES) ? cnt[i] : 0;
    s[t] = v;
    __syncthreads();
    for (int off = 1; off < 256; off <<= 1) {
        int u = (t >= off) ? s[t - off] : 0;
        __syncthreads();
        s[t] += u;
        __syncthreads();
    }
    int rp = boff[b] + s[t] - v;   // exclusive prefix
    if (i < N_NODES) { row_ptr[i] = rp; cursor[i] = rp; }
    if (i == N_NODES - 1) row_ptr[N_NODES] = rp + v;   // = E+N total
}
__global__ void scatter_kernel(const int* __restrict__ srcs, const int* __restrict__ dsts,
                               int* cursor, int* col) {
    int i = blockIdx.x * blockDim.x + threadIdx.x;
    if (i >= E_EDGES + N_NODES) return;
    int s, d;
    if (i < E_EDGES) { s = srcs[i]; d = dsts[i]; }
    else             { s = d = i - E_EDGES; }     // self loops
    int pos = atomicAdd(&cursor[d], 1);
    col[pos] = s;
}

// ---------------- per-node softmax + aggregation -----------------------------
// mode 0: concat heads, +bias[256], ELU.   mode 1: mean heads, +bias[64], no ELU.
// Gather payload is fp16 (512B rows); all math fp32.
__global__ __launch_bounds__(256) void agg_kernel(const __half* __restrict__ hh,
        const float* __restrict__ al_s, const float* __restrict__ al_d,
        const int* __restrict__ row_ptr, const int* __restrict__ col,
        const float* __restrict__ bias, float* __restrict__ out, int mode) {
    __shared__ int   lds_col[4][64];
    __shared__ float lds_alpha[4][64 * 4];
    int wid  = threadIdx.x >> 6;
    int node = blockIdx.x * 4 + wid;
    int lane = threadIdx.x & 63;
    if (node >= N_NODES) return;
    int start = row_ptr[node], end = row_ptr[node + 1];
    int deg = end - start;
    const float4 ald = *(const float4*)&al_d[node * 4];
    int head = lane >> 4;
    float ald_h = head == 0 ? ald.x : head == 1 ? ald.y : head == 2 ? ald.z : ald.w;

    float ax = 0.f, ay = 0.f, az = 0.f, aw = 0.f;

    if (deg <= 64) {
        // ---- single-gather softmax ----
        int j = start + lane;
        bool active = j < end;
        int s = active ? col[j] : 0;
        float4 as = *(const float4*)&al_s[s * 4];
        float e0 = as.x + ald.x; e0 = e0 > 0.f ? e0 : SLOPE * e0;
        float e1 = as.y + ald.y; e1 = e1 > 0.f ? e1 : SLOPE * e1;
        float e2 = as.z + ald.z; e2 = e2 > 0.f ? e2 : SLOPE * e2;
        float e3 = as.w + ald.w; e3 = e3 > 0.f ? e3 : SLOPE * e3;
        float m0 = active ? e0 : -1e30f, m1 = active ? e1 : -1e30f;
        float m2 = active ? e2 : -1e30f, m3 = active ? e3 : -1e30f;
#pragma unroll
        for (int off = 1; off < 64; off <<= 1) {
            m0 = fmaxf(m0, __shfl_xor(m0, off, 64));
            m1 = fmaxf(m1, __shfl_xor(m1, off, 64));
            m2 = fmaxf(m2, __shfl_xor(m2, off, 64));
            m3 = fmaxf(m3, __shfl_xor(m3, off, 64));
        }
        float x0 = active ? expf(e0 - m0) : 0.f;
        float x1 = active ? expf(e1 - m1) : 0.f;
        float x2 = active ? expf(e2 - m2) : 0.f;
        float x3 = active ? expf(e3 - m3) : 0.f;
        float d0 = x0, d1 = x1, d2 = x2, d3 = x3;
#pragma unroll
        for (int off = 1; off < 64; off <<= 1) {
            d0 += __shfl_xor(d0, off, 64);
            d1 += __shfl_xor(d1, off, 64);
            d2 += __shfl_xor(d2, off, 64);
            d3 += __shfl_xor(d3, off, 64);
        }
        float4 a4;
        a4.x = x0 / (d0 + 1e-16f); a4.y = x1 / (d1 + 1e-16f);
        a4.z = x2 / (d2 + 1e-16f); a4.w = x3 / (d3 + 1e-16f);
        lds_col[wid][lane] = s;
        *(float4*)&lds_alpha[wid][lane * 4] = a4;
        const int*   lc = lds_col[wid];
        const float* la = lds_alpha[wid];
        // ---- 8-deep pipelined fp16 gather ----
        for (int t0 = 0; t0 < deg; t0 += 8) {
            int nn = deg - t0;   // >= 1
            float w[8]; float2 raw[8];
#pragma unroll
            for (int k = 0; k < 8; ++k) {
                if (k < nn) {
                    int s2 = lc[t0 + k];
                    w[k] = la[(t0 + k) * 4 + head];
                    raw[k] = *(const float2*)&hh[(size_t)s2 * HC + lane * 4];
                } else {
                    w[k] = 0.f;
                    raw[k] = make_float2(0.f, 0.f);
                }
            }
#pragma unroll
            for (int k = 0; k < 8; ++k) {
                float2 f0 = __half22float2(*(__half2*)&raw[k].x);
                float2 f1 = __half22float2(*(__half2*)&raw[k].y);
                ax = fmaf(w[k], f0.x, ax); ay = fmaf(w[k], f0.y, ay);
                az = fmaf(w[k], f1.x, az); aw = fmaf(w[k], f1.y, aw);
            }
        }
    } else {
        // ---- fallback: 3-pass streaming (deg > 64) ----
        float m0 = -1e30f, m1 = -1e30f, m2 = -1e30f, m3 = -1e30f;
        for (int j = start + lane; j < end; j += 64) {
            int s = col[j];
            float4 as = *(const float4*)&al_s[s * 4];
            float e0 = as.x + ald.x; e0 = e0 > 0.f ? e0 : SLOPE * e0;
            float e1 = as.y + ald.y; e1 = e1 > 0.f ? e1 : SLOPE * e1;
            float e2 = as.z + ald.z; e2 = e2 > 0.f ? e2 : SLOPE * e2;
            float e3 = as.w + ald.w; e3 = e3 > 0.f ? e3 : SLOPE * e3;
            m0 = fmaxf(m0, e0); m1 = fmaxf(m1, e1);
            m2 = fmaxf(m2, e2); m3 = fmaxf(m3, e3);
        }
#pragma unroll
        for (int off = 1; off < 64; off <<= 1) {
            m0 = fmaxf(m0, __shfl_xor(m0, off, 64));
            m1 = fmaxf(m1, __shfl_xor(m1, off, 64));
            m2 = fmaxf(m2, __shfl_xor(m2, off, 64));
            m3 = fmaxf(m3, __shfl_xor(m3, off, 64));
        }
        float d0 = 0.f, d1 = 0.f, d2 = 0.f, d3 = 0.f;
        for (int j = start + lane; j < end; j += 64) {
            int s = col[j];
            float4 as = *(const float4*)&al_s[s * 4];
            float e0 = as.x + ald.x; e0 = e0 > 0.f ? e0 : SLOPE * e0;
            float e1 = as.y + ald.y; e1 = e1 > 0.f ? e1 : SLOPE * e1;
            float e2 = as.z + ald.z; e2 = e2 > 0.f ? e2 : SLOPE * e2;
            float e3 = as.w + ald.w; e3 = e3 > 0.f ? e3 : SLOPE * e3;
            d0 += expf(e0 - m0); d1 += expf(e1 - m1);
            d2 += expf(e2 - m2); d3 += expf(e3 - m3);
        }
#pragma unroll
        for (int off = 1; off < 64; off <<= 1) {
            d0 += __shfl_xor(d0, off, 64);
            d1 += __shfl_xor(d1, off, 64);
            d2 += __shfl_xor(d2, off, 64);
            d3 += __shfl_xor(d3, off, 64);
        }
        float inv0 = 1.f / (d0 + 1e-16f), inv1 = 1.f / (d1 + 1e-16f);
        float inv2 = 1.f / (d2 + 1e-16f), inv3 = 1.f / (d3 + 1e-16f);
        float m_h   = head == 0 ? m0   : head == 1 ? m1   : head == 2 ? m2   : m3;
        float inv_h = head == 0 ? inv0 : head == 1 ? inv1 : head == 2 ? inv2 : inv3;
        for (int jb = start; jb < end; jb += 64) {
            int j = jb + lane;
            int cs = (j < end) ? col[j] : 0;
            int cnt = min(64, end - jb);
            for (int t = 0; t < cnt; ++t) {
                int s = __shfl(cs, t, 64);
                float als = al_s[s * 4 + head];
                float e = als + ald_h; e = e > 0.f ? e : SLOPE * e;
                float w = expf(e - m_h) * inv_h;
                float2 raw = *(const float2*)&hh[(size_t)s * HC + lane * 4];
                float2 f0 = __half22float2(*(__half2*)&raw.x);
                float2 f1 = __half22float2(*(__half2*)&raw.y);
                ax = fmaf(w, f0.x, ax); ay = fmaf(w, f0.y, ay);
                az = fmaf(w, f1.x, az); aw = fmaf(w, f1.y, aw);
            }
        }
    }

    if (mode == 0) {
        float4 b4 = *(const float4*)&bias[lane * 4];
        float vx = ax + b4.x; vx = vx > 0.f ? vx : expm1f(vx);
        float vy = ay + b4.y; vy = vy > 0.f ? vy : expm1f(vy);
        float vz = az + b4.z; vz = vz > 0.f ? vz : expm1f(vz);
        float vw = aw + b4.w; vw = vw > 0.f ? vw : expm1f(vw);
        float4 v = make_float4(vx, vy, vz, vw);
        *(float4*)&out[(size_t)node * HC + lane * 4] = v;
    } else {
        // mean over heads: sum lanes lane^16, lane^32
#pragma unroll
        for (int off = 16; off < 64; off <<= 1) {
            ax += __shfl_xor(ax, off, 64);
            ay += __shfl_xor(ay, off, 64);
            az += __shfl_xor(az, off, 64);
            aw += __shfl_xor(aw, off, 64);
        }
        if (lane < 16) {
            float4 b4 = *(const float4*)&bias[lane * 4];
            float4 v = make_float4(ax * 0.25f + b4.x, ay * 0.25f + b4.y,
                                   az * 0.25f + b4.z, aw * 0.25f + b4.w);
            *(float4*)&out[(size_t)node * 64 + lane * 4] = v;
        }
    }
}

// ---------------- pooling + MLP ----------------------------------------------
__global__ void pool_zero(float* __restrict__ pooled) {
    int i = blockIdx.x * blockDim.x + threadIdx.x;
    if (i < B_GR * 64) pooled[i] = 0.f;
}

__global__ __launch_bounds__(256) void pool_kernel(const float* __restrict__ act,
        const int* __restrict__ batch, float* __restrict__ pooled) {
    int b = blockIdx.x;
    int chunk = blockIdx.y;          // 0..15
    int warp = threadIdx.x >> 6;     // 0..3
    int lane = threadIdx.x & 63;
    int lo = 0, hi = N_NODES;
    while (lo < hi) { int mid = (lo + hi) >> 1; if (batch[mid] < b) lo = mid + 1; else hi = mid; }
    int s = lo;
    lo = 0; hi = N_NODES;
    while (lo < hi) { int mid = (lo + hi) >> 1; if (batch[mid] < b + 1) lo = mid + 1; else hi = mid; }
    int e = lo;
    float sum = 0.f;
    for (int n = s + chunk * 4 + warp; n < e; n += 64)
        sum += act[(size_t)n * 64 + lane];
    atomicAdd(&pooled[b * 64 + lane], sum);
}

__global__ __launch_bounds__(64) void mlp_kernel(const float* __restrict__ pooled,
        const int* __restrict__ batch,
        const float* __restrict__ pW1, const float* __restrict__ pb1,
        const float* __restrict__ pW2, const float* __restrict__ pb2,
        float* __restrict__ outp) {
    __shared__ float p[64];
    __shared__ float z[32];
    int b = blockIdx.x, t = threadIdx.x;
    int lo = 0, hi = N_NODES;
    while (lo < hi) { int mid = (lo + hi) >> 1; if (batch[mid] < b) lo = mid + 1; else hi = mid; }
    int s = lo;
    lo = 0; hi = N_NODES;
    while (lo < hi) { int mid = (lo + hi) >> 1; if (batch[mid] < b + 1) lo = mid + 1; else hi = mid; }
    int e = lo;
    float inv = 1.f / (float)max(e - s, 1);
    p[t] = pooled[b * 64 + t] * inv;
    __syncthreads();
    if (t < 32) {
        float s2 = pb1[t];
        for (int c = 0; c < 64; ++c) s2 += p[c] * pW1[c * 32 + t];
        z[t] = s2 > 0.f ? s2 : 0.f;
    }
    __syncthreads();
    if (t < OUT_DIM) {
        float s2 = pb2[t];
        for (int k = 0; k < 32; ++k) s2 += z[k] * pW2[k * 10 + t];
        outp[b * 10 + t] = s2;
    }
}

// ---------------- launch ------------------------------------------------------
extern "C" void kernel_launch(void* const* d_in, const int* in_sizes, int n_in,
                              void* d_out, int out_size, void* d_ws, size_t ws_size,
                              hipStream_t stream) {
    const float* x    = (const float*)d_in[0];
    const int*   ei   = (const int*)d_in[1];
    const int*   batch= (const int*)d_in[2];
    const float* W0   = (const float*)d_in[3];
    const float* b0   = (const float*)d_in[4];
    const float* as0  = (const float*)d_in[5];
    const float* ad0  = (const float*)d_in[6];
    const float* W1   = (const float*)d_in[7];
    const float* b1   = (const float*)d_in[8];
    const float* as1  = (const float*)d_in[9];
    const float* ad1  = (const float*)d_in[10];
    const float* W2   = (const float*)d_in[11];
    const float* b2   = (const float*)d_in[12];
    const float* as2  = (const float*)d_in[13];
    const float* ad2  = (const float*)d_in[14];
    const float* pW1  = (const float*)d_in[15];
    const float* pb1  = (const float*)d_in[16];
    const float* pW2  = (const float*)d_in[17];
    const float* pb2  = (const float*)d_in[18];
    float* out = (float*)d_out;

    char* ws = (char*)d_ws;
    size_t off = 0;
    auto alloc = [&](size_t bytes) -> void* {
        void* p = ws + off;
        off += (bytes + 255) & ~(size_t)255;
        return p;
    };
    __half* h_half = (__half*)alloc((size_t)N_NODES * HC * 2);
    float* act    = (float*)alloc((size_t)N_NODES * HC * 4);
    float* als    = (float*)alloc((size_t)N_NODES * 4 * 4);
    float* ald    = (float*)alloc((size_t)N_NODES * 4 * 4);
    int*   cnt    = (int*)alloc((size_t)N_NODES * 4);
    int*   row_ptr= (int*)alloc((size_t)(N_NODES + 1) * 4);
    int*   cursor = (int*)alloc((size_t)N_NODES * 4);
    int*   col    = (int*)alloc((size_t)(E_EDGES + N_NODES) * 4);
    float* pooled = (float*)alloc((size_t)B_GR * 64 * 4);
    int*   bsum   = (int*)alloc((size_t)NBLK_SCAN * 4);
    int*   boff   = (int*)alloc((size_t)NBLK_SCAN * 4);
    _Float16* w0h = (_Float16*)alloc((size_t)128 * 256 * 2);
    _Float16* w0l = (_Float16*)alloc((size_t)128 * 256 * 2);
    _Float16* w1h = (_Float16*)alloc((size_t)256 * 256 * 2);
    _Float16* w1l = (_Float16*)alloc((size_t)256 * 256 * 2);
    _Float16* w2h = (_Float16*)alloc((size_t)256 * 256 * 2);
    _Float16* w2l = (_Float16*)alloc((size_t)256 * 256 * 2);

    const int* srcs = ei;
    const int* dsts = ei + E_EDGES;

    // weight splits (tiny)
    wsplit_kernel<<<(128 * 256 + 255) / 256, 256, 0, stream>>>(W0, w0h, w0l, 128);
    wsplit_kernel<<<(256 * 256 + 255) / 256, 256, 0, stream>>>(W1, w1h, w1l, 256);
    wsplit_kernel<<<(256 * 256 + 255) / 256, 256, 0, stream>>>(W2, w2h, w2l, 256);

    // CSR by dst (graph static within call; reused by all 3 layers)
    init_cnt<<<(N_NODES + 255) / 256, 256, 0, stream>>>(cnt);
    hist_kernel<<<(E_EDGES + 255) / 256, 256, 0, stream>>>(dsts, cnt);
    scan_bsum<<<NBLK_SCAN, 256, 0, stream>>>(cnt, bsum);
    scan_boff<<<1, 256, 0, stream>>>(bsum, boff);
    scan_final<<<NBLK_SCAN, 256, 0, stream>>>(cnt, boff, row_ptr, cursor);
    scatter_kernel<<<(E_EDGES + N_NODES + 255) / 256, 256, 0, stream>>>(srcs, dsts, cursor, col);

    int gblk = (N_NODES + 63) / 64;   // 782
    int nblk = (N_NODES + 3) / 4;

    // layer 0
    gemm_mfma<128><<<gblk, 256, 0, stream>>>(x, w0h, w0l, h_half, as0, ad0, als, ald, N_NODES);
    agg_kernel<<<nblk, 256, 0, stream>>>(h_half, als, ald, row_ptr, col, b0, act, 0);
    // layer 1
    gemm_mfma<256><<<gblk, 256, 0, stream>>>(act, w1h, w1l, h_half, as1, ad1, als, ald, N_NODES);
    agg_kernel<<<nblk, 256, 0, stream>>>(h_half, als, ald, row_ptr, col, b1, act, 0);
    // layer 2 (mean heads, no ELU)
    gemm_mfma<256><<<gblk, 256, 0, stream>>>(act, w2h, w2l, h_half, as2, ad2, als, ald, N_NODES);
    agg_kernel<<<nblk, 256, 0, stream>>>(h_half, als, ald, row_ptr, col, b2, act, 1);

    pool_zero<<<(B_GR * 64 + 255) / 256, 256, 0, stream>>>(pooled);
    dim3 pgrid(B_GR, 16);
    pool_kernel<<<pgrid, 256, 0, stream>>>(act, batch, pooled);
    mlp_kernel<<<B_GR, 64, 0, stream>>>(pooled, batch, pW1, pb1, pW2, pb2, out);
}

// Round 7
// 445.044 us; speedup vs baseline: 2.4089x; 1.0374x over previous
//
#include <hip/hip_runtime.h>
#include <hip/hip_fp16.h>
#include <cstdint>

#define N_NODES 50000
#define E_EDGES 800000
#define HC 256           // H*C
#define B_GR 64
#define OUT_DIM 10
#define SLOPE 0.2f
#define NBLK_SCAN ((N_NODES + 255) / 256)   // 196

using f16x8 = __attribute__((ext_vector_type(8))) _Float16;
using f32x4 = __attribute__((ext_vector_type(4))) float;

// ---------------- W split prep ------------------------------------------------
// W[K x 256] fp32 -> hi/lo fp16 in fragment-major layout [K/32][256][kg=4][j=8]
// so each wave B-fragment load is one contiguous 1KB block (fully coalesced).
__global__ void wsplit_kernel(const float* __restrict__ W, _Float16* __restrict__ wt_hi,
                              _Float16* __restrict__ wt_lo, int K) {
    int i = blockIdx.x * 256 + threadIdx.x;
    if (i >= K * 256) return;
    int k = i >> 8, n = i & 255;           // W[k][n], coalesced read
    float v = W[i];
    _Float16 h = (_Float16)v;
    _Float16 l = (_Float16)(v - (float)h);
    int oidx = ((((k >> 5) * 256 + n) * 4) + ((k >> 3) & 3)) * 8 + (k & 7);
    wt_hi[oidx] = h;
    wt_lo[oidx] = l;
}

// ---------------- MFMA GEMM: h = A[M x K] * W[K x 256], split-fp16 ------------
// 3-term split (hi*hi + hi*lo + lo*hi), fp32 accumulate -> fp32-grade accuracy.
// Block: 64 rows x 256 cols, 4 waves; wave w owns cols [64w,64w+64) = head w.
// Fused epilogue: fp16 h store + al_s/al_d logits from fp32 accumulators.
template<int K>
__global__ __launch_bounds__(256) void gemm_mfma(const float* __restrict__ A,
        const _Float16* __restrict__ wt_hi, const _Float16* __restrict__ wt_lo,
        __half* __restrict__ h_half,
        const float* __restrict__ a_src, const float* __restrict__ a_dst,
        float* __restrict__ al_s, float* __restrict__ al_d, int M) {
    __shared__ _Float16 a_hi[64][64];
    __shared__ _Float16 a_lo[64][64];
    int tid = threadIdx.x;
    int w = tid >> 6;           // wave 0..3 -> head / col quadrant
    int l = tid & 63;           // lane
    int rr = l & 15;            // frag row/col index
    int kg = l >> 4;            // k-group 0..3 within 32-k chunk
    int row0 = blockIdx.x * 64;
    int lrow = tid >> 2;        // staging row 0..63
    int lgp  = (tid & 3) * 2;   // staging k-group pair base (groups of 8)

    f32x4 acc[4][4] = {};

    for (int k0 = 0; k0 < K; k0 += 64) {
        if (k0 > 0) __syncthreads();
        // ---- stage A chunk [64][64] as hi/lo fp16, XOR-swizzled groups ----
        int gr = row0 + lrow;
#pragma unroll
        for (int gi = 0; gi < 2; ++gi) {
            int g = lgp + gi;
            float vv[8];
            if (gr < M) {
                float4 p = *(const float4*)&A[(size_t)gr * K + k0 + g * 8];
                float4 q = *(const float4*)&A[(size_t)gr * K + k0 + g * 8 + 4];
                vv[0] = p.x; vv[1] = p.y; vv[2] = p.z; vv[3] = p.w;
                vv[4] = q.x; vv[5] = q.y; vv[6] = q.z; vv[7] = q.w;
            } else {
#pragma unroll
                for (int j = 0; j < 8; ++j) vv[j] = 0.f;
            }
            f16x8 vh, vl;
#pragma unroll
            for (int j = 0; j < 8; ++j) {
                _Float16 hh = (_Float16)vv[j];
                vh[j] = hh;
                vl[j] = (_Float16)(vv[j] - (float)hh);
            }
            int gs = g ^ (lrow & 7);
            *(f16x8*)&a_hi[lrow][gs * 8] = vh;
            *(f16x8*)&a_lo[lrow][gs * 8] = vl;
        }
        __syncthreads();
        // ---- compute: 2 chunks of k=32 ----
#pragma unroll
        for (int c = 0; c < 2; ++c) {
            f16x8 ah[4], alo[4];
#pragma unroll
            for (int fm = 0; fm < 4; ++fm) {
                int row = fm * 16 + rr;
                int gsw = ((c * 4 + kg) ^ (row & 7));
                ah[fm]  = *(const f16x8*)&a_hi[row][gsw * 8];
                alo[fm] = *(const f16x8*)&a_lo[row][gsw * 8];
            }
            int chunk = (k0 >> 5) + c;
#pragma unroll
            for (int fn = 0; fn < 4; ++fn) {
                int col = w * 64 + fn * 16 + rr;
                size_t boff = (((size_t)chunk * 256 + col) * 4 + kg) * 8;
                f16x8 bh = *(const f16x8*)&wt_hi[boff];
                f16x8 bl = *(const f16x8*)&wt_lo[boff];
#pragma unroll
                for (int fm = 0; fm < 4; ++fm) {
                    acc[fm][fn] = __builtin_amdgcn_mfma_f32_16x16x32_f16(ah[fm],  bh, acc[fm][fn], 0, 0, 0);
                    acc[fm][fn] = __builtin_amdgcn_mfma_f32_16x16x32_f16(ah[fm],  bl, acc[fm][fn], 0, 0, 0);
                    acc[fm][fn] = __builtin_amdgcn_mfma_f32_16x16x32_f16(alo[fm], bh, acc[fm][fn], 0, 0, 0);
                }
            }
        }
    }

    // ---- epilogue: fp16 h + per-head logits (head = wave) ----
    int head = w;
    float asv[4], adv[4];
#pragma unroll
    for (int fn = 0; fn < 4; ++fn) {
        asv[fn] = a_src[head * 64 + fn * 16 + rr];
        adv[fn] = a_dst[head * 64 + fn * 16 + rr];
    }
#pragma unroll
    for (int fm = 0; fm < 4; ++fm) {
#pragma unroll
        for (int r = 0; r < 4; ++r) {
            int row = fm * 16 + kg * 4 + r;     // C/D: row=(lane>>4)*4+reg
            int gr = row0 + row;
            float ps = acc[fm][0][r] * asv[0] + acc[fm][1][r] * asv[1]
                     + acc[fm][2][r] * asv[2] + acc[fm][3][r] * asv[3];
            float pd = acc[fm][0][r] * adv[0] + acc[fm][1][r] * adv[1]
                     + acc[fm][2][r] * adv[2] + acc[fm][3][r] * adv[3];
#pragma unroll
            for (int off = 1; off < 16; off <<= 1) {
                ps += __shfl_xor(ps, off, 64);
                pd += __shfl_xor(pd, off, 64);
            }
            if (gr < M) {
#pragma unroll
                for (int fn = 0; fn < 4; ++fn)
                    h_half[(size_t)gr * HC + w * 64 + fn * 16 + rr] = __float2half(acc[fm][fn][r]);
                if (rr == 0) {
                    al_s[gr * 4 + head] = ps;
                    al_d[gr * 4 + head] = pd;
                }
            }
        }
    }
}

// ---------------- CSR build (counting sort by dst) ---------------------------
__global__ void init_cnt(int* cnt) {
    int i = blockIdx.x * blockDim.x + threadIdx.x;
    if (i < N_NODES) cnt[i] = 1;   // self-loop pre-counted
}
__global__ void hist_kernel(const int* __restrict__ dsts, int* cnt) {
    int i = blockIdx.x * blockDim.x + threadIdx.x;
    if (i < E_EDGES) atomicAdd(&cnt[dsts[i]], 1);
}
// hierarchical scan: (1) per-block sums, (2) scan of block sums, (3) final.
__global__ __launch_bounds__(256) void scan_bsum(const int* __restrict__ cnt,
                                                 int* __restrict__ bsum) {
    __shared__ int ws[4];
    int t = threadIdx.x;
    int i = blockIdx.x * 256 + t;
    int v = (i < N_NODES) ? cnt[i] : 0;
#pragma unroll
    for (int off = 1; off < 64; off <<= 1) v += __shfl_xor(v, off, 64);
    if ((t & 63) == 0) ws[t >> 6] = v;
    __syncthreads();
    if (t == 0) bsum[blockIdx.x] = ws[0] + ws[1] + ws[2] + ws[3];
}
__global__ __launch_bounds__(256) void scan_boff(const int* __restrict__ bsum,
                                                 int* __restrict__ boff) {
    __shared__ int s[256];
    int t = threadIdx.x;
    int v = (t < NBLK_SCAN) ? bsum[t] : 0;
    s[t] = v;
    __syncthreads();
    for (int off = 1; off < 256; off <<= 1) {
        int u = (t >= off) ? s[t - off] : 0;
        __syncthreads();
        s[t] += u;
        __syncthreads();
    }
    if (t < NBLK_SCAN) boff[t] = s[t] - v;   // exclusive
}
__global__ __launch_bounds__(256) void scan_final(const int* __restrict__ cnt,
        const int* __restrict__ boff, int* __restrict__ row_ptr,
        int* __restrict__ cursor) {
    __shared__ int s[256];
    int b = blockIdx.x, t = threadIdx.x;
    int i = b * 256 + t;
    int v = (i < N_NODES) ? cnt[i] : 0;
    s[t] = v;
    __syncthreads();
    for (int off = 1; off < 256; off <<= 1) {
        int u = (t >= off) ? s[t - off] : 0;
        __syncthreads();
        s[t] += u;
        __syncthreads();
    }
    int rp = boff[b] + s[t] - v;   // exclusive prefix
    if (i < N_NODES) { row_ptr[i] = rp; cursor[i] = rp; }
    if (i == N_NODES - 1) row_ptr[N_NODES] = rp + v;   // = E+N total
}
__global__ void scatter_kernel(const int* __restrict__ srcs, const int* __restrict__ dsts,
                               int* cursor, int* col) {
    int i = blockIdx.x * blockDim.x + threadIdx.x;
    if (i >= E_EDGES + N_NODES) return;
    int s, d;
    if (i < E_EDGES) { s = srcs[i]; d = dsts[i]; }
    else             { s = d = i - E_EDGES; }     // self loops
    int pos = atomicAdd(&cursor[d], 1);
    col[pos] = s;
}

// ---------------- per-node softmax + aggregation -----------------------------
// mode 0: concat heads, +bias[256], ELU.   mode 1: mean heads, +bias[64], no ELU.
// Fast path: 2 nodes per wave (lanes 0-31 node A, 32-63 node B), deg<=32 each;
// lane covers 8 channels (float4 fp16 row load). Rare deg>32 -> old 1-node path.
__global__ __launch_bounds__(256) void agg_kernel(const __half* __restrict__ hh,
        const float* __restrict__ al_s, const float* __restrict__ al_d,
        const int* __restrict__ row_ptr, const int* __restrict__ col,
        const float* __restrict__ bias, float* __restrict__ out, int mode) {
    __shared__ int   lds_col[4][64];
    __shared__ float lds_alpha[4][64][4];
    int wid  = threadIdx.x >> 6;
    int lane = threadIdx.x & 63;
    int hf   = lane >> 5;
    int ln   = lane & 31;
    int nodeA = blockIdx.x * 8 + wid * 2;   // N_NODES % 8 == 0 -> no tail
    int nodeB = nodeA + 1;
    int sA = row_ptr[nodeA], eA = row_ptr[nodeA + 1];
    int sB = row_ptr[nodeB], eB = row_ptr[nodeB + 1];
    int degA = eA - sA, degB = eB - sB;

    if (degA <= 32 && degB <= 32) {
        // ================= fast path: 2 nodes / wave =================
        int node  = hf ? nodeB : nodeA;
        int start = hf ? sB : sA;
        int deg   = hf ? degB : degA;
        int degmax = max(degA, degB);
        const float4 ald = *(const float4*)&al_d[node * 4];
        bool active = ln < deg;
        int s = active ? col[start + ln] : 0;
        float4 as = *(const float4*)&al_s[s * 4];
        float e0 = as.x + ald.x; e0 = e0 > 0.f ? e0 : SLOPE * e0;
        float e1 = as.y + ald.y; e1 = e1 > 0.f ? e1 : SLOPE * e1;
        float e2 = as.z + ald.z; e2 = e2 > 0.f ? e2 : SLOPE * e2;
        float e3 = as.w + ald.w; e3 = e3 > 0.f ? e3 : SLOPE * e3;
        float m0 = active ? e0 : -1e30f, m1 = active ? e1 : -1e30f;
        float m2 = active ? e2 : -1e30f, m3 = active ? e3 : -1e30f;
#pragma unroll
        for (int off = 1; off < 32; off <<= 1) {   // width-32: stays in half
            m0 = fmaxf(m0, __shfl_xor(m0, off, 64));
            m1 = fmaxf(m1, __shfl_xor(m1, off, 64));
            m2 = fmaxf(m2, __shfl_xor(m2, off, 64));
            m3 = fmaxf(m3, __shfl_xor(m3, off, 64));
        }
        float x0 = active ? expf(e0 - m0) : 0.f;
        float x1 = active ? expf(e1 - m1) : 0.f;
        float x2 = active ? expf(e2 - m2) : 0.f;
        float x3 = active ? expf(e3 - m3) : 0.f;
        float d0 = x0, d1 = x1, d2 = x2, d3 = x3;
#pragma unroll
        for (int off = 1; off < 32; off <<= 1) {
            d0 += __shfl_xor(d0, off, 64);
            d1 += __shfl_xor(d1, off, 64);
            d2 += __shfl_xor(d2, off, 64);
            d3 += __shfl_xor(d3, off, 64);
        }
        float4 a4;
        a4.x = x0 / (d0 + 1e-16f); a4.y = x1 / (d1 + 1e-16f);
        a4.z = x2 / (d2 + 1e-16f); a4.w = x3 / (d3 + 1e-16f);
        int e = hf * 32 + ln;
        lds_col[wid][e] = s;
        *(float4*)&lds_alpha[wid][e][0] = a4;
        // same-wave LDS produce->consume: no barrier needed
        int head = ln >> 3;
        int ch0 = ln * 8;
        float acc[8] = {0.f, 0.f, 0.f, 0.f, 0.f, 0.f, 0.f, 0.f};
        int ebase = hf * 32;
        for (int t0 = 0; t0 < degmax; t0 += 4) {
            float wv[4]; float4 raw[4];
#pragma unroll
            for (int k = 0; k < 4; ++k) {
                int t = t0 + k;
                int tt = min(t, deg - 1);          // deg >= 1 (self-loop)
                int s2 = lds_col[wid][ebase + tt];
                wv[k] = (t < deg) ? lds_alpha[wid][ebase + tt][head] : 0.f;
                raw[k] = *(const float4*)&hh[(size_t)s2 * HC + ch0];
            }
#pragma unroll
            for (int k = 0; k < 4; ++k) {
                const __half2* hp = (const __half2*)&raw[k];
                float2 f0 = __half22float2(hp[0]);
                float2 f1 = __half22float2(hp[1]);
                float2 f2 = __half22float2(hp[2]);
                float2 f3 = __half22float2(hp[3]);
                acc[0] = fmaf(wv[k], f0.x, acc[0]); acc[1] = fmaf(wv[k], f0.y, acc[1]);
                acc[2] = fmaf(wv[k], f1.x, acc[2]); acc[3] = fmaf(wv[k], f1.y, acc[3]);
                acc[4] = fmaf(wv[k], f2.x, acc[4]); acc[5] = fmaf(wv[k], f2.y, acc[5]);
                acc[6] = fmaf(wv[k], f3.x, acc[6]); acc[7] = fmaf(wv[k], f3.y, acc[7]);
            }
        }
        if (mode == 0) {
            float b8[8];
            *(float4*)&b8[0] = *(const float4*)&bias[ch0];
            *(float4*)&b8[4] = *(const float4*)&bias[ch0 + 4];
            float v[8];
#pragma unroll
            for (int j = 0; j < 8; ++j) {
                float t = acc[j] + b8[j];
                v[j] = t > 0.f ? t : expm1f(t);
            }
            *(float4*)&out[(size_t)node * HC + ch0]     = *(float4*)&v[0];
            *(float4*)&out[(size_t)node * HC + ch0 + 4] = *(float4*)&v[4];
        } else {
            // mean over heads: lanes {ln, ln^8, ln^16, ln^24} share within-head idx
#pragma unroll
            for (int j = 0; j < 8; ++j) {
                acc[j] += __shfl_xor(acc[j], 8, 64);
                acc[j] += __shfl_xor(acc[j], 16, 64);
            }
            if (ln < 8) {
                float v[8];
#pragma unroll
                for (int j = 0; j < 8; ++j)
                    v[j] = acc[j] * 0.25f + bias[ln * 8 + j];
                *(float4*)&out[(size_t)node * 64 + ln * 8]     = *(float4*)&v[0];
                *(float4*)&out[(size_t)node * 64 + ln * 8 + 4] = *(float4*)&v[4];
            }
        }
        return;
    }

    // ================= fallback: 1 node / wave (rare, deg>32) =================
    for (int nn = 0; nn < 2; ++nn) {
        int node = nodeA + nn;
        int start = row_ptr[node], end = row_ptr[node + 1];
        int deg = end - start;
        const float4 ald = *(const float4*)&al_d[node * 4];
        int head = lane >> 4;
        float ald_h = head == 0 ? ald.x : head == 1 ? ald.y : head == 2 ? ald.z : ald.w;
        float ax = 0.f, ay = 0.f, az = 0.f, aw = 0.f;

        if (deg <= 64) {
            int j = start + lane;
            bool active = j < end;
            int s = active ? col[j] : 0;
            float4 as = *(const float4*)&al_s[s * 4];
            float e0 = as.x + ald.x; e0 = e0 > 0.f ? e0 : SLOPE * e0;
            float e1 = as.y + ald.y; e1 = e1 > 0.f ? e1 : SLOPE * e1;
            float e2 = as.z + ald.z; e2 = e2 > 0.f ? e2 : SLOPE * e2;
            float e3 = as.w + ald.w; e3 = e3 > 0.f ? e3 : SLOPE * e3;
            float m0 = active ? e0 : -1e30f, m1 = active ? e1 : -1e30f;
            float m2 = active ? e2 : -1e30f, m3 = active ? e3 : -1e30f;
#pragma unroll
            for (int off = 1; off < 64; off <<= 1) {
                m0 = fmaxf(m0, __shfl_xor(m0, off, 64));
                m1 = fmaxf(m1, __shfl_xor(m1, off, 64));
                m2 = fmaxf(m2, __shfl_xor(m2, off, 64));
                m3 = fmaxf(m3, __shfl_xor(m3, off, 64));
            }
            float x0 = active ? expf(e0 - m0) : 0.f;
            float x1 = active ? expf(e1 - m1) : 0.f;
            float x2 = active ? expf(e2 - m2) : 0.f;
            float x3 = active ? expf(e3 - m3) : 0.f;
            float d0 = x0, d1 = x1, d2 = x2, d3 = x3;
#pragma unroll
            for (int off = 1; off < 64; off <<= 1) {
                d0 += __shfl_xor(d0, off, 64);
                d1 += __shfl_xor(d1, off, 64);
                d2 += __shfl_xor(d2, off, 64);
                d3 += __shfl_xor(d3, off, 64);
            }
            float4 a4;
            a4.x = x0 / (d0 + 1e-16f); a4.y = x1 / (d1 + 1e-16f);
            a4.z = x2 / (d2 + 1e-16f); a4.w = x3 / (d3 + 1e-16f);
            lds_col[wid][lane] = s;
            *(float4*)&lds_alpha[wid][lane][0] = a4;
            for (int t0 = 0; t0 < deg; t0 += 8) {
                int nr = deg - t0;
                float wv[8]; float2 raw[8];
#pragma unroll
                for (int k = 0; k < 8; ++k) {
                    if (k < nr) {
                        int s2 = lds_col[wid][t0 + k];
                        wv[k] = lds_alpha[wid][t0 + k][head];
                        raw[k] = *(const float2*)&hh[(size_t)s2 * HC + lane * 4];
                    } else {
                        wv[k] = 0.f;
                        raw[k] = make_float2(0.f, 0.f);
                    }
                }
#pragma unroll
                for (int k = 0; k < 8; ++k) {
                    float2 f0 = __half22float2(*(__half2*)&raw[k].x);
                    float2 f1 = __half22float2(*(__half2*)&raw[k].y);
                    ax = fmaf(wv[k], f0.x, ax); ay = fmaf(wv[k], f0.y, ay);
                    az = fmaf(wv[k], f1.x, az); aw = fmaf(wv[k], f1.y, aw);
                }
            }
        } else {
            // 3-pass streaming (deg > 64)
            float m0 = -1e30f, m1 = -1e30f, m2 = -1e30f, m3 = -1e30f;
            for (int j = start + lane; j < end; j += 64) {
                int s = col[j];
                float4 as = *(const float4*)&al_s[s * 4];
                float e0 = as.x + ald.x; e0 = e0 > 0.f ? e0 : SLOPE * e0;
                float e1 = as.y + ald.y; e1 = e1 > 0.f ? e1 : SLOPE * e1;
                float e2 = as.z + ald.z; e2 = e2 > 0.f ? e2 : SLOPE * e2;
                float e3 = as.w + ald.w; e3 = e3 > 0.f ? e3 : SLOPE * e3;
                m0 = fmaxf(m0, e0); m1 = fmaxf(m1, e1);
                m2 = fmaxf(m2, e2); m3 = fmaxf(m3, e3);
            }
#pragma unroll
            for (int off = 1; off < 64; off <<= 1) {
                m0 = fmaxf(m0, __shfl_xor(m0, off, 64));
                m1 = fmaxf(m1, __shfl_xor(m1, off, 64));
                m2 = fmaxf(m2, __shfl_xor(m2, off, 64));
                m3 = fmaxf(m3, __shfl_xor(m3, off, 64));
            }
            float d0 = 0.f, d1 = 0.f, d2 = 0.f, d3 = 0.f;
            for (int j = start + lane; j < end; j += 64) {
                int s = col[j];
                float4 as = *(const float4*)&al_s[s * 4];
                float e0 = as.x + ald.x; e0 = e0 > 0.f ? e0 : SLOPE * e0;
                float e1 = as.y + ald.y; e1 = e1 > 0.f ? e1 : SLOPE * e1;
                float e2 = as.z + ald.z; e2 = e2 > 0.f ? e2 : SLOPE * e2;
                float e3 = as.w + ald.w; e3 = e3 > 0.f ? e3 : SLOPE * e3;
                d0 += expf(e0 - m0); d1 += expf(e1 - m1);
                d2 += expf(e2 - m2); d3 += expf(e3 - m3);
            }
#pragma unroll
            for (int off = 1; off < 64; off <<= 1) {
                d0 += __shfl_xor(d0, off, 64);
                d1 += __shfl_xor(d1, off, 64);
                d2 += __shfl_xor(d2, off, 64);
                d3 += __shfl_xor(d3, off, 64);
            }
            float inv0 = 1.f / (d0 + 1e-16f), inv1 = 1.f / (d1 + 1e-16f);
            float inv2 = 1.f / (d2 + 1e-16f), inv3 = 1.f / (d3 + 1e-16f);
            float m_h   = head == 0 ? m0   : head == 1 ? m1   : head == 2 ? m2   : m3;
            float inv_h = head == 0 ? inv0 : head == 1 ? inv1 : head == 2 ? inv2 : inv3;
            for (int jb = start; jb < end; jb += 64) {
                int j = jb + lane;
                int cs = (j < end) ? col[j] : 0;
                int cnt2 = min(64, end - jb);
                for (int t = 0; t < cnt2; ++t) {
                    int s = __shfl(cs, t, 64);
                    float als2 = al_s[s * 4 + head];
                    float e = als2 + ald_h; e = e > 0.f ? e : SLOPE * e;
                    float wv = expf(e - m_h) * inv_h;
                    float2 raw = *(const float2*)&hh[(size_t)s * HC + lane * 4];
                    float2 f0 = __half22float2(*(__half2*)&raw.x);
                    float2 f1 = __half22float2(*(__half2*)&raw.y);
                    ax = fmaf(wv, f0.x, ax); ay = fmaf(wv, f0.y, ay);
                    az = fmaf(wv, f1.x, az); aw = fmaf(wv, f1.y, aw);
                }
            }
        }

        if (mode == 0) {
            float4 b4 = *(const float4*)&bias[lane * 4];
            float vx = ax + b4.x; vx = vx > 0.f ? vx : expm1f(vx);
            float vy = ay + b4.y; vy = vy > 0.f ? vy : expm1f(vy);
            float vz = az + b4.z; vz = vz > 0.f ? vz : expm1f(vz);
            float vw = aw + b4.w; vw = vw > 0.f ? vw : expm1f(vw);
            float4 v = make_float4(vx, vy, vz, vw);
            *(float4*)&out[(size_t)node * HC + lane * 4] = v;
        } else {
#pragma unroll
            for (int off = 16; off < 64; off <<= 1) {
                ax += __shfl_xor(ax, off, 64);
                ay += __shfl_xor(ay, off, 64);
                az += __shfl_xor(az, off, 64);
                aw += __shfl_xor(aw, off, 64);
            }
            if (lane < 16) {
                float4 b4 = *(const float4*)&bias[lane * 4];
                float4 v = make_float4(ax * 0.25f + b4.x, ay * 0.25f + b4.y,
                                       az * 0.25f + b4.z, aw * 0.25f + b4.w);
                *(float4*)&out[(size_t)node * 64 + lane * 4] = v;
            }
        }
    }
}

// ---------------- pooling + MLP ----------------------------------------------
__global__ void pool_zero(float* __restrict__ pooled) {
    int i = blockIdx.x * blockDim.x + threadIdx.x;
    if (i < B_GR * 64) pooled[i] = 0.f;
}

__global__ __launch_bounds__(256) void pool_kernel(const float* __restrict__ act,
        const int* __restrict__ batch, float* __restrict__ pooled) {
    int b = blockIdx.x;
    int chunk = blockIdx.y;          // 0..15
    int warp = threadIdx.x >> 6;     // 0..3
    int lane = threadIdx.x & 63;
    int lo = 0, hi = N_NODES;
    while (lo < hi) { int mid = (lo + hi) >> 1; if (batch[mid] < b) lo = mid + 1; else hi = mid; }
    int s = lo;
    lo = 0; hi = N_NODES;
    while (lo < hi) { int mid = (lo + hi) >> 1; if (batch[mid] < b + 1) lo = mid + 1; else hi = mid; }
    int e = lo;
    float sum = 0.f;
    for (int n = s + chunk * 4 + warp; n < e; n += 64)
        sum += act[(size_t)n * 64 + lane];
    atomicAdd(&pooled[b * 64 + lane], sum);
}

__global__ __launch_bounds__(64) void mlp_kernel(const float* __restrict__ pooled,
        const int* __restrict__ batch,
        const float* __restrict__ pW1, const float* __restrict__ pb1,
        const float* __restrict__ pW2, const float* __restrict__ pb2,
        float* __restrict__ outp) {
    __shared__ float p[64];
    __shared__ float z[32];
    int b = blockIdx.x, t = threadIdx.x;
    int lo = 0, hi = N_NODES;
    while (lo < hi) { int mid = (lo + hi) >> 1; if (batch[mid] < b) lo = mid + 1; else hi = mid; }
    int s = lo;
    lo = 0; hi = N_NODES;
    while (lo < hi) { int mid = (lo + hi) >> 1; if (batch[mid] < b + 1) lo = mid + 1; else hi = mid; }
    int e = lo;
    float inv = 1.f / (float)max(e - s, 1);
    p[t] = pooled[b * 64 + t] * inv;
    __syncthreads();
    if (t < 32) {
        float s2 = pb1[t];
        for (int c = 0; c < 64; ++c) s2 += p[c] * pW1[c * 32 + t];
        z[t] = s2 > 0.f ? s2 : 0.f;
    }
    __syncthreads();
    if (t < OUT_DIM) {
        float s2 = pb2[t];
        for (int k = 0; k < 32; ++k) s2 += z[k] * pW2[k * 10 + t];
        outp[b * 10 + t] = s2;
    }
}

// ---------------- launch ------------------------------------------------------
extern "C" void kernel_launch(void* const* d_in, const int* in_sizes, int n_in,
                              void* d_out, int out_size, void* d_ws, size_t ws_size,
                              hipStream_t stream) {
    const float* x    = (const float*)d_in[0];
    const int*   ei   = (const int*)d_in[1];
    const int*   batch= (const int*)d_in[2];
    const float* W0   = (const float*)d_in[3];
    const float* b0   = (const float*)d_in[4];
    const float* as0  = (const float*)d_in[5];
    const float* ad0  = (const float*)d_in[6];
    const float* W1   = (const float*)d_in[7];
    const float* b1   = (const float*)d_in[8];
    const float* as1  = (const float*)d_in[9];
    const float* ad1  = (const float*)d_in[10];
    const float* W2   = (const float*)d_in[11];
    const float* b2   = (const float*)d_in[12];
    const float* as2  = (const float*)d_in[13];
    const float* ad2  = (const float*)d_in[14];
    const float* pW1  = (const float*)d_in[15];
    const float* pb1  = (const float*)d_in[16];
    const float* pW2  = (const float*)d_in[17];
    const float* pb2  = (const float*)d_in[18];
    float* out = (float*)d_out;

    char* ws = (char*)d_ws;
    size_t off = 0;
    auto alloc = [&](size_t bytes) -> void* {
        void* p = ws + off;
        off += (bytes + 255) & ~(size_t)255;
        return p;
    };
    __half* h_half = (__half*)alloc((size_t)N_NODES * HC * 2);
    float* act    = (float*)alloc((size_t)N_NODES * HC * 4);
    float* als    = (float*)alloc((size_t)N_NODES * 4 * 4);
    float* ald    = (float*)alloc((size_t)N_NODES * 4 * 4);
    int*   cnt    = (int*)alloc((size_t)N_NODES * 4);
    int*   row_ptr= (int*)alloc((size_t)(N_NODES + 1) * 4);
    int*   cursor = (int*)alloc((size_t)N_NODES * 4);
    int*   col    = (int*)alloc((size_t)(E_EDGES + N_NODES) * 4);
    float* pooled = (float*)alloc((size_t)B_GR * 64 * 4);
    int*   bsum   = (int*)alloc((size_t)NBLK_SCAN * 4);
    int*   boff   = (int*)alloc((size_t)NBLK_SCAN * 4);
    _Float16* w0h = (_Float16*)alloc((size_t)128 * 256 * 2);
    _Float16* w0l = (_Float16*)alloc((size_t)128 * 256 * 2);
    _Float16* w1h = (_Float16*)alloc((size_t)256 * 256 * 2);
    _Float16* w1l = (_Float16*)alloc((size_t)256 * 256 * 2);
    _Float16* w2h = (_Float16*)alloc((size_t)256 * 256 * 2);
    _Float16* w2l = (_Float16*)alloc((size_t)256 * 256 * 2);

    const int* srcs = ei;
    const int* dsts = ei + E_EDGES;

    // weight splits (tiny)
    wsplit_kernel<<<(128 * 256 + 255) / 256, 256, 0, stream>>>(W0, w0h, w0l, 128);
    wsplit_kernel<<<(256 * 256 + 255) / 256, 256, 0, stream>>>(W1, w1h, w1l, 256);
    wsplit_kernel<<<(256 * 256 + 255) / 256, 256, 0, stream>>>(W2, w2h, w2l, 256);

    // CSR by dst (graph static within call; reused by all 3 layers)
    init_cnt<<<(N_NODES + 255) / 256, 256, 0, stream>>>(cnt);
    hist_kernel<<<(E_EDGES + 255) / 256, 256, 0, stream>>>(dsts, cnt);
    scan_bsum<<<NBLK_SCAN, 256, 0, stream>>>(cnt, bsum);
    scan_boff<<<1, 256, 0, stream>>>(bsum, boff);
    scan_final<<<NBLK_SCAN, 256, 0, stream>>>(cnt, boff, row_ptr, cursor);
    scatter_kernel<<<(E_EDGES + N_NODES + 255) / 256, 256, 0, stream>>>(srcs, dsts, cursor, col);

    int gblk = (N_NODES + 63) / 64;   // 782
    int nblk = (N_NODES + 7) / 8;     // 6250 (2 nodes per wave, 4 waves/block)

    // layer 0
    gemm_mfma<128><<<gblk, 256, 0, stream>>>(x, w0h, w0l, h_half, as0, ad0, als, ald, N_NODES);
    agg_kernel<<<nblk, 256, 0, stream>>>(h_half, als, ald, row_ptr, col, b0, act, 0);
    // layer 1
    gemm_mfma<256><<<gblk, 256, 0, stream>>>(act, w1h, w1l, h_half, as1, ad1, als, ald, N_NODES);
    agg_kernel<<<nblk, 256, 0, stream>>>(h_half, als, ald, row_ptr, col, b1, act, 0);
    // layer 2 (mean heads, no ELU)
    gemm_mfma<256><<<gblk, 256, 0, stream>>>(act, w2h, w2l, h_half, as2, ad2, als, ald, N_NODES);
    agg_kernel<<<nblk, 256, 0, stream>>>(h_half, als, ald, row_ptr, col, b2, act, 1);

    pool_zero<<<(B_GR * 64 + 255) / 256, 256, 0, stream>>>(pooled);
    dim3 pgrid(B_GR, 16);
    pool_kernel<<<pgrid, 256, 0, stream>>>(act, batch, pooled);
    mlp_kernel<<<B_GR, 64, 0, stream>>>(pooled, batch, pW1, pb1, pW2, pb2, out);
}

// Round 8
// 425.296 us; speedup vs baseline: 2.5207x; 1.0464x over previous
//
#include <hip/hip_runtime.h>
#include <hip/hip_fp16.h>
#include <cstdint>

#define N_NODES 50000
#define E_EDGES 800000
#define HC 256           // H*C
#define B_GR 64
#define OUT_DIM 10
#define SLOPE 0.2f
#define NBLK_SCAN ((N_NODES + 255) / 256)   // 196

using f16x8 = __attribute__((ext_vector_type(8))) _Float16;
using f32x4 = __attribute__((ext_vector_type(4))) float;

#define GLOAD_LDS16(gsrc, ldst) \
    __builtin_amdgcn_global_load_lds((const __attribute__((address_space(1))) void*)(gsrc), \
        (__attribute__((address_space(3))) void*)(ldst), 16, 0, 0)

// ---------------- W split prep ------------------------------------------------
// W[K x 256] fp32 -> hi/lo fp16 in fragment-major layout [K/32][256][kg=4][j=8]
// so each wave B-fragment load is one contiguous 1KB block (fully coalesced).
__global__ void wsplit_kernel(const float* __restrict__ W, _Float16* __restrict__ wt_hi,
                              _Float16* __restrict__ wt_lo, int K) {
    int i = blockIdx.x * 256 + threadIdx.x;
    if (i >= K * 256) return;
    int k = i >> 8, n = i & 255;           // W[k][n], coalesced read
    float v = W[i];
    _Float16 h = (_Float16)v;
    _Float16 l = (_Float16)(v - (float)h);
    int oidx = ((((k >> 5) * 256 + n) * 4) + ((k >> 3) & 3)) * 8 + (k & 7);
    wt_hi[oidx] = h;
    wt_lo[oidx] = l;
}

// ---------------- MFMA GEMM (layer 0): A fp32, 3-term split -------------------
template<int K>
__global__ __launch_bounds__(256) void gemm_mfma(const float* __restrict__ A,
        const _Float16* __restrict__ wt_hi, const _Float16* __restrict__ wt_lo,
        __half* __restrict__ h_half,
        const float* __restrict__ a_src, const float* __restrict__ a_dst,
        float* __restrict__ al_s, float* __restrict__ al_d, int M) {
    __shared__ _Float16 a_hi[64][64];
    __shared__ _Float16 a_lo[64][64];
    int tid = threadIdx.x;
    int w = tid >> 6;           // wave 0..3 -> head / col quadrant
    int l = tid & 63;           // lane
    int rr = l & 15;            // frag row/col index
    int kg = l >> 4;            // k-group 0..3 within 32-k chunk
    int row0 = blockIdx.x * 64;
    int lrow = tid >> 2;        // staging row 0..63
    int lgp  = (tid & 3) * 2;   // staging k-group pair base (groups of 8)

    f32x4 acc[4][4] = {};

    for (int k0 = 0; k0 < K; k0 += 64) {
        if (k0 > 0) __syncthreads();
        int gr = row0 + lrow;
#pragma unroll
        for (int gi = 0; gi < 2; ++gi) {
            int g = lgp + gi;
            float vv[8];
            if (gr < M) {
                float4 p = *(const float4*)&A[(size_t)gr * K + k0 + g * 8];
                float4 q = *(const float4*)&A[(size_t)gr * K + k0 + g * 8 + 4];
                vv[0] = p.x; vv[1] = p.y; vv[2] = p.z; vv[3] = p.w;
                vv[4] = q.x; vv[5] = q.y; vv[6] = q.z; vv[7] = q.w;
            } else {
#pragma unroll
                for (int j = 0; j < 8; ++j) vv[j] = 0.f;
            }
            f16x8 vh, vl;
#pragma unroll
            for (int j = 0; j < 8; ++j) {
                _Float16 hh = (_Float16)vv[j];
                vh[j] = hh;
                vl[j] = (_Float16)(vv[j] - (float)hh);
            }
            int gs = g ^ (lrow & 7);
            *(f16x8*)&a_hi[lrow][gs * 8] = vh;
            *(f16x8*)&a_lo[lrow][gs * 8] = vl;
        }
        __syncthreads();
#pragma unroll
        for (int c = 0; c < 2; ++c) {
            f16x8 ah[4], alo[4];
#pragma unroll
            for (int fm = 0; fm < 4; ++fm) {
                int row = fm * 16 + rr;
                int gsw = ((c * 4 + kg) ^ (row & 7));
                ah[fm]  = *(const f16x8*)&a_hi[row][gsw * 8];
                alo[fm] = *(const f16x8*)&a_lo[row][gsw * 8];
            }
            int chunk = (k0 >> 5) + c;
#pragma unroll
            for (int fn = 0; fn < 4; ++fn) {
                int col = w * 64 + fn * 16 + rr;
                size_t boff = (((size_t)chunk * 256 + col) * 4 + kg) * 8;
                f16x8 bh = *(const f16x8*)&wt_hi[boff];
                f16x8 bl = *(const f16x8*)&wt_lo[boff];
#pragma unroll
                for (int fm = 0; fm < 4; ++fm) {
                    acc[fm][fn] = __builtin_amdgcn_mfma_f32_16x16x32_f16(ah[fm],  bh, acc[fm][fn], 0, 0, 0);
                    acc[fm][fn] = __builtin_amdgcn_mfma_f32_16x16x32_f16(ah[fm],  bl, acc[fm][fn], 0, 0, 0);
                    acc[fm][fn] = __builtin_amdgcn_mfma_f32_16x16x32_f16(alo[fm], bh, acc[fm][fn], 0, 0, 0);
                }
            }
        }
    }

    // ---- epilogue: fp16 h + per-head logits (head = wave) ----
    int head = w;
    float asv[4], adv[4];
#pragma unroll
    for (int fn = 0; fn < 4; ++fn) {
        asv[fn] = a_src[head * 64 + fn * 16 + rr];
        adv[fn] = a_dst[head * 64 + fn * 16 + rr];
    }
#pragma unroll
    for (int fm = 0; fm < 4; ++fm) {
#pragma unroll
        for (int r = 0; r < 4; ++r) {
            int row = fm * 16 + kg * 4 + r;     // C/D: row=(lane>>4)*4+reg
            int gr = row0 + row;
            float ps = acc[fm][0][r] * asv[0] + acc[fm][1][r] * asv[1]
                     + acc[fm][2][r] * asv[2] + acc[fm][3][r] * asv[3];
            float pd = acc[fm][0][r] * adv[0] + acc[fm][1][r] * adv[1]
                     + acc[fm][2][r] * adv[2] + acc[fm][3][r] * adv[3];
#pragma unroll
            for (int off = 1; off < 16; off <<= 1) {
                ps += __shfl_xor(ps, off, 64);
                pd += __shfl_xor(pd, off, 64);
            }
            if (gr < M) {
#pragma unroll
                for (int fn = 0; fn < 4; ++fn)
                    h_half[(size_t)gr * HC + w * 64 + fn * 16 + rr] = __float2half(acc[fm][fn][r]);
                if (rr == 0) {
                    al_s[gr * 4 + head] = ps;
                    al_d[gr * 4 + head] = pd;
                }
            }
        }
    }
}

// ---------------- MFMA GEMM (layers 1-2): A fp16 exact, 2-term ----------------
// A (= act) already quantized to fp16 -> lo(A)==0, so only A*(Whi+Wlo) needed.
// Staging via global_load_lds: linear LDS dest, inverse-swizzled global source
// (involution g^(row&7)), zero staging VALU.
template<int K>
__global__ __launch_bounds__(256) void gemm_fp16(const _Float16* __restrict__ A,
        const _Float16* __restrict__ wt_hi, const _Float16* __restrict__ wt_lo,
        __half* __restrict__ h_half,
        const float* __restrict__ a_src, const float* __restrict__ a_dst,
        float* __restrict__ al_s, float* __restrict__ al_d, int M) {
    __shared__ _Float16 a16[64][64];   // 8 KB tile
    int tid = threadIdx.x;
    int w = tid >> 6;
    int l = tid & 63;
    int rr = l & 15;
    int kg = l >> 4;
    int row0 = blockIdx.x * 64;
    int srow = tid >> 3;        // staging row (within half-tile) 0..31
    int sgs  = tid & 7;         // staging k-group slot (linear LDS)

    f32x4 acc[4][4] = {};

    for (int k0 = 0; k0 < K; k0 += 64) {
        if (k0 > 0) __syncthreads();
        // issue 2 direct-to-LDS loads; each wave fills a contiguous 1KB chunk
#pragma unroll
        for (int i = 0; i < 2; ++i) {
            int row = i * 32 + srow;
            int g   = sgs ^ (row & 7);           // inverse swizzle on SOURCE
            int gr  = min(row0 + row, M - 1);    // clamp (rows >= M unused)
            const _Float16* src = &A[(size_t)gr * K + k0 + g * 8];
            char* ldsbase = (char*)&a16[0][0] + i * 4096 + w * 1024;  // wave-uniform
            GLOAD_LDS16(src, ldsbase);
        }
        __syncthreads();
#pragma unroll
        for (int c = 0; c < 2; ++c) {
            f16x8 ah[4];
#pragma unroll
            for (int fm = 0; fm < 4; ++fm) {
                int row = fm * 16 + rr;
                int gsw = ((c * 4 + kg) ^ (row & 7));   // swizzle on READ
                ah[fm] = *(const f16x8*)&a16[row][gsw * 8];
            }
            int chunk = (k0 >> 5) + c;
#pragma unroll
            for (int fn = 0; fn < 4; ++fn) {
                int col = w * 64 + fn * 16 + rr;
                size_t boff = (((size_t)chunk * 256 + col) * 4 + kg) * 8;
                f16x8 bh = *(const f16x8*)&wt_hi[boff];
                f16x8 bl = *(const f16x8*)&wt_lo[boff];
#pragma unroll
                for (int fm = 0; fm < 4; ++fm) {
                    acc[fm][fn] = __builtin_amdgcn_mfma_f32_16x16x32_f16(ah[fm], bh, acc[fm][fn], 0, 0, 0);
                    acc[fm][fn] = __builtin_amdgcn_mfma_f32_16x16x32_f16(ah[fm], bl, acc[fm][fn], 0, 0, 0);
                }
            }
        }
    }

    // ---- epilogue: fp16 h + per-head logits (head = wave) ----
    int head = w;
    float asv[4], adv[4];
#pragma unroll
    for (int fn = 0; fn < 4; ++fn) {
        asv[fn] = a_src[head * 64 + fn * 16 + rr];
        adv[fn] = a_dst[head * 64 + fn * 16 + rr];
    }
#pragma unroll
    for (int fm = 0; fm < 4; ++fm) {
#pragma unroll
        for (int r = 0; r < 4; ++r) {
            int row = fm * 16 + kg * 4 + r;
            int gr = row0 + row;
            float ps = acc[fm][0][r] * asv[0] + acc[fm][1][r] * asv[1]
                     + acc[fm][2][r] * asv[2] + acc[fm][3][r] * asv[3];
            float pd = acc[fm][0][r] * adv[0] + acc[fm][1][r] * adv[1]
                     + acc[fm][2][r] * adv[2] + acc[fm][3][r] * adv[3];
#pragma unroll
            for (int off = 1; off < 16; off <<= 1) {
                ps += __shfl_xor(ps, off, 64);
                pd += __shfl_xor(pd, off, 64);
            }
            if (gr < M) {
#pragma unroll
                for (int fn = 0; fn < 4; ++fn)
                    h_half[(size_t)gr * HC + w * 64 + fn * 16 + rr] = __float2half(acc[fm][fn][r]);
                if (rr == 0) {
                    al_s[gr * 4 + head] = ps;
                    al_d[gr * 4 + head] = pd;
                }
            }
        }
    }
}

// ---------------- CSR build (counting sort by dst) ---------------------------
__global__ void init_cnt(int* cnt) {
    int i = blockIdx.x * blockDim.x + threadIdx.x;
    if (i < N_NODES) cnt[i] = 1;   // self-loop pre-counted
}
__global__ void hist_kernel(const int* __restrict__ dsts, int* cnt) {
    int i = blockIdx.x * blockDim.x + threadIdx.x;
    if (i < E_EDGES) atomicAdd(&cnt[dsts[i]], 1);
}
__global__ __launch_bounds__(256) void scan_bsum(const int* __restrict__ cnt,
                                                 int* __restrict__ bsum) {
    __shared__ int ws[4];
    int t = threadIdx.x;
    int i = blockIdx.x * 256 + t;
    int v = (i < N_NODES) ? cnt[i] : 0;
#pragma unroll
    for (int off = 1; off < 64; off <<= 1) v += __shfl_xor(v, off, 64);
    if ((t & 63) == 0) ws[t >> 6] = v;
    __syncthreads();
    if (t == 0) bsum[blockIdx.x] = ws[0] + ws[1] + ws[2] + ws[3];
}
__global__ __launch_bounds__(256) void scan_boff(const int* __restrict__ bsum,
                                                 int* __restrict__ boff) {
    __shared__ int s[256];
    int t = threadIdx.x;
    int v = (t < NBLK_SCAN) ? bsum[t] : 0;
    s[t] = v;
    __syncthreads();
    for (int off = 1; off < 256; off <<= 1) {
        int u = (t >= off) ? s[t - off] : 0;
        __syncthreads();
        s[t] += u;
        __syncthreads();
    }
    if (t < NBLK_SCAN) boff[t] = s[t] - v;   // exclusive
}
__global__ __launch_bounds__(256) void scan_final(const int* __restrict__ cnt,
        const int* __restrict__ boff, int* __restrict__ row_ptr,
        int* __restrict__ cursor) {
    __shared__ int s[256];
    int b = blockIdx.x, t = threadIdx.x;
    int i = b * 256 + t;
    int v = (i < N_NODES) ? cnt[i] : 0;
    s[t] = v;
    __syncthreads();
    for (int off = 1; off < 256; off <<= 1) {
        int u = (t >= off) ? s[t - off] : 0;
        __syncthreads();
        s[t] += u;
        __syncthreads();
    }
    int rp = boff[b] + s[t] - v;   // exclusive prefix
    if (i < N_NODES) { row_ptr[i] = rp; cursor[i] = rp; }
    if (i == N_NODES - 1) row_ptr[N_NODES] = rp + v;   // = E+N total
}
__global__ void scatter_kernel(const int* __restrict__ srcs, const int* __restrict__ dsts,
                               int* cursor, int* col) {
    int i = blockIdx.x * blockDim.x + threadIdx.x;
    if (i >= E_EDGES + N_NODES) return;
    int s, d;
    if (i < E_EDGES) { s = srcs[i]; d = dsts[i]; }
    else             { s = d = i - E_EDGES; }     // self loops
    int pos = atomicAdd(&cursor[d], 1);
    col[pos] = s;
}

// ---------------- per-node softmax + aggregation -----------------------------
// mode 0: concat heads, +bias[256], ELU, fp16 out (act_h).
// mode 1: mean heads, +bias[64], no ELU, fp32 out (act_f).
__global__ __launch_bounds__(256) void agg_kernel(const __half* __restrict__ hh,
        const float* __restrict__ al_s, const float* __restrict__ al_d,
        const int* __restrict__ row_ptr, const int* __restrict__ col,
        const float* __restrict__ bias, _Float16* __restrict__ out_h,
        float* __restrict__ out_f, int mode) {
    __shared__ int   lds_col[4][64];
    __shared__ float lds_alpha[4][64][4];
    int wid  = threadIdx.x >> 6;
    int lane = threadIdx.x & 63;
    int hf   = lane >> 5;
    int ln   = lane & 31;
    int nodeA = blockIdx.x * 8 + wid * 2;   // N_NODES % 8 == 0 -> no tail
    int nodeB = nodeA + 1;
    int sA = row_ptr[nodeA], eA = row_ptr[nodeA + 1];
    int sB = row_ptr[nodeB], eB = row_ptr[nodeB + 1];
    int degA = eA - sA, degB = eB - sB;

    if (degA <= 32 && degB <= 32) {
        // ================= fast path: 2 nodes / wave =================
        int node  = hf ? nodeB : nodeA;
        int start = hf ? sB : sA;
        int deg   = hf ? degB : degA;
        int degmax = max(degA, degB);
        const float4 ald = *(const float4*)&al_d[node * 4];
        bool active = ln < deg;
        int s = active ? col[start + ln] : 0;
        float4 as = *(const float4*)&al_s[s * 4];
        float e0 = as.x + ald.x; e0 = e0 > 0.f ? e0 : SLOPE * e0;
        float e1 = as.y + ald.y; e1 = e1 > 0.f ? e1 : SLOPE * e1;
        float e2 = as.z + ald.z; e2 = e2 > 0.f ? e2 : SLOPE * e2;
        float e3 = as.w + ald.w; e3 = e3 > 0.f ? e3 : SLOPE * e3;
        float m0 = active ? e0 : -1e30f, m1 = active ? e1 : -1e30f;
        float m2 = active ? e2 : -1e30f, m3 = active ? e3 : -1e30f;
#pragma unroll
        for (int off = 1; off < 32; off <<= 1) {   // width-32: stays in half
            m0 = fmaxf(m0, __shfl_xor(m0, off, 64));
            m1 = fmaxf(m1, __shfl_xor(m1, off, 64));
            m2 = fmaxf(m2, __shfl_xor(m2, off, 64));
            m3 = fmaxf(m3, __shfl_xor(m3, off, 64));
        }
        float x0 = active ? expf(e0 - m0) : 0.f;
        float x1 = active ? expf(e1 - m1) : 0.f;
        float x2 = active ? expf(e2 - m2) : 0.f;
        float x3 = active ? expf(e3 - m3) : 0.f;
        float d0 = x0, d1 = x1, d2 = x2, d3 = x3;
#pragma unroll
        for (int off = 1; off < 32; off <<= 1) {
            d0 += __shfl_xor(d0, off, 64);
            d1 += __shfl_xor(d1, off, 64);
            d2 += __shfl_xor(d2, off, 64);
            d3 += __shfl_xor(d3, off, 64);
        }
        float4 a4;
        a4.x = x0 / (d0 + 1e-16f); a4.y = x1 / (d1 + 1e-16f);
        a4.z = x2 / (d2 + 1e-16f); a4.w = x3 / (d3 + 1e-16f);
        int e = hf * 32 + ln;
        lds_col[wid][e] = s;
        *(float4*)&lds_alpha[wid][e][0] = a4;
        int head = ln >> 3;
        int ch0 = ln * 8;
        float acc[8] = {0.f, 0.f, 0.f, 0.f, 0.f, 0.f, 0.f, 0.f};
        int ebase = hf * 32;
        for (int t0 = 0; t0 < degmax; t0 += 4) {
            float wv[4]; float4 raw[4];
#pragma unroll
            for (int k = 0; k < 4; ++k) {
                int t = t0 + k;
                int tt = min(t, deg - 1);          // deg >= 1 (self-loop)
                int s2 = lds_col[wid][ebase + tt];
                wv[k] = (t < deg) ? lds_alpha[wid][ebase + tt][head] : 0.f;
                raw[k] = *(const float4*)&hh[(size_t)s2 * HC + ch0];
            }
#pragma unroll
            for (int k = 0; k < 4; ++k) {
                const __half2* hp = (const __half2*)&raw[k];
                float2 f0 = __half22float2(hp[0]);
                float2 f1 = __half22float2(hp[1]);
                float2 f2 = __half22float2(hp[2]);
                float2 f3 = __half22float2(hp[3]);
                acc[0] = fmaf(wv[k], f0.x, acc[0]); acc[1] = fmaf(wv[k], f0.y, acc[1]);
                acc[2] = fmaf(wv[k], f1.x, acc[2]); acc[3] = fmaf(wv[k], f1.y, acc[3]);
                acc[4] = fmaf(wv[k], f2.x, acc[4]); acc[5] = fmaf(wv[k], f2.y, acc[5]);
                acc[6] = fmaf(wv[k], f3.x, acc[6]); acc[7] = fmaf(wv[k], f3.y, acc[7]);
            }
        }
        if (mode == 0) {
            float b8[8];
            *(float4*)&b8[0] = *(const float4*)&bias[ch0];
            *(float4*)&b8[4] = *(const float4*)&bias[ch0 + 4];
            _Float16 v[8];
#pragma unroll
            for (int j = 0; j < 8; ++j) {
                float t = acc[j] + b8[j];
                v[j] = (_Float16)(t > 0.f ? t : expm1f(t));
            }
            *(float4*)&out_h[(size_t)node * HC + ch0] = *(float4*)v;   // 16B
        } else {
#pragma unroll
            for (int j = 0; j < 8; ++j) {
                acc[j] += __shfl_xor(acc[j], 8, 64);
                acc[j] += __shfl_xor(acc[j], 16, 64);
            }
            if (ln < 8) {
                float v[8];
#pragma unroll
                for (int j = 0; j < 8; ++j)
                    v[j] = acc[j] * 0.25f + bias[ln * 8 + j];
                *(float4*)&out_f[(size_t)node * 64 + ln * 8]     = *(float4*)&v[0];
                *(float4*)&out_f[(size_t)node * 64 + ln * 8 + 4] = *(float4*)&v[4];
            }
        }
        return;
    }

    // ================= fallback: 1 node / wave (rare, deg>32) =================
    for (int nn = 0; nn < 2; ++nn) {
        int node = nodeA + nn;
        int start = row_ptr[node], end = row_ptr[node + 1];
        int deg = end - start;
        const float4 ald = *(const float4*)&al_d[node * 4];
        int head = lane >> 4;
        float ald_h = head == 0 ? ald.x : head == 1 ? ald.y : head == 2 ? ald.z : ald.w;
        float ax = 0.f, ay = 0.f, az = 0.f, aw = 0.f;

        if (deg <= 64) {
            int j = start + lane;
            bool active = j < end;
            int s = active ? col[j] : 0;
            float4 as = *(const float4*)&al_s[s * 4];
            float e0 = as.x + ald.x; e0 = e0 > 0.f ? e0 : SLOPE * e0;
            float e1 = as.y + ald.y; e1 = e1 > 0.f ? e1 : SLOPE * e1;
            float e2 = as.z + ald.z; e2 = e2 > 0.f ? e2 : SLOPE * e2;
            float e3 = as.w + ald.w; e3 = e3 > 0.f ? e3 : SLOPE * e3;
            float m0 = active ? e0 : -1e30f, m1 = active ? e1 : -1e30f;
            float m2 = active ? e2 : -1e30f, m3 = active ? e3 : -1e30f;
#pragma unroll
            for (int off = 1; off < 64; off <<= 1) {
                m0 = fmaxf(m0, __shfl_xor(m0, off, 64));
                m1 = fmaxf(m1, __shfl_xor(m1, off, 64));
                m2 = fmaxf(m2, __shfl_xor(m2, off, 64));
                m3 = fmaxf(m3, __shfl_xor(m3, off, 64));
            }
            float x0 = active ? expf(e0 - m0) : 0.f;
            float x1 = active ? expf(e1 - m1) : 0.f;
            float x2 = active ? expf(e2 - m2) : 0.f;
            float x3 = active ? expf(e3 - m3) : 0.f;
            float d0 = x0, d1 = x1, d2 = x2, d3 = x3;
#pragma unroll
            for (int off = 1; off < 64; off <<= 1) {
                d0 += __shfl_xor(d0, off, 64);
                d1 += __shfl_xor(d1, off, 64);
                d2 += __shfl_xor(d2, off, 64);
                d3 += __shfl_xor(d3, off, 64);
            }
            float4 a4;
            a4.x = x0 / (d0 + 1e-16f); a4.y = x1 / (d1 + 1e-16f);
            a4.z = x2 / (d2 + 1e-16f); a4.w = x3 / (d3 + 1e-16f);
            lds_col[wid][lane] = s;
            *(float4*)&lds_alpha[wid][lane][0] = a4;
            for (int t0 = 0; t0 < deg; t0 += 8) {
                int nr = deg - t0;
                float wv[8]; float2 raw[8];
#pragma unroll
                for (int k = 0; k < 8; ++k) {
                    if (k < nr) {
                        int s2 = lds_col[wid][t0 + k];
                        wv[k] = lds_alpha[wid][t0 + k][head];
                        raw[k] = *(const float2*)&hh[(size_t)s2 * HC + lane * 4];
                    } else {
                        wv[k] = 0.f;
                        raw[k] = make_float2(0.f, 0.f);
                    }
                }
#pragma unroll
                for (int k = 0; k < 8; ++k) {
                    float2 f0 = __half22float2(*(__half2*)&raw[k].x);
                    float2 f1 = __half22float2(*(__half2*)&raw[k].y);
                    ax = fmaf(wv[k], f0.x, ax); ay = fmaf(wv[k], f0.y, ay);
                    az = fmaf(wv[k], f1.x, az); aw = fmaf(wv[k], f1.y, aw);
                }
            }
        } else {
            float m0 = -1e30f, m1 = -1e30f, m2 = -1e30f, m3 = -1e30f;
            for (int j = start + lane; j < end; j += 64) {
                int s = col[j];
                float4 as = *(const float4*)&al_s[s * 4];
                float e0 = as.x + ald.x; e0 = e0 > 0.f ? e0 : SLOPE * e0;
                float e1 = as.y + ald.y; e1 = e1 > 0.f ? e1 : SLOPE * e1;
                float e2 = as.z + ald.z; e2 = e2 > 0.f ? e2 : SLOPE * e2;
                float e3 = as.w + ald.w; e3 = e3 > 0.f ? e3 : SLOPE * e3;
                m0 = fmaxf(m0, e0); m1 = fmaxf(m1, e1);
                m2 = fmaxf(m2, e2); m3 = fmaxf(m3, e3);
            }
#pragma unroll
            for (int off = 1; off < 64; off <<= 1) {
                m0 = fmaxf(m0, __shfl_xor(m0, off, 64));
                m1 = fmaxf(m1, __shfl_xor(m1, off, 64));
                m2 = fmaxf(m2, __shfl_xor(m2, off, 64));
                m3 = fmaxf(m3, __shfl_xor(m3, off, 64));
            }
            float d0 = 0.f, d1 = 0.f, d2 = 0.f, d3 = 0.f;
            for (int j = start + lane; j < end; j += 64) {
                int s = col[j];
                float4 as = *(const float4*)&al_s[s * 4];
                float e0 = as.x + ald.x; e0 = e0 > 0.f ? e0 : SLOPE * e0;
                float e1 = as.y + ald.y; e1 = e1 > 0.f ? e1 : SLOPE * e1;
                float e2 = as.z + ald.z; e2 = e2 > 0.f ? e2 : SLOPE * e2;
                float e3 = as.w + ald.w; e3 = e3 > 0.f ? e3 : SLOPE * e3;
                d0 += expf(e0 - m0); d1 += expf(e1 - m1);
                d2 += expf(e2 - m2); d3 += expf(e3 - m3);
            }
#pragma unroll
            for (int off = 1; off < 64; off <<= 1) {
                d0 += __shfl_xor(d0, off, 64);
                d1 += __shfl_xor(d1, off, 64);
                d2 += __shfl_xor(d2, off, 64);
                d3 += __shfl_xor(d3, off, 64);
            }
            float inv0 = 1.f / (d0 + 1e-16f), inv1 = 1.f / (d1 + 1e-16f);
            float inv2 = 1.f / (d2 + 1e-16f), inv3 = 1.f / (d3 + 1e-16f);
            float m_h   = head == 0 ? m0   : head == 1 ? m1   : head == 2 ? m2   : m3;
            float inv_h = head == 0 ? inv0 : head == 1 ? inv1 : head == 2 ? inv2 : inv3;
            for (int jb = start; jb < end; jb += 64) {
                int j = jb + lane;
                int cs = (j < end) ? col[j] : 0;
                int cnt2 = min(64, end - jb);
                for (int t = 0; t < cnt2; ++t) {
                    int s = __shfl(cs, t, 64);
                    float als2 = al_s[s * 4 + head];
                    float e = als2 + ald_h; e = e > 0.f ? e : SLOPE * e;
                    float wv = expf(e - m_h) * inv_h;
                    float2 raw = *(const float2*)&hh[(size_t)s * HC + lane * 4];
                    float2 f0 = __half22float2(*(__half2*)&raw.x);
                    float2 f1 = __half22float2(*(__half2*)&raw.y);
                    ax = fmaf(wv, f0.x, ax); ay = fmaf(wv, f0.y, ay);
                    az = fmaf(wv, f1.x, az); aw = fmaf(wv, f1.y, aw);
                }
            }
        }

        if (mode == 0) {
            float4 b4 = *(const float4*)&bias[lane * 4];
            float vx = ax + b4.x; vx = vx > 0.f ? vx : expm1f(vx);
            float vy = ay + b4.y; vy = vy > 0.f ? vy : expm1f(vy);
            float vz = az + b4.z; vz = vz > 0.f ? vz : expm1f(vz);
            float vw = aw + b4.w; vw = vw > 0.f ? vw : expm1f(vw);
            _Float16 v[4] = {(_Float16)vx, (_Float16)vy, (_Float16)vz, (_Float16)vw};
            *(float2*)&out_h[(size_t)node * HC + lane * 4] = *(float2*)v;   // 8B
        } else {
#pragma unroll
            for (int off = 16; off < 64; off <<= 1) {
                ax += __shfl_xor(ax, off, 64);
                ay += __shfl_xor(ay, off, 64);
                az += __shfl_xor(az, off, 64);
                aw += __shfl_xor(aw, off, 64);
            }
            if (lane < 16) {
                float4 b4 = *(const float4*)&bias[lane * 4];
                float4 v = make_float4(ax * 0.25f + b4.x, ay * 0.25f + b4.y,
                                       az * 0.25f + b4.z, aw * 0.25f + b4.w);
                *(float4*)&out_f[(size_t)node * 64 + lane * 4] = v;
            }
        }
    }
}

// ---------------- pooling + MLP ----------------------------------------------
__global__ void pool_zero(float* __restrict__ pooled) {
    int i = blockIdx.x * blockDim.x + threadIdx.x;
    if (i < B_GR * 64) pooled[i] = 0.f;
}

__global__ __launch_bounds__(256) void pool_kernel(const float* __restrict__ act,
        const int* __restrict__ batch, float* __restrict__ pooled) {
    int b = blockIdx.x;
    int chunk = blockIdx.y;          // 0..15
    int warp = threadIdx.x >> 6;     // 0..3
    int lane = threadIdx.x & 63;
    int lo = 0, hi = N_NODES;
    while (lo < hi) { int mid = (lo + hi) >> 1; if (batch[mid] < b) lo = mid + 1; else hi = mid; }
    int s = lo;
    lo = 0; hi = N_NODES;
    while (lo < hi) { int mid = (lo + hi) >> 1; if (batch[mid] < b + 1) lo = mid + 1; else hi = mid; }
    int e = lo;
    float sum = 0.f;
    for (int n = s + chunk * 4 + warp; n < e; n += 64)
        sum += act[(size_t)n * 64 + lane];
    atomicAdd(&pooled[b * 64 + lane], sum);
}

__global__ __launch_bounds__(64) void mlp_kernel(const float* __restrict__ pooled,
        const int* __restrict__ batch,
        const float* __restrict__ pW1, const float* __restrict__ pb1,
        const float* __restrict__ pW2, const float* __restrict__ pb2,
        float* __restrict__ outp) {
    __shared__ float p[64];
    __shared__ float z[32];
    int b = blockIdx.x, t = threadIdx.x;
    int lo = 0, hi = N_NODES;
    while (lo < hi) { int mid = (lo + hi) >> 1; if (batch[mid] < b) lo = mid + 1; else hi = mid; }
    int s = lo;
    lo = 0; hi = N_NODES;
    while (lo < hi) { int mid = (lo + hi) >> 1; if (batch[mid] < b + 1) lo = mid + 1; else hi = mid; }
    int e = lo;
    float inv = 1.f / (float)max(e - s, 1);
    p[t] = pooled[b * 64 + t] * inv;
    __syncthreads();
    if (t < 32) {
        float s2 = pb1[t];
        for (int c = 0; c < 64; ++c) s2 += p[c] * pW1[c * 32 + t];
        z[t] = s2 > 0.f ? s2 : 0.f;
    }
    __syncthreads();
    if (t < OUT_DIM) {
        float s2 = pb2[t];
        for (int k = 0; k < 32; ++k) s2 += z[k] * pW2[k * 10 + t];
        outp[b * 10 + t] = s2;
    }
}

// ---------------- launch ------------------------------------------------------
extern "C" void kernel_launch(void* const* d_in, const int* in_sizes, int n_in,
                              void* d_out, int out_size, void* d_ws, size_t ws_size,
                              hipStream_t stream) {
    const float* x    = (const float*)d_in[0];
    const int*   ei   = (const int*)d_in[1];
    const int*   batch= (const int*)d_in[2];
    const float* W0   = (const float*)d_in[3];
    const float* b0   = (const float*)d_in[4];
    const float* as0  = (const float*)d_in[5];
    const float* ad0  = (const float*)d_in[6];
    const float* W1   = (const float*)d_in[7];
    const float* b1   = (const float*)d_in[8];
    const float* as1  = (const float*)d_in[9];
    const float* ad1  = (const float*)d_in[10];
    const float* W2   = (const float*)d_in[11];
    const float* b2   = (const float*)d_in[12];
    const float* as2  = (const float*)d_in[13];
    const float* ad2  = (const float*)d_in[14];
    const float* pW1  = (const float*)d_in[15];
    const float* pb1  = (const float*)d_in[16];
    const float* pW2  = (const float*)d_in[17];
    const float* pb2  = (const float*)d_in[18];
    float* out = (float*)d_out;

    char* ws = (char*)d_ws;
    size_t off = 0;
    auto alloc = [&](size_t bytes) -> void* {
        void* p = ws + off;
        off += (bytes + 255) & ~(size_t)255;
        return p;
    };
    __half*    h_half = (__half*)alloc((size_t)N_NODES * HC * 2);
    _Float16*  act_h  = (_Float16*)alloc((size_t)N_NODES * HC * 2);
    float*     act_f  = (float*)alloc((size_t)N_NODES * 64 * 4);
    float* als    = (float*)alloc((size_t)N_NODES * 4 * 4);
    float* ald    = (float*)alloc((size_t)N_NODES * 4 * 4);
    int*   cnt    = (int*)alloc((size_t)N_NODES * 4);
    int*   row_ptr= (int*)alloc((size_t)(N_NODES + 1) * 4);
    int*   cursor = (int*)alloc((size_t)N_NODES * 4);
    int*   col    = (int*)alloc((size_t)(E_EDGES + N_NODES) * 4);
    float* pooled = (float*)alloc((size_t)B_GR * 64 * 4);
    int*   bsum   = (int*)alloc((size_t)NBLK_SCAN * 4);
    int*   boff   = (int*)alloc((size_t)NBLK_SCAN * 4);
    _Float16* w0h = (_Float16*)alloc((size_t)128 * 256 * 2);
    _Float16* w0l = (_Float16*)alloc((size_t)128 * 256 * 2);
    _Float16* w1h = (_Float16*)alloc((size_t)256 * 256 * 2);
    _Float16* w1l = (_Float16*)alloc((size_t)256 * 256 * 2);
    _Float16* w2h = (_Float16*)alloc((size_t)256 * 256 * 2);
    _Float16* w2l = (_Float16*)alloc((size_t)256 * 256 * 2);

    const int* srcs = ei;
    const int* dsts = ei + E_EDGES;

    // weight splits (tiny)
    wsplit_kernel<<<(128 * 256 + 255) / 256, 256, 0, stream>>>(W0, w0h, w0l, 128);
    wsplit_kernel<<<(256 * 256 + 255) / 256, 256, 0, stream>>>(W1, w1h, w1l, 256);
    wsplit_kernel<<<(256 * 256 + 255) / 256, 256, 0, stream>>>(W2, w2h, w2l, 256);

    // CSR by dst (graph static within call; reused by all 3 layers)
    init_cnt<<<(N_NODES + 255) / 256, 256, 0, stream>>>(cnt);
    hist_kernel<<<(E_EDGES + 255) / 256, 256, 0, stream>>>(dsts, cnt);
    scan_bsum<<<NBLK_SCAN, 256, 0, stream>>>(cnt, bsum);
    scan_boff<<<1, 256, 0, stream>>>(bsum, boff);
    scan_final<<<NBLK_SCAN, 256, 0, stream>>>(cnt, boff, row_ptr, cursor);
    scatter_kernel<<<(E_EDGES + N_NODES + 255) / 256, 256, 0, stream>>>(srcs, dsts, cursor, col);

    int gblk = (N_NODES + 63) / 64;   // 782
    int nblk = (N_NODES + 7) / 8;     // 6250 (2 nodes per wave, 4 waves/block)

    // layer 0 (A = x fp32: 3-term split kernel)
    gemm_mfma<128><<<gblk, 256, 0, stream>>>(x, w0h, w0l, h_half, as0, ad0, als, ald, N_NODES);
    agg_kernel<<<nblk, 256, 0, stream>>>(h_half, als, ald, row_ptr, col, b0, act_h, act_f, 0);
    // layer 1 (A = act fp16 exact: 2-term, zero-VALU staging)
    gemm_fp16<256><<<gblk, 256, 0, stream>>>(act_h, w1h, w1l, h_half, as1, ad1, als, ald, N_NODES);
    agg_kernel<<<nblk, 256, 0, stream>>>(h_half, als, ald, row_ptr, col, b1, act_h, act_f, 0);
    // layer 2 (mean heads, no ELU, fp32 out)
    gemm_fp16<256><<<gblk, 256, 0, stream>>>(act_h, w2h, w2l, h_half, as2, ad2, als, ald, N_NODES);
    agg_kernel<<<nblk, 256, 0, stream>>>(h_half, als, ald, row_ptr, col, b2, act_h, act_f, 1);

    pool_zero<<<(B_GR * 64 + 255) / 256, 256, 0, stream>>>(pooled);
    dim3 pgrid(B_GR, 16);
    pool_kernel<<<pgrid, 256, 0, stream>>>(act_f, batch, pooled);
    mlp_kernel<<<B_GR, 64, 0, stream>>>(pooled, batch, pW1, pb1, pW2, pb2, out);
}

// Round 9
// 423.123 us; speedup vs baseline: 2.5337x; 1.0051x over previous
//
#include <hip/hip_runtime.h>
#include <hip/hip_fp16.h>
#include <cstdint>

#define N_NODES 50000
#define E_EDGES 800000
#define HC 256           // H*C
#define B_GR 64
#define OUT_DIM 10
#define SLOPE 0.2f
#define NBLK_SCAN ((N_NODES + 255) / 256)   // 196

using f16x8 = __attribute__((ext_vector_type(8))) _Float16;
using f32x4 = __attribute__((ext_vector_type(4))) float;

#define GLOAD_LDS16(gsrc, ldst) \
    __builtin_amdgcn_global_load_lds((const __attribute__((address_space(1))) void*)(gsrc), \
        (__attribute__((address_space(3))) void*)(ldst), 16, 0, 0)

// ---------------- prep: x -> hi/lo fp16; W0/W1/W2 -> fragment-major hi/lo -----
// W layout [K/32][256][kg=4][j=8]: wave B-fragment load = contiguous 1KB.
__device__ inline void wsplit_one(const float* W, _Float16* wh, _Float16* wl,
                                  int K, int i) {
    int k = i >> 8, n = i & 255;
    float v = W[i];
    _Float16 h = (_Float16)v;
    _Float16 l = (_Float16)(v - (float)h);
    int oidx = ((((k >> 5) * 256 + n) * 4) + ((k >> 3) & 3)) * 8 + (k & 7);
    wh[oidx] = h;
    wl[oidx] = l;
}

__global__ void prep_split(const float* __restrict__ x,
        _Float16* __restrict__ xhi, _Float16* __restrict__ xlo,
        const float* __restrict__ W0, _Float16* __restrict__ w0h, _Float16* __restrict__ w0l,
        const float* __restrict__ W1, _Float16* __restrict__ w1h, _Float16* __restrict__ w1l,
        const float* __restrict__ W2, _Float16* __restrict__ w2h, _Float16* __restrict__ w2l) {
    const int NX = N_NODES * 128;
    int i = blockIdx.x * 256 + threadIdx.x;
    if (i < NX) {
        float v = x[i];
        _Float16 h = (_Float16)v;
        xhi[i] = h;
        xlo[i] = (_Float16)(v - (float)h);
        return;
    }
    int j = i - NX;
    if (j < 128 * 256) { wsplit_one(W0, w0h, w0l, 128, j); return; }
    j -= 128 * 256;
    if (j < 256 * 256) { wsplit_one(W1, w1h, w1l, 256, j); return; }
    j -= 256 * 256;
    if (j < 256 * 256) { wsplit_one(W2, w2h, w2l, 256, j); return; }
}

// ---------------- MFMA GEMM: h = A * W, split-fp16, 2-phase prefetch ----------
// TERMS=3 (layer 0: A has hi+lo parts) or TERMS=2 (A exact fp16).
// Double-buffered LDS staging via global_load_lds (linear dest, inverse-swizzled
// source involution g^(row&7)); stage(next) issued before compute(cur).
template<int K, int TERMS>
__global__ __launch_bounds__(256) void gemm16(const _Float16* __restrict__ Ahi,
        const _Float16* __restrict__ Alo,
        const _Float16* __restrict__ wt_hi, const _Float16* __restrict__ wt_lo,
        __half* __restrict__ h_half,
        const float* __restrict__ a_src, const float* __restrict__ a_dst,
        float* __restrict__ al_s, float* __restrict__ al_d, int M) {
    __shared__ _Float16 abuf[2][2][64][64];   // [dbuf][hi/lo][row][col] = 32KB
    int tid = threadIdx.x;
    int w = tid >> 6;           // wave -> head / col quadrant
    int l = tid & 63;
    int rr = l & 15;
    int kg = l >> 4;
    int row0 = blockIdx.x * 64;
    int srow = tid >> 3;        // staging row within half-tile 0..31
    int sgs  = tid & 7;         // staging slot (linear LDS)

    f32x4 acc[4][4] = {};
    const int NT = K / 64;

    auto stage = [&](int buf, int t) {
        int k0 = t * 64;
#pragma unroll
        for (int i = 0; i < 2; ++i) {
            int row = i * 32 + srow;
            int g = sgs ^ (row & 7);            // inverse swizzle on SOURCE
            int gr = min(row0 + row, M - 1);    // clamped rows unused in epilogue
            char* dst = (char*)abuf + buf * 16384 + i * 4096 + w * 1024;  // wave-uniform
            GLOAD_LDS16(&Ahi[(size_t)gr * K + k0 + g * 8], dst);
            if constexpr (TERMS == 3)
                GLOAD_LDS16(&Alo[(size_t)gr * K + k0 + g * 8], dst + 8192);
        }
    };

    stage(0, 0);
    __syncthreads();           // compiler drains vmcnt before barrier
    int cur = 0;
    for (int t = 0; t < NT; ++t) {
        if (t + 1 < NT) stage(cur ^ 1, t + 1);   // prefetch overlaps compute
        const _Float16* base_hi = &abuf[cur][0][0][0];
        const _Float16* base_lo = &abuf[cur][1][0][0];
#pragma unroll
        for (int c = 0; c < 2; ++c) {
            f16x8 ah[4], alo_[4];
#pragma unroll
            for (int fm = 0; fm < 4; ++fm) {
                int row = fm * 16 + rr;
                int gsw = ((c * 4 + kg) ^ (row & 7));   // swizzle on READ
                ah[fm] = *(const f16x8*)&base_hi[row * 64 + gsw * 8];
                if constexpr (TERMS == 3)
                    alo_[fm] = *(const f16x8*)&base_lo[row * 64 + gsw * 8];
            }
            int chunk = t * 2 + c;
#pragma unroll
            for (int fn = 0; fn < 4; ++fn) {
                int col = w * 64 + fn * 16 + rr;
                size_t boff = (((size_t)chunk * 256 + col) * 4 + kg) * 8;
                f16x8 bh = *(const f16x8*)&wt_hi[boff];
                f16x8 bl = *(const f16x8*)&wt_lo[boff];
#pragma unroll
                for (int fm = 0; fm < 4; ++fm) {
                    acc[fm][fn] = __builtin_amdgcn_mfma_f32_16x16x32_f16(ah[fm], bh, acc[fm][fn], 0, 0, 0);
                    acc[fm][fn] = __builtin_amdgcn_mfma_f32_16x16x32_f16(ah[fm], bl, acc[fm][fn], 0, 0, 0);
                    if constexpr (TERMS == 3)
                        acc[fm][fn] = __builtin_amdgcn_mfma_f32_16x16x32_f16(alo_[fm], bh, acc[fm][fn], 0, 0, 0);
                }
            }
        }
        __syncthreads();   // drains prefetch loads + protects buffer reuse
        cur ^= 1;
    }

    // ---- epilogue: fp16 h + per-head logits (head = wave) ----
    int head = w;
    float asv[4], adv[4];
#pragma unroll
    for (int fn = 0; fn < 4; ++fn) {
        asv[fn] = a_src[head * 64 + fn * 16 + rr];
        adv[fn] = a_dst[head * 64 + fn * 16 + rr];
    }
#pragma unroll
    for (int fm = 0; fm < 4; ++fm) {
#pragma unroll
        for (int r = 0; r < 4; ++r) {
            int row = fm * 16 + kg * 4 + r;     // C/D: row=(lane>>4)*4+reg
            int gr = row0 + row;
            float ps = acc[fm][0][r] * asv[0] + acc[fm][1][r] * asv[1]
                     + acc[fm][2][r] * asv[2] + acc[fm][3][r] * asv[3];
            float pd = acc[fm][0][r] * adv[0] + acc[fm][1][r] * adv[1]
                     + acc[fm][2][r] * adv[2] + acc[fm][3][r] * adv[3];
#pragma unroll
            for (int off = 1; off < 16; off <<= 1) {
                ps += __shfl_xor(ps, off, 64);
                pd += __shfl_xor(pd, off, 64);
            }
            if (gr < M) {
#pragma unroll
                for (int fn = 0; fn < 4; ++fn)
                    h_half[(size_t)gr * HC + w * 64 + fn * 16 + rr] = __float2half(acc[fm][fn][r]);
                if (rr == 0) {
                    al_s[gr * 4 + head] = ps;
                    al_d[gr * 4 + head] = pd;
                }
            }
        }
    }
}

// ---------------- CSR build (counting sort by dst) ---------------------------
__global__ void init_cnt(int* cnt) {
    int i = blockIdx.x * blockDim.x + threadIdx.x;
    if (i < N_NODES) cnt[i] = 1;   // self-loop pre-counted
}
__global__ void hist_kernel(const int* __restrict__ dsts, int* cnt) {
    int i = blockIdx.x * blockDim.x + threadIdx.x;
    if (i < E_EDGES) atomicAdd(&cnt[dsts[i]], 1);
}
__global__ __launch_bounds__(256) void scan_bsum(const int* __restrict__ cnt,
                                                 int* __restrict__ bsum) {
    __shared__ int ws[4];
    int t = threadIdx.x;
    int i = blockIdx.x * 256 + t;
    int v = (i < N_NODES) ? cnt[i] : 0;
#pragma unroll
    for (int off = 1; off < 64; off <<= 1) v += __shfl_xor(v, off, 64);
    if ((t & 63) == 0) ws[t >> 6] = v;
    __syncthreads();
    if (t == 0) bsum[blockIdx.x] = ws[0] + ws[1] + ws[2] + ws[3];
}
__global__ __launch_bounds__(256) void scan_boff(const int* __restrict__ bsum,
                                                 int* __restrict__ boff) {
    __shared__ int s[256];
    int t = threadIdx.x;
    int v = (t < NBLK_SCAN) ? bsum[t] : 0;
    s[t] = v;
    __syncthreads();
    for (int off = 1; off < 256; off <<= 1) {
        int u = (t >= off) ? s[t - off] : 0;
        __syncthreads();
        s[t] += u;
        __syncthreads();
    }
    if (t < NBLK_SCAN) boff[t] = s[t] - v;   // exclusive
}
__global__ __launch_bounds__(256) void scan_final(const int* __restrict__ cnt,
        const int* __restrict__ boff, int* __restrict__ row_ptr,
        int* __restrict__ cursor) {
    __shared__ int s[256];
    int b = blockIdx.x, t = threadIdx.x;
    int i = b * 256 + t;
    int v = (i < N_NODES) ? cnt[i] : 0;
    s[t] = v;
    __syncthreads();
    for (int off = 1; off < 256; off <<= 1) {
        int u = (t >= off) ? s[t - off] : 0;
        __syncthreads();
        s[t] += u;
        __syncthreads();
    }
    int rp = boff[b] + s[t] - v;   // exclusive prefix
    if (i < N_NODES) { row_ptr[i] = rp; cursor[i] = rp; }
    if (i == N_NODES - 1) row_ptr[N_NODES] = rp + v;   // = E+N total
}
__global__ void scatter_kernel(const int* __restrict__ srcs, const int* __restrict__ dsts,
                               int* cursor, int* col) {
    int i = blockIdx.x * blockDim.x + threadIdx.x;
    if (i >= E_EDGES + N_NODES) return;
    int s, d;
    if (i < E_EDGES) { s = srcs[i]; d = dsts[i]; }
    else             { s = d = i - E_EDGES; }     // self loops
    int pos = atomicAdd(&cursor[d], 1);
    col[pos] = s;
}

// ---------------- per-node softmax + aggregation -----------------------------
// mode 0: concat heads, +bias[256], ELU, fp16 out (act_h).
// mode 1: mean heads, +bias[64], no ELU, fp32 out (act_f).
__global__ __launch_bounds__(256) void agg_kernel(const __half* __restrict__ hh,
        const float* __restrict__ al_s, const float* __restrict__ al_d,
        const int* __restrict__ row_ptr, const int* __restrict__ col,
        const float* __restrict__ bias, _Float16* __restrict__ out_h,
        float* __restrict__ out_f, int mode) {
    __shared__ int   lds_col[4][64];
    __shared__ float lds_alpha[4][64][4];
    int wid  = threadIdx.x >> 6;
    int lane = threadIdx.x & 63;
    int hf   = lane >> 5;
    int ln   = lane & 31;
    int nodeA = blockIdx.x * 8 + wid * 2;   // N_NODES % 8 == 0 -> no tail
    int nodeB = nodeA + 1;
    int sA = row_ptr[nodeA], eA = row_ptr[nodeA + 1];
    int sB = row_ptr[nodeB], eB = row_ptr[nodeB + 1];
    int degA = eA - sA, degB = eB - sB;

    if (degA <= 32 && degB <= 32) {
        // ================= fast path: 2 nodes / wave =================
        int node  = hf ? nodeB : nodeA;
        int start = hf ? sB : sA;
        int deg   = hf ? degB : degA;
        int degmax = max(degA, degB);
        const float4 ald = *(const float4*)&al_d[node * 4];
        bool active = ln < deg;
        int s = active ? col[start + ln] : 0;
        float4 as = *(const float4*)&al_s[s * 4];
        float e0 = as.x + ald.x; e0 = e0 > 0.f ? e0 : SLOPE * e0;
        float e1 = as.y + ald.y; e1 = e1 > 0.f ? e1 : SLOPE * e1;
        float e2 = as.z + ald.z; e2 = e2 > 0.f ? e2 : SLOPE * e2;
        float e3 = as.w + ald.w; e3 = e3 > 0.f ? e3 : SLOPE * e3;
        float m0 = active ? e0 : -1e30f, m1 = active ? e1 : -1e30f;
        float m2 = active ? e2 : -1e30f, m3 = active ? e3 : -1e30f;
#pragma unroll
        for (int off = 1; off < 32; off <<= 1) {   // width-32: stays in half
            m0 = fmaxf(m0, __shfl_xor(m0, off, 64));
            m1 = fmaxf(m1, __shfl_xor(m1, off, 64));
            m2 = fmaxf(m2, __shfl_xor(m2, off, 64));
            m3 = fmaxf(m3, __shfl_xor(m3, off, 64));
        }
        float x0 = active ? expf(e0 - m0) : 0.f;
        float x1 = active ? expf(e1 - m1) : 0.f;
        float x2 = active ? expf(e2 - m2) : 0.f;
        float x3 = active ? expf(e3 - m3) : 0.f;
        float d0 = x0, d1 = x1, d2 = x2, d3 = x3;
#pragma unroll
        for (int off = 1; off < 32; off <<= 1) {
            d0 += __shfl_xor(d0, off, 64);
            d1 += __shfl_xor(d1, off, 64);
            d2 += __shfl_xor(d2, off, 64);
            d3 += __shfl_xor(d3, off, 64);
        }
        float4 a4;
        a4.x = x0 / (d0 + 1e-16f); a4.y = x1 / (d1 + 1e-16f);
        a4.z = x2 / (d2 + 1e-16f); a4.w = x3 / (d3 + 1e-16f);
        int e = hf * 32 + ln;
        lds_col[wid][e] = s;
        *(float4*)&lds_alpha[wid][e][0] = a4;
        int head = ln >> 3;
        int ch0 = ln * 8;
        float acc[8] = {0.f, 0.f, 0.f, 0.f, 0.f, 0.f, 0.f, 0.f};
        int ebase = hf * 32;
        for (int t0 = 0; t0 < degmax; t0 += 4) {
            float wv[4]; float4 raw[4];
#pragma unroll
            for (int k = 0; k < 4; ++k) {
                int t = t0 + k;
                int tt = min(t, deg - 1);          // deg >= 1 (self-loop)
                int s2 = lds_col[wid][ebase + tt];
                wv[k] = (t < deg) ? lds_alpha[wid][ebase + tt][head] : 0.f;
                raw[k] = *(const float4*)&hh[(size_t)s2 * HC + ch0];
            }
#pragma unroll
            for (int k = 0; k < 4; ++k) {
                const __half2* hp = (const __half2*)&raw[k];
                float2 f0 = __half22float2(hp[0]);
                float2 f1 = __half22float2(hp[1]);
                float2 f2 = __half22float2(hp[2]);
                float2 f3 = __half22float2(hp[3]);
                acc[0] = fmaf(wv[k], f0.x, acc[0]); acc[1] = fmaf(wv[k], f0.y, acc[1]);
                acc[2] = fmaf(wv[k], f1.x, acc[2]); acc[3] = fmaf(wv[k], f1.y, acc[3]);
                acc[4] = fmaf(wv[k], f2.x, acc[4]); acc[5] = fmaf(wv[k], f2.y, acc[5]);
                acc[6] = fmaf(wv[k], f3.x, acc[6]); acc[7] = fmaf(wv[k], f3.y, acc[7]);
            }
        }
        if (mode == 0) {
            float b8[8];
            *(float4*)&b8[0] = *(const float4*)&bias[ch0];
            *(float4*)&b8[4] = *(const float4*)&bias[ch0 + 4];
            _Float16 v[8];
#pragma unroll
            for (int j = 0; j < 8; ++j) {
                float t = acc[j] + b8[j];
                v[j] = (_Float16)(t > 0.f ? t : expm1f(t));
            }
            *(float4*)&out_h[(size_t)node * HC + ch0] = *(float4*)v;   // 16B
        } else {
#pragma unroll
            for (int j = 0; j < 8; ++j) {
                acc[j] += __shfl_xor(acc[j], 8, 64);
                acc[j] += __shfl_xor(acc[j], 16, 64);
            }
            if (ln < 8) {
                float v[8];
#pragma unroll
                for (int j = 0; j < 8; ++j)
                    v[j] = acc[j] * 0.25f + bias[ln * 8 + j];
                *(float4*)&out_f[(size_t)node * 64 + ln * 8]     = *(float4*)&v[0];
                *(float4*)&out_f[(size_t)node * 64 + ln * 8 + 4] = *(float4*)&v[4];
            }
        }
        return;
    }

    // ================= fallback: 1 node / wave (rare, deg>32) =================
    for (int nn = 0; nn < 2; ++nn) {
        int node = nodeA + nn;
        int start = row_ptr[node], end = row_ptr[node + 1];
        int deg = end - start;
        const float4 ald = *(const float4*)&al_d[node * 4];
        int head = lane >> 4;
        float ald_h = head == 0 ? ald.x : head == 1 ? ald.y : head == 2 ? ald.z : ald.w;
        float ax = 0.f, ay = 0.f, az = 0.f, aw = 0.f;

        if (deg <= 64) {
            int j = start + lane;
            bool active = j < end;
            int s = active ? col[j] : 0;
            float4 as = *(const float4*)&al_s[s * 4];
            float e0 = as.x + ald.x; e0 = e0 > 0.f ? e0 : SLOPE * e0;
            float e1 = as.y + ald.y; e1 = e1 > 0.f ? e1 : SLOPE * e1;
            float e2 = as.z + ald.z; e2 = e2 > 0.f ? e2 : SLOPE * e2;
            float e3 = as.w + ald.w; e3 = e3 > 0.f ? e3 : SLOPE * e3;
            float m0 = active ? e0 : -1e30f, m1 = active ? e1 : -1e30f;
            float m2 = active ? e2 : -1e30f, m3 = active ? e3 : -1e30f;
#pragma unroll
            for (int off = 1; off < 64; off <<= 1) {
                m0 = fmaxf(m0, __shfl_xor(m0, off, 64));
                m1 = fmaxf(m1, __shfl_xor(m1, off, 64));
                m2 = fmaxf(m2, __shfl_xor(m2, off, 64));
                m3 = fmaxf(m3, __shfl_xor(m3, off, 64));
            }
            float x0 = active ? expf(e0 - m0) : 0.f;
            float x1 = active ? expf(e1 - m1) : 0.f;
            float x2 = active ? expf(e2 - m2) : 0.f;
            float x3 = active ? expf(e3 - m3) : 0.f;
            float d0 = x0, d1 = x1, d2 = x2, d3 = x3;
#pragma unroll
            for (int off = 1; off < 64; off <<= 1) {
                d0 += __shfl_xor(d0, off, 64);
                d1 += __shfl_xor(d1, off, 64);
                d2 += __shfl_xor(d2, off, 64);
                d3 += __shfl_xor(d3, off, 64);
            }
            float4 a4;
            a4.x = x0 / (d0 + 1e-16f); a4.y = x1 / (d1 + 1e-16f);
            a4.z = x2 / (d2 + 1e-16f); a4.w = x3 / (d3 + 1e-16f);
            lds_col[wid][lane] = s;
            *(float4*)&lds_alpha[wid][lane][0] = a4;
            for (int t0 = 0; t0 < deg; t0 += 8) {
                int nr = deg - t0;
                float wv[8]; float2 raw[8];
#pragma unroll
                for (int k = 0; k < 8; ++k) {
                    if (k < nr) {
                        int s2 = lds_col[wid][t0 + k];
                        wv[k] = lds_alpha[wid][t0 + k][head];
                        raw[k] = *(const float2*)&hh[(size_t)s2 * HC + lane * 4];
                    } else {
                        wv[k] = 0.f;
                        raw[k] = make_float2(0.f, 0.f);
                    }
                }
#pragma unroll
                for (int k = 0; k < 8; ++k) {
                    float2 f0 = __half22float2(*(__half2*)&raw[k].x);
                    float2 f1 = __half22float2(*(__half2*)&raw[k].y);
                    ax = fmaf(wv[k], f0.x, ax); ay = fmaf(wv[k], f0.y, ay);
                    az = fmaf(wv[k], f1.x, az); aw = fmaf(wv[k], f1.y, aw);
                }
            }
        } else {
            float m0 = -1e30f, m1 = -1e30f, m2 = -1e30f, m3 = -1e30f;
            for (int j = start + lane; j < end; j += 64) {
                int s = col[j];
                float4 as = *(const float4*)&al_s[s * 4];
                float e0 = as.x + ald.x; e0 = e0 > 0.f ? e0 : SLOPE * e0;
                float e1 = as.y + ald.y; e1 = e1 > 0.f ? e1 : SLOPE * e1;
                float e2 = as.z + ald.z; e2 = e2 > 0.f ? e2 : SLOPE * e2;
                float e3 = as.w + ald.w; e3 = e3 > 0.f ? e3 : SLOPE * e3;
                m0 = fmaxf(m0, e0); m1 = fmaxf(m1, e1);
                m2 = fmaxf(m2, e2); m3 = fmaxf(m3, e3);
            }
#pragma unroll
            for (int off = 1; off < 64; off <<= 1) {
                m0 = fmaxf(m0, __shfl_xor(m0, off, 64));
                m1 = fmaxf(m1, __shfl_xor(m1, off, 64));
                m2 = fmaxf(m2, __shfl_xor(m2, off, 64));
                m3 = fmaxf(m3, __shfl_xor(m3, off, 64));
            }
            float d0 = 0.f, d1 = 0.f, d2 = 0.f, d3 = 0.f;
            for (int j = start + lane; j < end; j += 64) {
                int s = col[j];
                float4 as = *(const float4*)&al_s[s * 4];
                float e0 = as.x + ald.x; e0 = e0 > 0.f ? e0 : SLOPE * e0;
                float e1 = as.y + ald.y; e1 = e1 > 0.f ? e1 : SLOPE * e1;
                float e2 = as.z + ald.z; e2 = e2 > 0.f ? e2 : SLOPE * e2;
                float e3 = as.w + ald.w; e3 = e3 > 0.f ? e3 : SLOPE * e3;
                d0 += expf(e0 - m0); d1 += expf(e1 - m1);
                d2 += expf(e2 - m2); d3 += expf(e3 - m3);
            }
#pragma unroll
            for (int off = 1; off < 64; off <<= 1) {
                d0 += __shfl_xor(d0, off, 64);
                d1 += __shfl_xor(d1, off, 64);
                d2 += __shfl_xor(d2, off, 64);
                d3 += __shfl_xor(d3, off, 64);
            }
            float inv0 = 1.f / (d0 + 1e-16f), inv1 = 1.f / (d1 + 1e-16f);
            float inv2 = 1.f / (d2 + 1e-16f), inv3 = 1.f / (d3 + 1e-16f);
            float m_h   = head == 0 ? m0   : head == 1 ? m1   : head == 2 ? m2   : m3;
            float inv_h = head == 0 ? inv0 : head == 1 ? inv1 : head == 2 ? inv2 : inv3;
            for (int jb = start; jb < end; jb += 64) {
                int j = jb + lane;
                int cs = (j < end) ? col[j] : 0;
                int cnt2 = min(64, end - jb);
                for (int t = 0; t < cnt2; ++t) {
                    int s = __shfl(cs, t, 64);
                    float als2 = al_s[s * 4 + head];
                    float e = als2 + ald_h; e = e > 0.f ? e : SLOPE * e;
                    float wv = expf(e - m_h) * inv_h;
                    float2 raw = *(const float2*)&hh[(size_t)s * HC + lane * 4];
                    float2 f0 = __half22float2(*(__half2*)&raw.x);
                    float2 f1 = __half22float2(*(__half2*)&raw.y);
                    ax = fmaf(wv, f0.x, ax); ay = fmaf(wv, f0.y, ay);
                    az = fmaf(wv, f1.x, az); aw = fmaf(wv, f1.y, aw);
                }
            }
        }

        if (mode == 0) {
            float4 b4 = *(const float4*)&bias[lane * 4];
            float vx = ax + b4.x; vx = vx > 0.f ? vx : expm1f(vx);
            float vy = ay + b4.y; vy = vy > 0.f ? vy : expm1f(vy);
            float vz = az + b4.z; vz = vz > 0.f ? vz : expm1f(vz);
            float vw = aw + b4.w; vw = vw > 0.f ? vw : expm1f(vw);
            _Float16 v[4] = {(_Float16)vx, (_Float16)vy, (_Float16)vz, (_Float16)vw};
            *(float2*)&out_h[(size_t)node * HC + lane * 4] = *(float2*)v;   // 8B
        } else {
#pragma unroll
            for (int off = 16; off < 64; off <<= 1) {
                ax += __shfl_xor(ax, off, 64);
                ay += __shfl_xor(ay, off, 64);
                az += __shfl_xor(az, off, 64);
                aw += __shfl_xor(aw, off, 64);
            }
            if (lane < 16) {
                float4 b4 = *(const float4*)&bias[lane * 4];
                float4 v = make_float4(ax * 0.25f + b4.x, ay * 0.25f + b4.y,
                                       az * 0.25f + b4.z, aw * 0.25f + b4.w);
                *(float4*)&out_f[(size_t)node * 64 + lane * 4] = v;
            }
        }
    }
}

// ---------------- pooling + MLP ----------------------------------------------
// Non-atomic: 64 blocks x 1024 threads (16 waves), LDS tree reduce.
__global__ __launch_bounds__(1024) void pool_kernel(const float* __restrict__ act,
        const int* __restrict__ batch, float* __restrict__ pooled) {
    __shared__ float part[16][64];
    int b = blockIdx.x;
    int warp = threadIdx.x >> 6;     // 0..15
    int lane = threadIdx.x & 63;
    int lo = 0, hi = N_NODES;
    while (lo < hi) { int mid = (lo + hi) >> 1; if (batch[mid] < b) lo = mid + 1; else hi = mid; }
    int s = lo;
    lo = 0; hi = N_NODES;
    while (lo < hi) { int mid = (lo + hi) >> 1; if (batch[mid] < b + 1) lo = mid + 1; else hi = mid; }
    int e = lo;
    float sum = 0.f;
    for (int n = s + warp; n < e; n += 16)
        sum += act[(size_t)n * 64 + lane];
    part[warp][lane] = sum;
    __syncthreads();
    if (threadIdx.x < 64) {
        float t = 0.f;
#pragma unroll
        for (int r = 0; r < 16; ++r) t += part[r][lane];
        pooled[b * 64 + lane] = t;
    }
}

__global__ __launch_bounds__(64) void mlp_kernel(const float* __restrict__ pooled,
        const int* __restrict__ batch,
        const float* __restrict__ pW1, const float* __restrict__ pb1,
        const float* __restrict__ pW2, const float* __restrict__ pb2,
        float* __restrict__ outp) {
    __shared__ float p[64];
    __shared__ float z[32];
    int b = blockIdx.x, t = threadIdx.x;
    int lo = 0, hi = N_NODES;
    while (lo < hi) { int mid = (lo + hi) >> 1; if (batch[mid] < b) lo = mid + 1; else hi = mid; }
    int s = lo;
    lo = 0; hi = N_NODES;
    while (lo < hi) { int mid = (lo + hi) >> 1; if (batch[mid] < b + 1) lo = mid + 1; else hi = mid; }
    int e = lo;
    float inv = 1.f / (float)max(e - s, 1);
    p[t] = pooled[b * 64 + t] * inv;
    __syncthreads();
    if (t < 32) {
        float s2 = pb1[t];
        for (int c = 0; c < 64; ++c) s2 += p[c] * pW1[c * 32 + t];
        z[t] = s2 > 0.f ? s2 : 0.f;
    }
    __syncthreads();
    if (t < OUT_DIM) {
        float s2 = pb2[t];
        for (int k = 0; k < 32; ++k) s2 += z[k] * pW2[k * 10 + t];
        outp[b * 10 + t] = s2;
    }
}

// ---------------- launch ------------------------------------------------------
extern "C" void kernel_launch(void* const* d_in, const int* in_sizes, int n_in,
                              void* d_out, int out_size, void* d_ws, size_t ws_size,
                              hipStream_t stream) {
    const float* x    = (const float*)d_in[0];
    const int*   ei   = (const int*)d_in[1];
    const int*   batch= (const int*)d_in[2];
    const float* W0   = (const float*)d_in[3];
    const float* b0   = (const float*)d_in[4];
    const float* as0  = (const float*)d_in[5];
    const float* ad0  = (const float*)d_in[6];
    const float* W1   = (const float*)d_in[7];
    const float* b1   = (const float*)d_in[8];
    const float* as1  = (const float*)d_in[9];
    const float* ad1  = (const float*)d_in[10];
    const float* W2   = (const float*)d_in[11];
    const float* b2   = (const float*)d_in[12];
    const float* as2  = (const float*)d_in[13];
    const float* ad2  = (const float*)d_in[14];
    const float* pW1  = (const float*)d_in[15];
    const float* pb1  = (const float*)d_in[16];
    const float* pW2  = (const float*)d_in[17];
    const float* pb2  = (const float*)d_in[18];
    float* out = (float*)d_out;

    char* ws = (char*)d_ws;
    size_t off = 0;
    auto alloc = [&](size_t bytes) -> void* {
        void* p = ws + off;
        off += (bytes + 255) & ~(size_t)255;
        return p;
    };
    __half*    h_half = (__half*)alloc((size_t)N_NODES * HC * 2);
    _Float16*  act_h  = (_Float16*)alloc((size_t)N_NODES * HC * 2);
    float*     act_f  = (float*)alloc((size_t)N_NODES * 64 * 4);
    _Float16*  xhi    = (_Float16*)alloc((size_t)N_NODES * 128 * 2);
    _Float16*  xlo    = (_Float16*)alloc((size_t)N_NODES * 128 * 2);
    float* als    = (float*)alloc((size_t)N_NODES * 4 * 4);
    float* ald    = (float*)alloc((size_t)N_NODES * 4 * 4);
    int*   cnt    = (int*)alloc((size_t)N_NODES * 4);
    int*   row_ptr= (int*)alloc((size_t)(N_NODES + 1) * 4);
    int*   cursor = (int*)alloc((size_t)N_NODES * 4);
    int*   col    = (int*)alloc((size_t)(E_EDGES + N_NODES) * 4);
    float* pooled = (float*)alloc((size_t)B_GR * 64 * 4);
    int*   bsum   = (int*)alloc((size_t)NBLK_SCAN * 4);
    int*   boff   = (int*)alloc((size_t)NBLK_SCAN * 4);
    _Float16* w0h = (_Float16*)alloc((size_t)128 * 256 * 2);
    _Float16* w0l = (_Float16*)alloc((size_t)128 * 256 * 2);
    _Float16* w1h = (_Float16*)alloc((size_t)256 * 256 * 2);
    _Float16* w1l = (_Float16*)alloc((size_t)256 * 256 * 2);
    _Float16* w2h = (_Float16*)alloc((size_t)256 * 256 * 2);
    _Float16* w2l = (_Float16*)alloc((size_t)256 * 256 * 2);

    const int* srcs = ei;
    const int* dsts = ei + E_EDGES;

    // fused prep: x hi/lo split + 3 W splits
    const int PREP_N = N_NODES * 128 + 128 * 256 + 256 * 256 + 256 * 256;
    prep_split<<<(PREP_N + 255) / 256, 256, 0, stream>>>(
        x, xhi, xlo, W0, w0h, w0l, W1, w1h, w1l, W2, w2h, w2l);

    // CSR by dst (graph static within call; reused by all 3 layers)
    init_cnt<<<(N_NODES + 255) / 256, 256, 0, stream>>>(cnt);
    hist_kernel<<<(E_EDGES + 255) / 256, 256, 0, stream>>>(dsts, cnt);
    scan_bsum<<<NBLK_SCAN, 256, 0, stream>>>(cnt, bsum);
    scan_boff<<<1, 256, 0, stream>>>(bsum, boff);
    scan_final<<<NBLK_SCAN, 256, 0, stream>>>(cnt, boff, row_ptr, cursor);
    scatter_kernel<<<(E_EDGES + N_NODES + 255) / 256, 256, 0, stream>>>(srcs, dsts, cursor, col);

    int gblk = (N_NODES + 63) / 64;   // 782
    int nblk = (N_NODES + 7) / 8;     // 6250 (2 nodes per wave, 4 waves/block)

    // layer 0 (A = x split hi/lo: 3-term)
    gemm16<128, 3><<<gblk, 256, 0, stream>>>(xhi, xlo, w0h, w0l, h_half, as0, ad0, als, ald, N_NODES);
    agg_kernel<<<nblk, 256, 0, stream>>>(h_half, als, ald, row_ptr, col, b0, act_h, act_f, 0);
    // layer 1 (A = act fp16 exact: 2-term)
    gemm16<256, 2><<<gblk, 256, 0, stream>>>(act_h, nullptr, w1h, w1l, h_half, as1, ad1, als, ald, N_NODES);
    agg_kernel<<<nblk, 256, 0, stream>>>(h_half, als, ald, row_ptr, col, b1, act_h, act_f, 0);
    // layer 2 (mean heads, no ELU, fp32 out)
    gemm16<256, 2><<<gblk, 256, 0, stream>>>(act_h, nullptr, w2h, w2l, h_half, as2, ad2, als, ald, N_NODES);
    agg_kernel<<<nblk, 256, 0, stream>>>(h_half, als, ald, row_ptr, col, b2, act_h, act_f, 1);

    pool_kernel<<<B_GR, 1024, 0, stream>>>(act_f, batch, pooled);
    mlp_kernel<<<B_GR, 64, 0, stream>>>(pooled, batch, pW1, pb1, pW2, pb2, out);
}